// Round 1
// baseline (17712.157 us; speedup 1.0000x reference)
//
#include <hip/hip_runtime.h>
#include <hip/hip_cooperative_groups.h>

namespace cg = cooperative_groups;

#define V_    32000
#define B_    32
#define T_    128
#define H_    1024
#define BT_   4096     // B_*T_
#define G4H_  4096     // 4*H_
#define EPS_  1e-5f
#define FB_   1.0f     // forget bias

typedef __bf16  bf16x8 __attribute__((ext_vector_type(8)));
typedef float   f32x4  __attribute__((ext_vector_type(4)));
typedef short   short8 __attribute__((ext_vector_type(8)));

__device__ __forceinline__ unsigned short f2bf(float f) {
  unsigned u = __builtin_bit_cast(unsigned, f);
  u = u + 0x7FFFu + ((u >> 16) & 1u);          // round-to-nearest-even
  return (unsigned short)(u >> 16);
}
__device__ __forceinline__ float sigm(float x) { return 1.0f / (1.0f + expf(-x)); }

// ---------------------------------------------------------------- transpose+cast
// in: fp32 [R][C] (ld = ldin), out: bf16 [C][R]. grid (C/32, R/32), block (32,8).
__global__ void k_transpose_cast(const float* __restrict__ in, unsigned short* __restrict__ out,
                                 int R, int C, int ldin) {
  __shared__ float tl[32][33];
  const int tx = threadIdx.x, ty = threadIdx.y;
  const int r0 = blockIdx.y * 32, c0 = blockIdx.x * 32;
#pragma unroll
  for (int i = 0; i < 4; ++i)
    tl[ty + 8 * i][tx] = in[(size_t)(r0 + ty + 8 * i) * ldin + c0 + tx];
  __syncthreads();
#pragma unroll
  for (int i = 0; i < 4; ++i)
    out[(size_t)(c0 + ty + 8 * i) * R + r0 + tx] = f2bf(tl[tx][ty + 8 * i]);
}

// ---------------------------------------------------------------- embedding gather
// grid BT_, block 256. x[r][:] = bf16(embedding[ids[r]][:])
__global__ void k_gather(const int* __restrict__ ids, const float* __restrict__ emb,
                         unsigned short* __restrict__ x) {
  const int r = blockIdx.x;
  const int t4 = threadIdx.x * 4;
  const int row = ids[r];
  const float4 v = *(const float4*)&emb[(size_t)row * H_ + t4];
  ushort4 o;
  o.x = f2bf(v.x); o.y = f2bf(v.y); o.z = f2bf(v.z); o.w = f2bf(v.w);
  *(ushort4*)&x[(size_t)r * H_ + t4] = o;
}

// ---------------------------------------------------------------- bf16 GEMM, C = A * BT^T + bias
// A: bf16 [M][K] row-major, BT: bf16 [N][K] row-major, C: fp32 [M][N].
// 128x128 tile, BK=32, 4 waves in 2x2 wave grid, mfma 16x16x32.
__global__ __launch_bounds__(256)
void k_gemm_bt(const unsigned short* __restrict__ A, const unsigned short* __restrict__ BT,
               const float* __restrict__ bias, float* __restrict__ C,
               int M, int N, int K) {
  __shared__ unsigned short As[128 * 32];
  __shared__ unsigned short Bs[128 * 32];
  const int tid = threadIdx.x;
  const int lane = tid & 63, wid = tid >> 6;
  const int wr = wid >> 1, wc = wid & 1;
  const int la = lane & 15, lb = lane >> 4;
  const int m0 = blockIdx.y * 128, n0 = blockIdx.x * 128;

  f32x4 acc[4][4];
#pragma unroll
  for (int i = 0; i < 4; ++i)
#pragma unroll
    for (int j = 0; j < 4; ++j) acc[i][j] = f32x4{0.f, 0.f, 0.f, 0.f};

  for (int k0 = 0; k0 < K; k0 += 32) {
    __syncthreads();
#pragma unroll
    for (int i = 0; i < 2; ++i) {
      const int off = i * 2048 + tid * 8;
      const int row = off >> 5, col = off & 31;
      *(short8*)&As[off] = *(const short8*)&A[(size_t)(m0 + row) * K + k0 + col];
      *(short8*)&Bs[off] = *(const short8*)&BT[(size_t)(n0 + row) * K + k0 + col];
    }
    __syncthreads();
    bf16x8 a[4], b[4];
#pragma unroll
    for (int mm = 0; mm < 4; ++mm) a[mm] = *(bf16x8*)&As[(wr * 64 + mm * 16 + la) * 32 + lb * 8];
#pragma unroll
    for (int nn = 0; nn < 4; ++nn) b[nn] = *(bf16x8*)&Bs[(wc * 64 + nn * 16 + la) * 32 + lb * 8];
#pragma unroll
    for (int mm = 0; mm < 4; ++mm)
#pragma unroll
      for (int nn = 0; nn < 4; ++nn)
        acc[mm][nn] = __builtin_amdgcn_mfma_f32_16x16x32_bf16(a[mm], b[nn], acc[mm][nn], 0, 0, 0);
  }
#pragma unroll
  for (int mm = 0; mm < 4; ++mm)
#pragma unroll
    for (int nn = 0; nn < 4; ++nn) {
      const int row = m0 + wr * 64 + mm * 16 + lb * 4;
      const int col = n0 + wc * 64 + nn * 16 + la;
      const float bs = bias ? bias[col] : 0.f;
#pragma unroll
      for (int r = 0; r < 4; ++r)
        C[(size_t)(row + r) * N + col] = acc[mm][nn][r] + bs;
    }
}

// ---------------------------------------------------------------- persistent LN-LSTM layer
// Cooperative, grid=256 blocks x 256 threads, 1 block/CU (LDS ~108KB).
// Block j holds WhT cols [16j,16j+16) in LDS for all T steps.
// Per step: phase1 (all blocks): gf[32][4096] = G[t] + h_prev @ Wh ; grid sync;
//           phase2 (blocks 0..31): LN gates -> pointwise -> cell LN -> nh ; grid sync.
__global__ __launch_bounds__(256)
void k_lstm(const float* __restrict__ G, const unsigned short* __restrict__ WhT,
            const float* __restrict__ lng, const float* __restrict__ lnb,
            float* __restrict__ gf, unsigned short* __restrict__ Hout) {
  cg::grid_group grid = cg::this_grid();
  __shared__ unsigned short wh[16 * 1024];   // [col][k]
  __shared__ unsigned short hs[32 * 1024];   // [b][k] bf16
  __shared__ float crow[1024];               // cell state for row bid (blocks 0..31)
  __shared__ float red[4][32][16];           // cross-wave partials
  __shared__ float rsc[64];

  const int tid = threadIdx.x;
  const int bid = blockIdx.x;
  const int lane = tid & 63, w = tid >> 6;
  const int la = lane & 15, lb = lane >> 4;

  for (int i = tid * 8; i < 16 * 1024; i += 2048)
    *(short8*)&wh[i] = *(const short8*)&WhT[(size_t)bid * 16384 + i];
  if (bid < 32)
    for (int e = tid; e < 1024; e += 256) crow[e] = 0.0f;

  for (int t = 0; t < T_; ++t) {
    // ---- stage h_prev (bf16 [32][1024])
    if (t == 0) {
      const short8 z = {0, 0, 0, 0, 0, 0, 0, 0};
      for (int i = tid * 8; i < 32 * 1024; i += 2048) *(short8*)&hs[i] = z;
    } else {
      for (int i = tid * 8; i < 32 * 1024; i += 2048) {
        const int b = i >> 10, k = i & 1023;
        *(short8*)&hs[i] = *(const short8*)&Hout[((size_t)(b * T_ + (t - 1))) * H_ + k];
      }
    }
    __syncthreads();

    // ---- phase 1: recurrent matmul, wave w covers k in [256w, 256w+256)
    f32x4 acc0 = {0.f, 0.f, 0.f, 0.f}, acc1 = {0.f, 0.f, 0.f, 0.f};
#pragma unroll
    for (int kk = 0; kk < 8; ++kk) {
      const int k = w * 256 + kk * 32 + lb * 8;
      const bf16x8 bv = *(bf16x8*)&wh[la * 1024 + k];
      const bf16x8 a0 = *(bf16x8*)&hs[la * 1024 + k];
      const bf16x8 a1 = *(bf16x8*)&hs[(16 + la) * 1024 + k];
      acc0 = __builtin_amdgcn_mfma_f32_16x16x32_bf16(a0, bv, acc0, 0, 0, 0);
      acc1 = __builtin_amdgcn_mfma_f32_16x16x32_bf16(a1, bv, acc1, 0, 0, 0);
    }
#pragma unroll
    for (int r = 0; r < 4; ++r) {
      red[w][lb * 4 + r][la] = acc0[r];
      red[w][16 + lb * 4 + r][la] = acc1[r];
    }
    __syncthreads();
    for (int o = tid; o < 512; o += 256) {
      const int b = o >> 4, c = o & 15;
      const float s = red[0][b][c] + red[1][b][c] + red[2][b][c] + red[3][b][c];
      gf[b * G4H_ + bid * 16 + c] = s + G[((size_t)(b * T_ + t)) * G4H_ + bid * 16 + c];
    }
    grid.sync();

    // ---- phase 2: LN + pointwise, block b < 32 handles batch row b
    if (bid < 32) {
      const int b = bid;
      float iv[4], jv[4], fv[4], ov[4];
      float vals[8] = {0, 0, 0, 0, 0, 0, 0, 0};
#pragma unroll
      for (int u = 0; u < 4; ++u) {
        const int e = tid + u * 256;
        iv[u] = gf[b * G4H_ + e];
        jv[u] = gf[b * G4H_ + 1024 + e];
        fv[u] = gf[b * G4H_ + 2048 + e];
        ov[u] = gf[b * G4H_ + 3072 + e];
        vals[0] += iv[u]; vals[4] += iv[u] * iv[u];
        vals[1] += jv[u]; vals[5] += jv[u] * jv[u];
        vals[2] += fv[u]; vals[6] += fv[u] * fv[u];
        vals[3] += ov[u]; vals[7] += ov[u] * ov[u];
      }
#pragma unroll
      for (int i = 0; i < 8; ++i) {
        float x = vals[i];
        for (int off = 32; off > 0; off >>= 1) x += __shfl_down(x, off);
        if (lane == 0) rsc[w * 8 + i] = x;
      }
      __syncthreads();
#pragma unroll
      for (int i = 0; i < 8; ++i)
        vals[i] = rsc[i] + rsc[8 + i] + rsc[16 + i] + rsc[24 + i];
      __syncthreads();
      const float m0 = vals[0] * (1.f / 1024), m1 = vals[1] * (1.f / 1024);
      const float m2 = vals[2] * (1.f / 1024), m3 = vals[3] * (1.f / 1024);
      const float r0 = rsqrtf(vals[4] * (1.f / 1024) - m0 * m0 + EPS_);
      const float r1 = rsqrtf(vals[5] * (1.f / 1024) - m1 * m1 + EPS_);
      const float r2 = rsqrtf(vals[6] * (1.f / 1024) - m2 * m2 + EPS_);
      const float r3 = rsqrtf(vals[7] * (1.f / 1024) - m3 * m3 + EPS_);

      float nc[4], oo[4];
      float cs = 0.f, cq = 0.f;
#pragma unroll
      for (int u = 0; u < 4; ++u) {
        const int e = tid + u * 256;
        const float xi = lng[e] * ((iv[u] - m0) * r0) + lnb[e];
        const float xj = lng[1024 + e] * ((jv[u] - m1) * r1) + lnb[1024 + e];
        const float xf = lng[2048 + e] * ((fv[u] - m2) * r2) + lnb[2048 + e];
        const float xo = lng[3072 + e] * ((ov[u] - m3) * r3) + lnb[3072 + e];
        const float ncv = crow[e] * sigm(xf + FB_) + sigm(xi) * tanhf(xj);
        nc[u] = ncv; oo[u] = xo;
        cs += ncv; cq += ncv * ncv;
      }
      {
        float x = cs, y = cq;
        for (int off = 32; off > 0; off >>= 1) { x += __shfl_down(x, off); y += __shfl_down(y, off); }
        if (lane == 0) { rsc[w * 2] = x; rsc[w * 2 + 1] = y; }
      }
      __syncthreads();
      cs = rsc[0] + rsc[2] + rsc[4] + rsc[6];
      cq = rsc[1] + rsc[3] + rsc[5] + rsc[7];
      const float mc = cs * (1.f / 1024);
      const float rc = rsqrtf(cq * (1.f / 1024) - mc * mc + EPS_);
#pragma unroll
      for (int u = 0; u < 4; ++u) {
        const int e = tid + u * 256;
        crow[e] = nc[u];
        const float nh = tanhf(lng[4096 + e] * ((nc[u] - mc) * rc) + lnb[4096 + e]) * sigm(oo[u]);
        Hout[((size_t)(b * T_ + t)) * H_ + e] = f2bf(nh);
      }
    }
    grid.sync();
  }
}

// ---------------------------------------------------------------- per-row logsumexp
__global__ __launch_bounds__(256)
void k_lse(const float* __restrict__ logits, float* __restrict__ lse) {
  __shared__ float rm[4];
  __shared__ float rs[4];
  const int r = blockIdx.x, tid = threadIdx.x;
  const float* row = logits + (size_t)r * V_;
  float mx = -1e30f;
  for (int e = tid; e < V_; e += 256) mx = fmaxf(mx, row[e]);
  for (int off = 32; off > 0; off >>= 1) mx = fmaxf(mx, __shfl_down(mx, off));
  if ((tid & 63) == 0) rm[tid >> 6] = mx;
  __syncthreads();
  mx = fmaxf(fmaxf(rm[0], rm[1]), fmaxf(rm[2], rm[3]));
  float s = 0.f;
  for (int e = tid; e < V_; e += 256) s += expf(row[e] - mx);
  for (int off = 32; off > 0; off >>= 1) s += __shfl_down(s, off);
  if ((tid & 63) == 0) rs[tid >> 6] = s;
  __syncthreads();
  if (tid == 0) lse[r] = mx + logf(rs[0] + rs[1] + rs[2] + rs[3]);
}

// ---------------------------------------------------------------- loss (mean NLL)
__global__ __launch_bounds__(256)
void k_loss(const float* __restrict__ logits, const float* __restrict__ lse,
            const int* __restrict__ tgt, float* __restrict__ out) {
  __shared__ float rsc[4];
  const int tid = threadIdx.x;
  float s = 0.f;
  for (int r = tid; r < BT_; r += 256)
    s += lse[r] - logits[(size_t)r * V_ + tgt[r]];
  for (int off = 32; off > 0; off >>= 1) s += __shfl_down(s, off);
  if ((tid & 63) == 0) rsc[tid >> 6] = s;
  __syncthreads();
  if (tid == 0) out[(size_t)BT_ * V_] = (rsc[0] + rsc[1] + rsc[2] + rsc[3]) / (float)BT_;
}

// ================================================================ launch
extern "C" void kernel_launch(void* const* d_in, const int* in_sizes, int n_in,
                              void* d_out, int out_size, void* d_ws, size_t ws_size,
                              hipStream_t stream) {
  const int*   ids  = (const int*)d_in[0];
  const int*   tgt  = (const int*)d_in[1];
  const float* emb  = (const float*)d_in[2];
  const float* W    = (const float*)d_in[3];   // [2][2048][4096]
  const float* brnn = (const float*)d_in[4];   // [2][4096]
  const float* lng  = (const float*)d_in[5];   // [2][5][1024]
  const float* lnb  = (const float*)d_in[6];
  const float* sw   = (const float*)d_in[7];   // [1024][32000]
  const float* sb   = (const float*)d_in[8];   // [32000]
  float* out = (float*)d_out;

  char* ws = (char*)d_ws;
  size_t o = 0;
  auto take = [&](size_t n) { char* p = ws + o; o += (n + 255) & ~(size_t)255; return p; };
  unsigned short* WxT0 = (unsigned short*)take((size_t)G4H_ * H_ * 2);
  unsigned short* WhT0 = (unsigned short*)take((size_t)G4H_ * H_ * 2);
  unsigned short* WxT1 = (unsigned short*)take((size_t)G4H_ * H_ * 2);
  unsigned short* WhT1 = (unsigned short*)take((size_t)G4H_ * H_ * 2);
  unsigned short* WsT  = (unsigned short*)take((size_t)V_ * H_ * 2);
  unsigned short* Xemb = (unsigned short*)take((size_t)BT_ * H_ * 2);
  float*          Gbuf = (float*)take((size_t)BT_ * G4H_ * 4);
  unsigned short* Hb0  = (unsigned short*)take((size_t)BT_ * H_ * 2);
  unsigned short* Hb1  = (unsigned short*)take((size_t)BT_ * H_ * 2);
  float*          gf   = (float*)take((size_t)32 * G4H_ * 4);
  float*          lseb = (float*)take((size_t)BT_ * 4);

  const dim3 tb(32, 8);
  // weight transposes + bf16 cast: W[l] rows 0..1023 = Wx, rows 1024..2047 = Wh
  k_transpose_cast<<<dim3(128, 32),  tb, 0, stream>>>(W,                    WxT0, 1024, 4096, 4096);
  k_transpose_cast<<<dim3(128, 32),  tb, 0, stream>>>(W + 1024 * 4096,      WhT0, 1024, 4096, 4096);
  k_transpose_cast<<<dim3(128, 32),  tb, 0, stream>>>(W + 2048 * 4096,      WxT1, 1024, 4096, 4096);
  k_transpose_cast<<<dim3(128, 32),  tb, 0, stream>>>(W + 3072 * 4096,      WhT1, 1024, 4096, 4096);
  k_transpose_cast<<<dim3(1000, 32), tb, 0, stream>>>(sw,                   WsT,  1024, V_,  V_);

  k_gather<<<BT_, 256, 0, stream>>>(ids, emb, Xemb);

  // layer 0
  k_gemm_bt<<<dim3(32, 32), 256, 0, stream>>>(Xemb, WxT0, brnn, Gbuf, BT_, G4H_, H_);
  {
    const float* G_ = Gbuf; const unsigned short* Wh_ = WhT0;
    const float* g_ = lng;  const float* b_ = lnb;
    float* gf_ = gf; unsigned short* Ho_ = Hb0;
    void* args[] = {&G_, &Wh_, &g_, &b_, &gf_, &Ho_};
    hipLaunchCooperativeKernel((void*)k_lstm, dim3(256), dim3(256), args, 0, stream);
  }
  // layer 1
  k_gemm_bt<<<dim3(32, 32), 256, 0, stream>>>(Hb0, WxT1, brnn + 4096, Gbuf, BT_, G4H_, H_);
  {
    const float* G_ = Gbuf; const unsigned short* Wh_ = WhT1;
    const float* g_ = lng + 5120; const float* b_ = lnb + 5120;
    float* gf_ = gf; unsigned short* Ho_ = Hb1;
    void* args[] = {&G_, &Wh_, &g_, &b_, &gf_, &Ho_};
    hipLaunchCooperativeKernel((void*)k_lstm, dim3(256), dim3(256), args, 0, stream);
  }

  // projection -> logits (d_out) ; then logsumexp + loss
  k_gemm_bt<<<dim3(250, 32), 256, 0, stream>>>(Hb1, WsT, sb, out, BT_, V_, H_);
  k_lse<<<BT_, 256, 0, stream>>>(out, lseb);
  k_loss<<<1, 256, 0, stream>>>(out, lseb, tgt, out);
}

// Round 2
// 7518.732 us; speedup vs baseline: 2.3557x; 2.3557x over previous
//
#include <hip/hip_runtime.h>
#include <hip/hip_cooperative_groups.h>

namespace cg = cooperative_groups;

#define V_    32000
#define B_    32
#define T_    128
#define H_    1024
#define BT_   4096     // B_*T_
#define G4H_  4096     // 4*H_
#define EPS_  1e-5f
#define FB_   1.0f     // forget bias

typedef __bf16  bf16x8 __attribute__((ext_vector_type(8)));
typedef float   f32x4  __attribute__((ext_vector_type(4)));
typedef short   short8 __attribute__((ext_vector_type(8)));

__device__ __forceinline__ unsigned short f2bf(float f) {
  unsigned u = __builtin_bit_cast(unsigned, f);
  u = u + 0x7FFFu + ((u >> 16) & 1u);          // round-to-nearest-even
  return (unsigned short)(u >> 16);
}
__device__ __forceinline__ float sigm(float x) { return 1.0f / (1.0f + expf(-x)); }

// ---------------------------------------------------------------- fast grid barrier
// bars layout (unsigned, 64-word = 256B padded slots):
//   bars[0]          generation counter
//   bars[64*(1+i)]   sub-counter i, i=0..7   (blocks arrive at bid&7)
//   bars[64*9]       master counter
// Sense-free: gen increases monotonically; each block reads gen before arriving.
// Release/acquire chain: block --(ACQ_REL sub)--> sub-last --(ACQ_REL master)-->
// master-last --(RELEASE gen)--> spinners (relaxed spin + ACQUIRE fence).
__device__ __forceinline__ void gbar(unsigned* bars) {
  __syncthreads();
  if (threadIdx.x == 0) {
    const unsigned gen = __hip_atomic_load(&bars[0], __ATOMIC_RELAXED, __HIP_MEMORY_SCOPE_AGENT);
    unsigned* sub = &bars[64 * (1 + (blockIdx.x & 7))];
    const unsigned a = __hip_atomic_fetch_add(sub, 1u, __ATOMIC_ACQ_REL, __HIP_MEMORY_SCOPE_AGENT);
    if (a == 31u) {                                    // last arriver of this sub-group (256/8 = 32)
      const unsigned m = __hip_atomic_fetch_add(&bars[64 * 9], 1u, __ATOMIC_ACQ_REL, __HIP_MEMORY_SCOPE_AGENT);
      if (m == 7u) {                                   // last overall: reset counters, bump gen
#pragma unroll
        for (int i = 0; i < 8; ++i)
          __hip_atomic_store(&bars[64 * (1 + i)], 0u, __ATOMIC_RELAXED, __HIP_MEMORY_SCOPE_AGENT);
        __hip_atomic_store(&bars[64 * 9], 0u, __ATOMIC_RELAXED, __HIP_MEMORY_SCOPE_AGENT);
        __hip_atomic_fetch_add(&bars[0], 1u, __ATOMIC_RELEASE, __HIP_MEMORY_SCOPE_AGENT);
      }
    }
    while (__hip_atomic_load(&bars[0], __ATOMIC_RELAXED, __HIP_MEMORY_SCOPE_AGENT) == gen)
      __builtin_amdgcn_s_sleep(1);
    __builtin_amdgcn_fence(__ATOMIC_ACQUIRE, "agent");
  }
  __syncthreads();
}

// ---------------------------------------------------------------- transpose+cast
// in: fp32 [R][C] (ld = ldin), out: bf16 [C][R]. grid (C/32, R/32), block (32,8).
__global__ void k_transpose_cast(const float* __restrict__ in, unsigned short* __restrict__ out,
                                 int R, int C, int ldin) {
  __shared__ float tl[32][33];
  const int tx = threadIdx.x, ty = threadIdx.y;
  const int r0 = blockIdx.y * 32, c0 = blockIdx.x * 32;
#pragma unroll
  for (int i = 0; i < 4; ++i)
    tl[ty + 8 * i][tx] = in[(size_t)(r0 + ty + 8 * i) * ldin + c0 + tx];
  __syncthreads();
#pragma unroll
  for (int i = 0; i < 4; ++i)
    out[(size_t)(c0 + ty + 8 * i) * R + r0 + tx] = f2bf(tl[tx][ty + 8 * i]);
}

// ---------------------------------------------------------------- embedding gather
// grid BT_, block 256. x[r][:] = bf16(embedding[ids[r]][:])
__global__ void k_gather(const int* __restrict__ ids, const float* __restrict__ emb,
                         unsigned short* __restrict__ x) {
  const int r = blockIdx.x;
  const int t4 = threadIdx.x * 4;
  const int row = ids[r];
  const float4 v = *(const float4*)&emb[(size_t)row * H_ + t4];
  ushort4 o;
  o.x = f2bf(v.x); o.y = f2bf(v.y); o.z = f2bf(v.z); o.w = f2bf(v.w);
  *(ushort4*)&x[(size_t)r * H_ + t4] = o;
}

// ---------------------------------------------------------------- bf16 GEMM, C = A * BT^T + bias
// A: bf16 [M][K] row-major, BT: bf16 [N][K] row-major, C: fp32 [M][N].
// 128x128 tile, BK=32, 4 waves in 2x2 wave grid, mfma 16x16x32.
__global__ __launch_bounds__(256)
void k_gemm_bt(const unsigned short* __restrict__ A, const unsigned short* __restrict__ BT,
               const float* __restrict__ bias, float* __restrict__ C,
               int M, int N, int K) {
  __shared__ unsigned short As[128 * 32];
  __shared__ unsigned short Bs[128 * 32];
  const int tid = threadIdx.x;
  const int lane = tid & 63, wid = tid >> 6;
  const int wr = wid >> 1, wc = wid & 1;
  const int la = lane & 15, lb = lane >> 4;
  const int m0 = blockIdx.y * 128, n0 = blockIdx.x * 128;

  f32x4 acc[4][4];
#pragma unroll
  for (int i = 0; i < 4; ++i)
#pragma unroll
    for (int j = 0; j < 4; ++j) acc[i][j] = f32x4{0.f, 0.f, 0.f, 0.f};

  for (int k0 = 0; k0 < K; k0 += 32) {
    __syncthreads();
#pragma unroll
    for (int i = 0; i < 2; ++i) {
      const int off = i * 2048 + tid * 8;
      const int row = off >> 5, col = off & 31;
      *(short8*)&As[off] = *(const short8*)&A[(size_t)(m0 + row) * K + k0 + col];
      *(short8*)&Bs[off] = *(const short8*)&BT[(size_t)(n0 + row) * K + k0 + col];
    }
    __syncthreads();
    bf16x8 a[4], b[4];
#pragma unroll
    for (int mm = 0; mm < 4; ++mm) a[mm] = *(bf16x8*)&As[(wr * 64 + mm * 16 + la) * 32 + lb * 8];
#pragma unroll
    for (int nn = 0; nn < 4; ++nn) b[nn] = *(bf16x8*)&Bs[(wc * 64 + nn * 16 + la) * 32 + lb * 8];
#pragma unroll
    for (int mm = 0; mm < 4; ++mm)
#pragma unroll
      for (int nn = 0; nn < 4; ++nn)
        acc[mm][nn] = __builtin_amdgcn_mfma_f32_16x16x32_bf16(a[mm], b[nn], acc[mm][nn], 0, 0, 0);
  }
#pragma unroll
  for (int mm = 0; mm < 4; ++mm)
#pragma unroll
    for (int nn = 0; nn < 4; ++nn) {
      const int row = m0 + wr * 64 + mm * 16 + lb * 4;
      const int col = n0 + wc * 64 + nn * 16 + la;
      const float bs = bias ? bias[col] : 0.f;
#pragma unroll
      for (int r = 0; r < 4; ++r)
        C[(size_t)(row + r) * N + col] = acc[mm][nn][r] + bs;
    }
}

// ---------------------------------------------------------------- persistent LN-LSTM layer
// Cooperative, grid=256 blocks x 256 threads, 1 block/CU (LDS ~108KB).
// Block j holds WhT cols [16j,16j+16) in LDS for all T steps.
// Per step: phase1 (all blocks): gf[32][4096] = G[t] + h_prev @ Wh ; gbar;
//           phase2 (blocks 0..31): LN gates -> pointwise -> cell LN -> nh ; gbar.
__global__ __launch_bounds__(256)
void k_lstm(const float* __restrict__ G, const unsigned short* __restrict__ WhT,
            const float* __restrict__ lng, const float* __restrict__ lnb,
            float* __restrict__ gf, unsigned short* __restrict__ Hout,
            unsigned* bars) {
  __shared__ unsigned short wh[16 * 1024];   // [col][k]
  __shared__ unsigned short hs[32 * 1024];   // [b][k] bf16
  __shared__ float crow[1024];               // cell state for row bid (blocks 0..31)
  __shared__ float red[4][32][16];           // cross-wave partials
  __shared__ float rsc[64];

  const int tid = threadIdx.x;
  const int bid = blockIdx.x;
  const int lane = tid & 63, w = tid >> 6;
  const int la = lane & 15, lb = lane >> 4;

  for (int i = tid * 8; i < 16 * 1024; i += 2048)
    *(short8*)&wh[i] = *(const short8*)&WhT[(size_t)bid * 16384 + i];
  if (bid < 32)
    for (int e = tid; e < 1024; e += 256) crow[e] = 0.0f;

  for (int t = 0; t < T_; ++t) {
    // ---- stage h_prev (bf16 [32][1024])
    if (t == 0) {
      const short8 z = {0, 0, 0, 0, 0, 0, 0, 0};
      for (int i = tid * 8; i < 32 * 1024; i += 2048) *(short8*)&hs[i] = z;
    } else {
      for (int i = tid * 8; i < 32 * 1024; i += 2048) {
        const int b = i >> 10, k = i & 1023;
        *(short8*)&hs[i] = *(const short8*)&Hout[((size_t)(b * T_ + (t - 1))) * H_ + k];
      }
    }
    __syncthreads();

    // ---- phase 1: recurrent matmul, wave w covers k in [256w, 256w+256)
    f32x4 acc0 = {0.f, 0.f, 0.f, 0.f}, acc1 = {0.f, 0.f, 0.f, 0.f};
#pragma unroll
    for (int kk = 0; kk < 8; ++kk) {
      const int k = w * 256 + kk * 32 + lb * 8;
      const bf16x8 bv = *(bf16x8*)&wh[la * 1024 + k];
      const bf16x8 a0 = *(bf16x8*)&hs[la * 1024 + k];
      const bf16x8 a1 = *(bf16x8*)&hs[(16 + la) * 1024 + k];
      acc0 = __builtin_amdgcn_mfma_f32_16x16x32_bf16(a0, bv, acc0, 0, 0, 0);
      acc1 = __builtin_amdgcn_mfma_f32_16x16x32_bf16(a1, bv, acc1, 0, 0, 0);
    }
#pragma unroll
    for (int r = 0; r < 4; ++r) {
      red[w][lb * 4 + r][la] = acc0[r];
      red[w][16 + lb * 4 + r][la] = acc1[r];
    }
    __syncthreads();
    for (int o = tid; o < 512; o += 256) {
      const int b = o >> 4, c = o & 15;
      const float s = red[0][b][c] + red[1][b][c] + red[2][b][c] + red[3][b][c];
      gf[b * G4H_ + bid * 16 + c] = s + G[((size_t)(b * T_ + t)) * G4H_ + bid * 16 + c];
    }
    gbar(bars);

    // ---- phase 2: LN + pointwise, block b < 32 handles batch row b
    if (bid < 32) {
      const int b = bid;
      float iv[4], jv[4], fv[4], ov[4];
      float vals[8] = {0, 0, 0, 0, 0, 0, 0, 0};
#pragma unroll
      for (int u = 0; u < 4; ++u) {
        const int e = tid + u * 256;
        iv[u] = gf[b * G4H_ + e];
        jv[u] = gf[b * G4H_ + 1024 + e];
        fv[u] = gf[b * G4H_ + 2048 + e];
        ov[u] = gf[b * G4H_ + 3072 + e];
        vals[0] += iv[u]; vals[4] += iv[u] * iv[u];
        vals[1] += jv[u]; vals[5] += jv[u] * jv[u];
        vals[2] += fv[u]; vals[6] += fv[u] * fv[u];
        vals[3] += ov[u]; vals[7] += ov[u] * ov[u];
      }
#pragma unroll
      for (int i = 0; i < 8; ++i) {
        float x = vals[i];
        for (int off = 32; off > 0; off >>= 1) x += __shfl_down(x, off);
        if (lane == 0) rsc[w * 8 + i] = x;
      }
      __syncthreads();
#pragma unroll
      for (int i = 0; i < 8; ++i)
        vals[i] = rsc[i] + rsc[8 + i] + rsc[16 + i] + rsc[24 + i];
      __syncthreads();
      const float m0 = vals[0] * (1.f / 1024), m1 = vals[1] * (1.f / 1024);
      const float m2 = vals[2] * (1.f / 1024), m3 = vals[3] * (1.f / 1024);
      const float r0 = rsqrtf(vals[4] * (1.f / 1024) - m0 * m0 + EPS_);
      const float r1 = rsqrtf(vals[5] * (1.f / 1024) - m1 * m1 + EPS_);
      const float r2 = rsqrtf(vals[6] * (1.f / 1024) - m2 * m2 + EPS_);
      const float r3 = rsqrtf(vals[7] * (1.f / 1024) - m3 * m3 + EPS_);

      float nc[4], oo[4];
      float cs = 0.f, cq = 0.f;
#pragma unroll
      for (int u = 0; u < 4; ++u) {
        const int e = tid + u * 256;
        const float xi = lng[e] * ((iv[u] - m0) * r0) + lnb[e];
        const float xj = lng[1024 + e] * ((jv[u] - m1) * r1) + lnb[1024 + e];
        const float xf = lng[2048 + e] * ((fv[u] - m2) * r2) + lnb[2048 + e];
        const float xo = lng[3072 + e] * ((ov[u] - m3) * r3) + lnb[3072 + e];
        const float ncv = crow[e] * sigm(xf + FB_) + sigm(xi) * tanhf(xj);
        nc[u] = ncv; oo[u] = xo;
        cs += ncv; cq += ncv * ncv;
      }
      {
        float x = cs, y = cq;
        for (int off = 32; off > 0; off >>= 1) { x += __shfl_down(x, off); y += __shfl_down(y, off); }
        if (lane == 0) { rsc[w * 2] = x; rsc[w * 2 + 1] = y; }
      }
      __syncthreads();
      cs = rsc[0] + rsc[2] + rsc[4] + rsc[6];
      cq = rsc[1] + rsc[3] + rsc[5] + rsc[7];
      const float mc = cs * (1.f / 1024);
      const float rc = rsqrtf(cq * (1.f / 1024) - mc * mc + EPS_);
#pragma unroll
      for (int u = 0; u < 4; ++u) {
        const int e = tid + u * 256;
        crow[e] = nc[u];
        const float nh = tanhf(lng[4096 + e] * ((nc[u] - mc) * rc) + lnb[4096 + e]) * sigm(oo[u]);
        Hout[((size_t)(b * T_ + t)) * H_ + e] = f2bf(nh);
      }
    }
    gbar(bars);
  }
}

// ---------------------------------------------------------------- per-row logsumexp
__global__ __launch_bounds__(256)
void k_lse(const float* __restrict__ logits, float* __restrict__ lse) {
  __shared__ float rm[4];
  __shared__ float rs[4];
  const int r = blockIdx.x, tid = threadIdx.x;
  const float* row = logits + (size_t)r * V_;
  float mx = -1e30f;
  for (int e = tid; e < V_; e += 256) mx = fmaxf(mx, row[e]);
  for (int off = 32; off > 0; off >>= 1) mx = fmaxf(mx, __shfl_down(mx, off));
  if ((tid & 63) == 0) rm[tid >> 6] = mx;
  __syncthreads();
  mx = fmaxf(fmaxf(rm[0], rm[1]), fmaxf(rm[2], rm[3]));
  float s = 0.f;
  for (int e = tid; e < V_; e += 256) s += expf(row[e] - mx);
  for (int off = 32; off > 0; off >>= 1) s += __shfl_down(s, off);
  if ((tid & 63) == 0) rs[tid >> 6] = s;
  __syncthreads();
  if (tid == 0) lse[r] = mx + logf(rs[0] + rs[1] + rs[2] + rs[3]);
}

// ---------------------------------------------------------------- loss (mean NLL)
__global__ __launch_bounds__(256)
void k_loss(const float* __restrict__ logits, const float* __restrict__ lse,
            const int* __restrict__ tgt, float* __restrict__ out) {
  __shared__ float rsc[4];
  const int tid = threadIdx.x;
  float s = 0.f;
  for (int r = tid; r < BT_; r += 256)
    s += lse[r] - logits[(size_t)r * V_ + tgt[r]];
  for (int off = 32; off > 0; off >>= 1) s += __shfl_down(s, off);
  if ((tid & 63) == 0) rsc[tid >> 6] = s;
  __syncthreads();
  if (tid == 0) out[(size_t)BT_ * V_] = (rsc[0] + rsc[1] + rsc[2] + rsc[3]) / (float)BT_;
}

// ================================================================ launch
extern "C" void kernel_launch(void* const* d_in, const int* in_sizes, int n_in,
                              void* d_out, int out_size, void* d_ws, size_t ws_size,
                              hipStream_t stream) {
  const int*   ids  = (const int*)d_in[0];
  const int*   tgt  = (const int*)d_in[1];
  const float* emb  = (const float*)d_in[2];
  const float* W    = (const float*)d_in[3];   // [2][2048][4096]
  const float* brnn = (const float*)d_in[4];   // [2][4096]
  const float* lng  = (const float*)d_in[5];   // [2][5][1024]
  const float* lnb  = (const float*)d_in[6];
  const float* sw   = (const float*)d_in[7];   // [1024][32000]
  const float* sb   = (const float*)d_in[8];   // [32000]
  float* out = (float*)d_out;

  char* ws = (char*)d_ws;
  size_t o = 0;
  auto take = [&](size_t n) { char* p = ws + o; o += (n + 255) & ~(size_t)255; return p; };
  unsigned short* WxT0 = (unsigned short*)take((size_t)G4H_ * H_ * 2);
  unsigned short* WhT0 = (unsigned short*)take((size_t)G4H_ * H_ * 2);
  unsigned short* WxT1 = (unsigned short*)take((size_t)G4H_ * H_ * 2);
  unsigned short* WhT1 = (unsigned short*)take((size_t)G4H_ * H_ * 2);
  unsigned short* WsT  = (unsigned short*)take((size_t)V_ * H_ * 2);
  unsigned short* Xemb = (unsigned short*)take((size_t)BT_ * H_ * 2);
  float*          Gbuf = (float*)take((size_t)BT_ * G4H_ * 4);
  unsigned short* Hb0  = (unsigned short*)take((size_t)BT_ * H_ * 2);
  unsigned short* Hb1  = (unsigned short*)take((size_t)BT_ * H_ * 2);
  float*          gf   = (float*)take((size_t)32 * G4H_ * 4);
  float*          lseb = (float*)take((size_t)BT_ * 4);
  unsigned*       bars = (unsigned*)take(4096);

  // zero the barrier slots every launch (ws is poisoned 0xAA once by the harness)
  hipMemsetAsync(bars, 0, 4096, stream);

  const dim3 tb(32, 8);
  // weight transposes + bf16 cast: W[l] rows 0..1023 = Wx, rows 1024..2047 = Wh
  k_transpose_cast<<<dim3(128, 32),  tb, 0, stream>>>(W,                    WxT0, 1024, 4096, 4096);
  k_transpose_cast<<<dim3(128, 32),  tb, 0, stream>>>(W + 1024 * 4096,      WhT0, 1024, 4096, 4096);
  k_transpose_cast<<<dim3(128, 32),  tb, 0, stream>>>(W + 2048 * 4096,      WxT1, 1024, 4096, 4096);
  k_transpose_cast<<<dim3(128, 32),  tb, 0, stream>>>(W + 3072 * 4096,      WhT1, 1024, 4096, 4096);
  k_transpose_cast<<<dim3(1000, 32), tb, 0, stream>>>(sw,                   WsT,  1024, V_,  V_);

  k_gather<<<BT_, 256, 0, stream>>>(ids, emb, Xemb);

  // layer 0
  k_gemm_bt<<<dim3(32, 32), 256, 0, stream>>>(Xemb, WxT0, brnn, Gbuf, BT_, G4H_, H_);
  {
    const float* G_ = Gbuf; const unsigned short* Wh_ = WhT0;
    const float* g_ = lng;  const float* b_ = lnb;
    float* gf_ = gf; unsigned short* Ho_ = Hb0; unsigned* bars_ = bars;
    void* args[] = {&G_, &Wh_, &g_, &b_, &gf_, &Ho_, &bars_};
    hipLaunchCooperativeKernel((void*)k_lstm, dim3(256), dim3(256), args, 0, stream);
  }
  // layer 1
  k_gemm_bt<<<dim3(32, 32), 256, 0, stream>>>(Hb0, WxT1, brnn + 4096, Gbuf, BT_, G4H_, H_);
  {
    const float* G_ = Gbuf; const unsigned short* Wh_ = WhT1;
    const float* g_ = lng + 5120; const float* b_ = lnb + 5120;
    float* gf_ = gf; unsigned short* Ho_ = Hb1; unsigned* bars_ = bars;
    void* args[] = {&G_, &Wh_, &g_, &b_, &gf_, &Ho_, &bars_};
    hipLaunchCooperativeKernel((void*)k_lstm, dim3(256), dim3(256), args, 0, stream);
  }

  // projection -> logits (d_out) ; then logsumexp + loss
  k_gemm_bt<<<dim3(250, 32), 256, 0, stream>>>(Hb1, WsT, sb, out, BT_, V_, H_);
  k_lse<<<BT_, 256, 0, stream>>>(out, lseb);
  k_loss<<<1, 256, 0, stream>>>(out, lseb, tgt, out);
}

// Round 4
// 6698.345 us; speedup vs baseline: 2.6443x; 1.1225x over previous
//
#include <hip/hip_runtime.h>
#include <hip/hip_cooperative_groups.h>

#define V_    32000
#define B_    32
#define T_    128
#define H_    1024
#define BT_   4096     // B_*T_
#define G4H_  4096     // 4*H_
#define EPS_  1e-5f
#define FB_   1.0f     // forget bias

typedef __bf16  bf16x8 __attribute__((ext_vector_type(8)));
typedef float   f32x4  __attribute__((ext_vector_type(4)));
typedef short   short8 __attribute__((ext_vector_type(8)));

__device__ __forceinline__ unsigned short f2bf(float f) {
  unsigned u = __builtin_bit_cast(unsigned, f);
  u = u + 0x7FFFu + ((u >> 16) & 1u);          // round-to-nearest-even
  return (unsigned short)(u >> 16);
}
__device__ __forceinline__ float sigm(float x) { return 1.0f / (1.0f + expf(-x)); }

// ---------------------------------------------------------------- checker grid barrier
// bars layout (unsigned words): slots at bars[16*i], i=0..63 (64B apart);
// generation word at bars[2048]. All monotonic within one kernel run; host
// re-zeros bars before each cooperative launch.
// Arrival: block's tid 0 does release fetch_add on slot (bid&63)  -> <=4
// serialized RMWs per slot. Checker: block 255 wave 0 polls the 64 slots
// lane-parallel until all reach 4*(g+1), then publishes GEN = g+1.
// Spinners poll GEN relaxed + acquire fence.
__device__ __forceinline__ void cbar(unsigned* bars, unsigned& g) {
  __syncthreads();
  if (threadIdx.x == 0)
    __hip_atomic_fetch_add(&bars[16 * (blockIdx.x & 63)], 1u, __ATOMIC_RELEASE, __HIP_MEMORY_SCOPE_AGENT);
  if (blockIdx.x == 255) {
    if (threadIdx.x < 64) {
      const unsigned tgt = 4u * (g + 1);
      unsigned* slot = &bars[16 * threadIdx.x];
      while (__hip_atomic_load(slot, __ATOMIC_RELAXED, __HIP_MEMORY_SCOPE_AGENT) < tgt)
        __builtin_amdgcn_s_sleep(1);
      if (threadIdx.x == 0) {
        __builtin_amdgcn_fence(__ATOMIC_ACQUIRE, "agent");
        __hip_atomic_store(&bars[2048], g + 1, __ATOMIC_RELEASE, __HIP_MEMORY_SCOPE_AGENT);
      }
    }
  } else if (threadIdx.x == 0) {
    while (__hip_atomic_load(&bars[2048], __ATOMIC_RELAXED, __HIP_MEMORY_SCOPE_AGENT) < g + 1)
      __builtin_amdgcn_s_sleep(1);
    __builtin_amdgcn_fence(__ATOMIC_ACQUIRE, "agent");
  }
  __syncthreads();
  ++g;
}

// ---------------------------------------------------------------- transpose+cast
__global__ void k_transpose_cast(const float* __restrict__ in, unsigned short* __restrict__ out,
                                 int R, int C, int ldin) {
  __shared__ float tl[32][33];
  const int tx = threadIdx.x, ty = threadIdx.y;
  const int r0 = blockIdx.y * 32, c0 = blockIdx.x * 32;
#pragma unroll
  for (int i = 0; i < 4; ++i)
    tl[ty + 8 * i][tx] = in[(size_t)(r0 + ty + 8 * i) * ldin + c0 + tx];
  __syncthreads();
#pragma unroll
  for (int i = 0; i < 4; ++i)
    out[(size_t)(c0 + ty + 8 * i) * R + r0 + tx] = f2bf(tl[tx][ty + 8 * i]);
}

// ---------------------------------------------------------------- embedding gather
__global__ void k_gather(const int* __restrict__ ids, const float* __restrict__ emb,
                         unsigned short* __restrict__ x) {
  const int r = blockIdx.x;
  const int t4 = threadIdx.x * 4;
  const int row = ids[r];
  const float4 v = *(const float4*)&emb[(size_t)row * H_ + t4];
  ushort4 o;
  o.x = f2bf(v.x); o.y = f2bf(v.y); o.z = f2bf(v.z); o.w = f2bf(v.w);
  *(ushort4*)&x[(size_t)r * H_ + t4] = o;
}

// ---------------------------------------------------------------- bf16 GEMM, C = A * BT^T + bias
__global__ __launch_bounds__(256)
void k_gemm_bt(const unsigned short* __restrict__ A, const unsigned short* __restrict__ BT,
               const float* __restrict__ bias, float* __restrict__ C,
               int M, int N, int K) {
  __shared__ unsigned short As[128 * 32];
  __shared__ unsigned short Bs[128 * 32];
  const int tid = threadIdx.x;
  const int lane = tid & 63, wid = tid >> 6;
  const int wr = wid >> 1, wc = wid & 1;
  const int la = lane & 15, lb = lane >> 4;
  const int m0 = blockIdx.y * 128, n0 = blockIdx.x * 128;

  f32x4 acc[4][4];
#pragma unroll
  for (int i = 0; i < 4; ++i)
#pragma unroll
    for (int j = 0; j < 4; ++j) acc[i][j] = f32x4{0.f, 0.f, 0.f, 0.f};

  for (int k0 = 0; k0 < K; k0 += 32) {
    __syncthreads();
#pragma unroll
    for (int i = 0; i < 2; ++i) {
      const int off = i * 2048 + tid * 8;
      const int row = off >> 5, col = off & 31;
      *(short8*)&As[off] = *(const short8*)&A[(size_t)(m0 + row) * K + k0 + col];
      *(short8*)&Bs[off] = *(const short8*)&BT[(size_t)(n0 + row) * K + k0 + col];
    }
    __syncthreads();
    bf16x8 a[4], b[4];
#pragma unroll
    for (int mm = 0; mm < 4; ++mm) a[mm] = *(bf16x8*)&As[(wr * 64 + mm * 16 + la) * 32 + lb * 8];
#pragma unroll
    for (int nn = 0; nn < 4; ++nn) b[nn] = *(bf16x8*)&Bs[(wc * 64 + nn * 16 + la) * 32 + lb * 8];
#pragma unroll
    for (int mm = 0; mm < 4; ++mm)
#pragma unroll
      for (int nn = 0; nn < 4; ++nn)
        acc[mm][nn] = __builtin_amdgcn_mfma_f32_16x16x32_bf16(a[mm], b[nn], acc[mm][nn], 0, 0, 0);
  }
#pragma unroll
  for (int mm = 0; mm < 4; ++mm)
#pragma unroll
    for (int nn = 0; nn < 4; ++nn) {
      const int row = m0 + wr * 64 + mm * 16 + lb * 4;
      const int col = n0 + wc * 64 + nn * 16 + la;
      const float bs = bias ? bias[col] : 0.f;
#pragma unroll
      for (int r = 0; r < 4; ++r)
        C[(size_t)(row + r) * N + col] = acc[mm][nn][r] + bs;
    }
}

// ---------------------------------------------------------------- persistent LN-LSTM layer
// Cooperative, grid=256 blocks x 256 threads, 1 block/CU (LDS ~108KB).
// Block j holds WhT cols [16j,16j+16) in LDS for all T steps.
// Per step: phase1 (all blocks): gf[32][4096] = G[t] + h_prev @ Wh ; cbar;
//           phase2 (blocks 0..31): LN gates -> pointwise -> cell LN -> nh ; cbar.
__global__ __launch_bounds__(256)
void k_lstm(const float* __restrict__ G, const unsigned short* __restrict__ WhT,
            const float* __restrict__ lng, const float* __restrict__ lnb,
            float* __restrict__ gf, unsigned short* __restrict__ Hout,
            unsigned* bars) {
  __shared__ unsigned short wh[16 * 1024];   // [col][k]
  __shared__ unsigned short hs[32 * 1024];   // [b][k] bf16
  __shared__ float crow[1024];               // cell state for row bid (blocks 0..31)
  __shared__ float red[4][32][16];           // cross-wave partials
  __shared__ float rsc[64];

  const int tid = threadIdx.x;
  const int bid = blockIdx.x;
  const int lane = tid & 63, w = tid >> 6;
  const int la = lane & 15, lb = lane >> 4;

  for (int i = tid * 8; i < 16 * 1024; i += 2048)
    *(short8*)&wh[i] = *(const short8*)&WhT[(size_t)bid * 16384 + i];
  if (bid < 32)
    for (int e = tid; e < 1024; e += 256) crow[e] = 0.0f;

  unsigned g = 0;

  for (int t = 0; t < T_; ++t) {
    // ---- stage h_prev (bf16 [32][1024])
    if (t == 0) {
      const short8 z = {0, 0, 0, 0, 0, 0, 0, 0};
      for (int i = tid * 8; i < 32 * 1024; i += 2048) *(short8*)&hs[i] = z;
    } else {
      for (int i = tid * 8; i < 32 * 1024; i += 2048) {
        const int b = i >> 10, k = i & 1023;
        *(short8*)&hs[i] = *(const short8*)&Hout[((size_t)(b * T_ + (t - 1))) * H_ + k];
      }
    }
    __syncthreads();

    // ---- phase 1: recurrent matmul, wave w covers k in [256w, 256w+256)
    f32x4 acc0 = {0.f, 0.f, 0.f, 0.f}, acc1 = {0.f, 0.f, 0.f, 0.f};
#pragma unroll
    for (int kk = 0; kk < 8; ++kk) {
      const int k = w * 256 + kk * 32 + lb * 8;
      const bf16x8 bv = *(bf16x8*)&wh[la * 1024 + k];
      const bf16x8 a0 = *(bf16x8*)&hs[la * 1024 + k];
      const bf16x8 a1 = *(bf16x8*)&hs[(16 + la) * 1024 + k];
      acc0 = __builtin_amdgcn_mfma_f32_16x16x32_bf16(a0, bv, acc0, 0, 0, 0);
      acc1 = __builtin_amdgcn_mfma_f32_16x16x32_bf16(a1, bv, acc1, 0, 0, 0);
    }
#pragma unroll
    for (int r = 0; r < 4; ++r) {
      red[w][lb * 4 + r][la] = acc0[r];
      red[w][16 + lb * 4 + r][la] = acc1[r];
    }
    __syncthreads();
    for (int o = tid; o < 512; o += 256) {
      const int b = o >> 4, c = o & 15;
      const float s = red[0][b][c] + red[1][b][c] + red[2][b][c] + red[3][b][c];
      gf[b * G4H_ + bid * 16 + c] = s + G[((size_t)(b * T_ + t)) * G4H_ + bid * 16 + c];
    }
    cbar(bars, g);

    // ---- phase 2: LN + pointwise, block b < 32 handles batch row b
    if (bid < 32) {
      const int b = bid;
      float iv[4], jv[4], fv[4], ov[4];
      float vals[8] = {0, 0, 0, 0, 0, 0, 0, 0};
#pragma unroll
      for (int u = 0; u < 4; ++u) {
        const int e = tid + u * 256;
        iv[u] = gf[b * G4H_ + e];
        jv[u] = gf[b * G4H_ + 1024 + e];
        fv[u] = gf[b * G4H_ + 2048 + e];
        ov[u] = gf[b * G4H_ + 3072 + e];
        vals[0] += iv[u]; vals[4] += iv[u] * iv[u];
        vals[1] += jv[u]; vals[5] += jv[u] * jv[u];
        vals[2] += fv[u]; vals[6] += fv[u] * fv[u];
        vals[3] += ov[u]; vals[7] += ov[u] * ov[u];
      }
#pragma unroll
      for (int i = 0; i < 8; ++i) {
        float x = vals[i];
        for (int off = 32; off > 0; off >>= 1) x += __shfl_down(x, off);
        if (lane == 0) rsc[w * 8 + i] = x;
      }
      __syncthreads();
#pragma unroll
      for (int i = 0; i < 8; ++i)
        vals[i] = rsc[i] + rsc[8 + i] + rsc[16 + i] + rsc[24 + i];
      __syncthreads();
      const float m0 = vals[0] * (1.f / 1024), m1 = vals[1] * (1.f / 1024);
      const float m2 = vals[2] * (1.f / 1024), m3 = vals[3] * (1.f / 1024);
      const float r0 = rsqrtf(vals[4] * (1.f / 1024) - m0 * m0 + EPS_);
      const float r1 = rsqrtf(vals[5] * (1.f / 1024) - m1 * m1 + EPS_);
      const float r2 = rsqrtf(vals[6] * (1.f / 1024) - m2 * m2 + EPS_);
      const float r3 = rsqrtf(vals[7] * (1.f / 1024) - m3 * m3 + EPS_);

      float nc[4], oo[4];
      float cs = 0.f, cq = 0.f;
#pragma unroll
      for (int u = 0; u < 4; ++u) {
        const int e = tid + u * 256;
        const float xi = lng[e] * ((iv[u] - m0) * r0) + lnb[e];
        const float xj = lng[1024 + e] * ((jv[u] - m1) * r1) + lnb[1024 + e];
        const float xf = lng[2048 + e] * ((fv[u] - m2) * r2) + lnb[2048 + e];
        const float xo = lng[3072 + e] * ((ov[u] - m3) * r3) + lnb[3072 + e];
        const float ncv = crow[e] * sigm(xf + FB_) + sigm(xi) * tanhf(xj);
        nc[u] = ncv; oo[u] = xo;
        cs += ncv; cq += ncv * ncv;
      }
      {
        float x = cs, y = cq;
        for (int off = 32; off > 0; off >>= 1) { x += __shfl_down(x, off); y += __shfl_down(y, off); }
        if (lane == 0) { rsc[w * 2] = x; rsc[w * 2 + 1] = y; }
      }
      __syncthreads();
      cs = rsc[0] + rsc[2] + rsc[4] + rsc[6];
      cq = rsc[1] + rsc[3] + rsc[5] + rsc[7];
      const float mc = cs * (1.f / 1024);
      const float rc = rsqrtf(cq * (1.f / 1024) - mc * mc + EPS_);
#pragma unroll
      for (int u = 0; u < 4; ++u) {
        const int e = tid + u * 256;
        crow[e] = nc[u];
        const float nh = tanhf(lng[4096 + e] * ((nc[u] - mc) * rc) + lnb[4096 + e]) * sigm(oo[u]);
        Hout[((size_t)(b * T_ + t)) * H_ + e] = f2bf(nh);
      }
    }
    cbar(bars, g);
  }
}

// ---------------------------------------------------------------- per-row logsumexp
__global__ __launch_bounds__(256)
void k_lse(const float* __restrict__ logits, float* __restrict__ lse) {
  __shared__ float rm[4];
  __shared__ float rs[4];
  const int r = blockIdx.x, tid = threadIdx.x;
  const float* row = logits + (size_t)r * V_;
  float mx = -1e30f;
  for (int e = tid; e < V_; e += 256) mx = fmaxf(mx, row[e]);
  for (int off = 32; off > 0; off >>= 1) mx = fmaxf(mx, __shfl_down(mx, off));
  if ((tid & 63) == 0) rm[tid >> 6] = mx;
  __syncthreads();
  mx = fmaxf(fmaxf(rm[0], rm[1]), fmaxf(rm[2], rm[3]));
  float s = 0.f;
  for (int e = tid; e < V_; e += 256) s += expf(row[e] - mx);
  for (int off = 32; off > 0; off >>= 1) s += __shfl_down(s, off);
  if ((tid & 63) == 0) rs[tid >> 6] = s;
  __syncthreads();
  if (tid == 0) lse[r] = mx + logf(rs[0] + rs[1] + rs[2] + rs[3]);
}

// ---------------------------------------------------------------- loss (mean NLL)
__global__ __launch_bounds__(256)
void k_loss(const float* __restrict__ logits, const float* __restrict__ lse,
            const int* __restrict__ tgt, float* __restrict__ out) {
  __shared__ float rsc[4];
  const int tid = threadIdx.x;
  float s = 0.f;
  for (int r = tid; r < BT_; r += 256)
    s += lse[r] - logits[(size_t)r * V_ + tgt[r]];
  for (int off = 32; off > 0; off >>= 1) s += __shfl_down(s, off);
  if ((tid & 63) == 0) rsc[tid >> 6] = s;
  __syncthreads();
  if (tid == 0) out[(size_t)BT_ * V_] = (rsc[0] + rsc[1] + rsc[2] + rsc[3]) / (float)BT_;
}

// ================================================================ launch
extern "C" void kernel_launch(void* const* d_in, const int* in_sizes, int n_in,
                              void* d_out, int out_size, void* d_ws, size_t ws_size,
                              hipStream_t stream) {
  const int*   ids  = (const int*)d_in[0];
  const int*   tgt  = (const int*)d_in[1];
  const float* emb  = (const float*)d_in[2];
  const float* W    = (const float*)d_in[3];   // [2][2048][4096]
  const float* brnn = (const float*)d_in[4];   // [2][4096]
  const float* lng  = (const float*)d_in[5];   // [2][5][1024]
  const float* lnb  = (const float*)d_in[6];
  const float* sw   = (const float*)d_in[7];   // [1024][32000]
  const float* sb   = (const float*)d_in[8];   // [32000]
  float* out = (float*)d_out;

  char* ws = (char*)d_ws;
  size_t o = 0;
  auto take = [&](size_t n) { char* p = ws + o; o += (n + 255) & ~(size_t)255; return p; };
  unsigned short* WxT0 = (unsigned short*)take((size_t)G4H_ * H_ * 2);
  unsigned short* WhT0 = (unsigned short*)take((size_t)G4H_ * H_ * 2);
  unsigned short* WxT1 = (unsigned short*)take((size_t)G4H_ * H_ * 2);
  unsigned short* WhT1 = (unsigned short*)take((size_t)G4H_ * H_ * 2);
  unsigned short* WsT  = (unsigned short*)take((size_t)V_ * H_ * 2);
  unsigned short* Xemb = (unsigned short*)take((size_t)BT_ * H_ * 2);
  float*          Gbuf = (float*)take((size_t)BT_ * G4H_ * 4);
  unsigned short* Hb0  = (unsigned short*)take((size_t)BT_ * H_ * 2);
  unsigned short* Hb1  = (unsigned short*)take((size_t)BT_ * H_ * 2);
  float*          gf   = (float*)take((size_t)32 * G4H_ * 4);
  float*          lseb = (float*)take((size_t)BT_ * 4);
  unsigned*       bars = (unsigned*)take(16384);

  // zero the barrier slots before EACH cooperative launch (generation word is
  // monotonic within one kernel run; second launch must restart at 0)
  hipMemsetAsync(bars, 0, 16384, stream);

  const dim3 tb(32, 8);
  // weight transposes + bf16 cast: W[l] rows 0..1023 = Wx, rows 1024..2047 = Wh
  k_transpose_cast<<<dim3(128, 32),  tb, 0, stream>>>(W,                    WxT0, 1024, 4096, 4096);
  k_transpose_cast<<<dim3(128, 32),  tb, 0, stream>>>(W + 1024 * 4096,      WhT0, 1024, 4096, 4096);
  k_transpose_cast<<<dim3(128, 32),  tb, 0, stream>>>(W + 2048 * 4096,      WxT1, 1024, 4096, 4096);
  k_transpose_cast<<<dim3(128, 32),  tb, 0, stream>>>(W + 3072 * 4096,      WhT1, 1024, 4096, 4096);
  k_transpose_cast<<<dim3(1000, 32), tb, 0, stream>>>(sw,                   WsT,  1024, V_,  V_);

  k_gather<<<BT_, 256, 0, stream>>>(ids, emb, Xemb);

  // layer 0
  k_gemm_bt<<<dim3(32, 32), 256, 0, stream>>>(Xemb, WxT0, brnn, Gbuf, BT_, G4H_, H_);
  {
    const float* G_ = Gbuf; const unsigned short* Wh_ = WhT0;
    const float* g_ = lng;  const float* b_ = lnb;
    float* gf_ = gf; unsigned short* Ho_ = Hb0; unsigned* bars_ = bars;
    void* args[] = {&G_, &Wh_, &g_, &b_, &gf_, &Ho_, &bars_};
    hipLaunchCooperativeKernel((void*)k_lstm, dim3(256), dim3(256), args, 0, stream);
  }
  // re-zero barrier state for the second cooperative launch
  hipMemsetAsync(bars, 0, 16384, stream);

  // layer 1
  k_gemm_bt<<<dim3(32, 32), 256, 0, stream>>>(Hb0, WxT1, brnn + 4096, Gbuf, BT_, G4H_, H_);
  {
    const float* G_ = Gbuf; const unsigned short* Wh_ = WhT1;
    const float* g_ = lng + 5120; const float* b_ = lnb + 5120;
    float* gf_ = gf; unsigned short* Ho_ = Hb1; unsigned* bars_ = bars;
    void* args[] = {&G_, &Wh_, &g_, &b_, &gf_, &Ho_, &bars_};
    hipLaunchCooperativeKernel((void*)k_lstm, dim3(256), dim3(256), args, 0, stream);
  }

  // projection -> logits (d_out) ; then logsumexp + loss
  k_gemm_bt<<<dim3(250, 32), 256, 0, stream>>>(Hb1, WsT, sb, out, BT_, V_, H_);
  k_lse<<<BT_, 256, 0, stream>>>(out, lseb);
  k_loss<<<1, 256, 0, stream>>>(out, lseb, tgt, out);
}

// Round 5
// 6250.058 us; speedup vs baseline: 2.8339x; 1.0717x over previous
//
#include <hip/hip_runtime.h>
#include <hip/hip_cooperative_groups.h>

#define V_    32000
#define B_    32
#define T_    128
#define H_    1024
#define BT_   4096     // B_*T_
#define G4H_  4096     // 4*H_
#define EPS_  1e-5f
#define FB_   1.0f     // forget bias

typedef __bf16  bf16x8 __attribute__((ext_vector_type(8)));
typedef float   f32x4  __attribute__((ext_vector_type(4)));
typedef short   short8 __attribute__((ext_vector_type(8)));

__device__ __forceinline__ unsigned short f2bf(float f) {
  unsigned u = __builtin_bit_cast(unsigned, f);
  u = u + 0x7FFFu + ((u >> 16) & 1u);          // round-to-nearest-even
  return (unsigned short)(u >> 16);
}
__device__ __forceinline__ float sigm(float x) { return 1.0f / (1.0f + expf(-x)); }

// ---------------------------------------------------------------- dataflow flag sync
// flags layout (unsigned words, 64B-padded slots):
//   flag_g[j] at flags[16*j],        j = 0..255   (gf slice j ready, stamped t+1)
//   flag_h[b] at flags[4096 + 16*b], b = 0..31    (h row b ready,   stamped t+1)
// Monotonic within one launch; host zeroes before each cooperative launch.
// Producer: __syncthreads (drains all waves' stores to L2) -> tid0 release store
// (emits vmcnt wait + L2 writeback -> LLC). Consumer: wave 0 spins relaxed on the
// padded slots (lane-parallel), then acquire fence (L1/L2 inv; caches shared by
// the whole block at 1 block/CU) -> __syncthreads releases all waves.
__device__ __forceinline__ void wait_flags(unsigned* flags, int nslots, unsigned tgt) {
  const int lane = threadIdx.x & 63;
  for (;;) {
    unsigned v = 0xFFFFFFFFu;
    for (int s = lane; s < nslots; s += 64) {
      const unsigned x = __hip_atomic_load(&flags[16 * s], __ATOMIC_RELAXED, __HIP_MEMORY_SCOPE_AGENT);
      v = x < v ? x : v;
    }
    if (__all((int)(v >= tgt))) break;
    __builtin_amdgcn_s_sleep(1);
  }
}

// ---------------------------------------------------------------- transpose+cast
__global__ void k_transpose_cast(const float* __restrict__ in, unsigned short* __restrict__ out,
                                 int R, int C, int ldin) {
  __shared__ float tl[32][33];
  const int tx = threadIdx.x, ty = threadIdx.y;
  const int r0 = blockIdx.y * 32, c0 = blockIdx.x * 32;
#pragma unroll
  for (int i = 0; i < 4; ++i)
    tl[ty + 8 * i][tx] = in[(size_t)(r0 + ty + 8 * i) * ldin + c0 + tx];
  __syncthreads();
#pragma unroll
  for (int i = 0; i < 4; ++i)
    out[(size_t)(c0 + ty + 8 * i) * R + r0 + tx] = f2bf(tl[tx][ty + 8 * i]);
}

// ---------------------------------------------------------------- embedding gather
__global__ void k_gather(const int* __restrict__ ids, const float* __restrict__ emb,
                         unsigned short* __restrict__ x) {
  const int r = blockIdx.x;
  const int t4 = threadIdx.x * 4;
  const int row = ids[r];
  const float4 v = *(const float4*)&emb[(size_t)row * H_ + t4];
  ushort4 o;
  o.x = f2bf(v.x); o.y = f2bf(v.y); o.z = f2bf(v.z); o.w = f2bf(v.w);
  *(ushort4*)&x[(size_t)r * H_ + t4] = o;
}

// ---------------------------------------------------------------- bf16 GEMM, C = A * BT^T + bias
__global__ __launch_bounds__(256)
void k_gemm_bt(const unsigned short* __restrict__ A, const unsigned short* __restrict__ BT,
               const float* __restrict__ bias, float* __restrict__ C,
               int M, int N, int K) {
  __shared__ unsigned short As[128 * 32];
  __shared__ unsigned short Bs[128 * 32];
  const int tid = threadIdx.x;
  const int lane = tid & 63, wid = tid >> 6;
  const int wr = wid >> 1, wc = wid & 1;
  const int la = lane & 15, lb = lane >> 4;
  const int m0 = blockIdx.y * 128, n0 = blockIdx.x * 128;

  f32x4 acc[4][4];
#pragma unroll
  for (int i = 0; i < 4; ++i)
#pragma unroll
    for (int j = 0; j < 4; ++j) acc[i][j] = f32x4{0.f, 0.f, 0.f, 0.f};

  for (int k0 = 0; k0 < K; k0 += 32) {
    __syncthreads();
#pragma unroll
    for (int i = 0; i < 2; ++i) {
      const int off = i * 2048 + tid * 8;
      const int row = off >> 5, col = off & 31;
      *(short8*)&As[off] = *(const short8*)&A[(size_t)(m0 + row) * K + k0 + col];
      *(short8*)&Bs[off] = *(const short8*)&BT[(size_t)(n0 + row) * K + k0 + col];
    }
    __syncthreads();
    bf16x8 a[4], b[4];
#pragma unroll
    for (int mm = 0; mm < 4; ++mm) a[mm] = *(bf16x8*)&As[(wr * 64 + mm * 16 + la) * 32 + lb * 8];
#pragma unroll
    for (int nn = 0; nn < 4; ++nn) b[nn] = *(bf16x8*)&Bs[(wc * 64 + nn * 16 + la) * 32 + lb * 8];
#pragma unroll
    for (int mm = 0; mm < 4; ++mm)
#pragma unroll
      for (int nn = 0; nn < 4; ++nn)
        acc[mm][nn] = __builtin_amdgcn_mfma_f32_16x16x32_bf16(a[mm], b[nn], acc[mm][nn], 0, 0, 0);
  }
#pragma unroll
  for (int mm = 0; mm < 4; ++mm)
#pragma unroll
    for (int nn = 0; nn < 4; ++nn) {
      const int row = m0 + wr * 64 + mm * 16 + lb * 4;
      const int col = n0 + wc * 64 + nn * 16 + la;
      const float bs = bias ? bias[col] : 0.f;
#pragma unroll
      for (int r = 0; r < 4; ++r)
        C[(size_t)(row + r) * N + col] = acc[mm][nn][r] + bs;
    }
}

// ---------------------------------------------------------------- persistent LN-LSTM layer
// Cooperative, grid=256 blocks x 256 threads, 1 block/CU (LDS ~108KB).
// Block j holds WhT cols [16j,16j+16) in LDS for all T steps.
// Per step (dataflow-synced, no global barrier):
//   P1 (all blocks): wait flag_h >= t; stage hs; gf = G[t] + h@Wh; release flag_g[bid]=t+1
//   P2 (blocks 0-31): wait all flag_g >= t+1; LN gates -> pointwise -> cell LN -> h;
//                     release flag_h[bid]=t+1
__global__ __launch_bounds__(256)
void k_lstm(const float* __restrict__ G, const unsigned short* __restrict__ WhT,
            const float* __restrict__ lng, const float* __restrict__ lnb,
            float* __restrict__ gf, unsigned short* __restrict__ Hout,
            unsigned* flags) {
  __shared__ unsigned short wh[16 * 1024];   // [col][k]
  __shared__ unsigned short hs[32 * 1024];   // [b][k] bf16
  __shared__ float crow[1024];               // cell state for row bid (blocks 0..31)
  __shared__ float red[4][32][16];           // cross-wave partials
  __shared__ float rsc[64];

  const int tid = threadIdx.x;
  const int bid = blockIdx.x;
  const int lane = tid & 63, w = tid >> 6;
  const int la = lane & 15, lb = lane >> 4;
  unsigned* flag_g = flags;                  // 256 slots
  unsigned* flag_h = flags + 4096;           // 32 slots

  for (int i = tid * 8; i < 16 * 1024; i += 2048)
    *(short8*)&wh[i] = *(const short8*)&WhT[(size_t)bid * 16384 + i];
  if (bid < 32)
    for (int e = tid; e < 1024; e += 256) crow[e] = 0.0f;

  for (int t = 0; t < T_; ++t) {
    // ---- wait for h(t-1), then stage it (bf16 [32][1024])
    if (t == 0) {
      const short8 z = {0, 0, 0, 0, 0, 0, 0, 0};
      for (int i = tid * 8; i < 32 * 1024; i += 2048) *(short8*)&hs[i] = z;
    } else {
      if (w == 0) {
        wait_flags(flag_h, 32, (unsigned)t);
        __builtin_amdgcn_fence(__ATOMIC_ACQUIRE, "agent");
      }
      __syncthreads();
      for (int i = tid * 8; i < 32 * 1024; i += 2048) {
        const int b = i >> 10, k = i & 1023;
        *(short8*)&hs[i] = *(const short8*)&Hout[((size_t)(b * T_ + (t - 1))) * H_ + k];
      }
    }
    __syncthreads();

    // ---- phase 1: recurrent matmul, wave w covers k in [256w, 256w+256)
    f32x4 acc0 = {0.f, 0.f, 0.f, 0.f}, acc1 = {0.f, 0.f, 0.f, 0.f};
#pragma unroll
    for (int kk = 0; kk < 8; ++kk) {
      const int k = w * 256 + kk * 32 + lb * 8;
      const bf16x8 bv = *(bf16x8*)&wh[la * 1024 + k];
      const bf16x8 a0 = *(bf16x8*)&hs[la * 1024 + k];
      const bf16x8 a1 = *(bf16x8*)&hs[(16 + la) * 1024 + k];
      acc0 = __builtin_amdgcn_mfma_f32_16x16x32_bf16(a0, bv, acc0, 0, 0, 0);
      acc1 = __builtin_amdgcn_mfma_f32_16x16x32_bf16(a1, bv, acc1, 0, 0, 0);
    }
#pragma unroll
    for (int r = 0; r < 4; ++r) {
      red[w][lb * 4 + r][la] = acc0[r];
      red[w][16 + lb * 4 + r][la] = acc1[r];
    }
    __syncthreads();
    for (int o = tid; o < 512; o += 256) {
      const int b = o >> 4, c = o & 15;
      const float s = red[0][b][c] + red[1][b][c] + red[2][b][c] + red[3][b][c];
      gf[b * G4H_ + bid * 16 + c] = s + G[((size_t)(b * T_ + t)) * G4H_ + bid * 16 + c];
    }
    __syncthreads();                         // drain all waves' gf stores (vmcnt0/wave)
    if (tid == 0)
      __hip_atomic_store(&flag_g[16 * bid], (unsigned)(t + 1), __ATOMIC_RELEASE, __HIP_MEMORY_SCOPE_AGENT);

    // ---- phase 2: LN + pointwise, block b < 32 handles batch row b
    if (bid < 32) {
      if (w == 0) {
        wait_flags(flag_g, 256, (unsigned)(t + 1));
        __builtin_amdgcn_fence(__ATOMIC_ACQUIRE, "agent");
      }
      __syncthreads();
      const int b = bid;
      float iv[4], jv[4], fv[4], ov[4];
      float vals[8] = {0, 0, 0, 0, 0, 0, 0, 0};
#pragma unroll
      for (int u = 0; u < 4; ++u) {
        const int e = tid + u * 256;
        iv[u] = gf[b * G4H_ + e];
        jv[u] = gf[b * G4H_ + 1024 + e];
        fv[u] = gf[b * G4H_ + 2048 + e];
        ov[u] = gf[b * G4H_ + 3072 + e];
        vals[0] += iv[u]; vals[4] += iv[u] * iv[u];
        vals[1] += jv[u]; vals[5] += jv[u] * jv[u];
        vals[2] += fv[u]; vals[6] += fv[u] * fv[u];
        vals[3] += ov[u]; vals[7] += ov[u] * ov[u];
      }
#pragma unroll
      for (int i = 0; i < 8; ++i) {
        float x = vals[i];
        for (int off = 32; off > 0; off >>= 1) x += __shfl_down(x, off);
        if (lane == 0) rsc[w * 8 + i] = x;
      }
      __syncthreads();
#pragma unroll
      for (int i = 0; i < 8; ++i)
        vals[i] = rsc[i] + rsc[8 + i] + rsc[16 + i] + rsc[24 + i];
      __syncthreads();
      const float m0 = vals[0] * (1.f / 1024), m1 = vals[1] * (1.f / 1024);
      const float m2 = vals[2] * (1.f / 1024), m3 = vals[3] * (1.f / 1024);
      const float r0 = rsqrtf(vals[4] * (1.f / 1024) - m0 * m0 + EPS_);
      const float r1 = rsqrtf(vals[5] * (1.f / 1024) - m1 * m1 + EPS_);
      const float r2 = rsqrtf(vals[6] * (1.f / 1024) - m2 * m2 + EPS_);
      const float r3 = rsqrtf(vals[7] * (1.f / 1024) - m3 * m3 + EPS_);

      float nc[4], oo[4];
      float cs = 0.f, cq = 0.f;
#pragma unroll
      for (int u = 0; u < 4; ++u) {
        const int e = tid + u * 256;
        const float xi = lng[e] * ((iv[u] - m0) * r0) + lnb[e];
        const float xj = lng[1024 + e] * ((jv[u] - m1) * r1) + lnb[1024 + e];
        const float xf = lng[2048 + e] * ((fv[u] - m2) * r2) + lnb[2048 + e];
        const float xo = lng[3072 + e] * ((ov[u] - m3) * r3) + lnb[3072 + e];
        const float ncv = crow[e] * sigm(xf + FB_) + sigm(xi) * tanhf(xj);
        nc[u] = ncv; oo[u] = xo;
        cs += ncv; cq += ncv * ncv;
      }
      {
        float x = cs, y = cq;
        for (int off = 32; off > 0; off >>= 1) { x += __shfl_down(x, off); y += __shfl_down(y, off); }
        if (lane == 0) { rsc[w * 2] = x; rsc[w * 2 + 1] = y; }
      }
      __syncthreads();
      cs = rsc[0] + rsc[2] + rsc[4] + rsc[6];
      cq = rsc[1] + rsc[3] + rsc[5] + rsc[7];
      const float mc = cs * (1.f / 1024);
      const float rc = rsqrtf(cq * (1.f / 1024) - mc * mc + EPS_);
#pragma unroll
      for (int u = 0; u < 4; ++u) {
        const int e = tid + u * 256;
        crow[e] = nc[u];
        const float nh = tanhf(lng[4096 + e] * ((nc[u] - mc) * rc) + lnb[4096 + e]) * sigm(oo[u]);
        Hout[((size_t)(b * T_ + t)) * H_ + e] = f2bf(nh);
      }
      __syncthreads();                       // drain Hout stores
      if (tid == 0)
        __hip_atomic_store(&flag_h[16 * bid], (unsigned)(t + 1), __ATOMIC_RELEASE, __HIP_MEMORY_SCOPE_AGENT);
    }
  }
}

// ---------------------------------------------------------------- per-row logsumexp
__global__ __launch_bounds__(256)
void k_lse(const float* __restrict__ logits, float* __restrict__ lse) {
  __shared__ float rm[4];
  __shared__ float rs[4];
  const int r = blockIdx.x, tid = threadIdx.x;
  const float* row = logits + (size_t)r * V_;
  float mx = -1e30f;
  for (int e = tid; e < V_; e += 256) mx = fmaxf(mx, row[e]);
  for (int off = 32; off > 0; off >>= 1) mx = fmaxf(mx, __shfl_down(mx, off));
  if ((tid & 63) == 0) rm[tid >> 6] = mx;
  __syncthreads();
  mx = fmaxf(fmaxf(rm[0], rm[1]), fmaxf(rm[2], rm[3]));
  float s = 0.f;
  for (int e = tid; e < V_; e += 256) s += expf(row[e] - mx);
  for (int off = 32; off > 0; off >>= 1) s += __shfl_down(s, off);
  if ((tid & 63) == 0) rs[tid >> 6] = s;
  __syncthreads();
  if (tid == 0) lse[r] = mx + logf(rs[0] + rs[1] + rs[2] + rs[3]);
}

// ---------------------------------------------------------------- loss (mean NLL)
__global__ __launch_bounds__(256)
void k_loss(const float* __restrict__ logits, const float* __restrict__ lse,
            const int* __restrict__ tgt, float* __restrict__ out) {
  __shared__ float rsc[4];
  const int tid = threadIdx.x;
  float s = 0.f;
  for (int r = tid; r < BT_; r += 256)
    s += lse[r] - logits[(size_t)r * V_ + tgt[r]];
  for (int off = 32; off > 0; off >>= 1) s += __shfl_down(s, off);
  if ((tid & 63) == 0) rsc[tid >> 6] = s;
  __syncthreads();
  if (tid == 0) out[(size_t)BT_ * V_] = (rsc[0] + rsc[1] + rsc[2] + rsc[3]) / (float)BT_;
}

// ================================================================ launch
extern "C" void kernel_launch(void* const* d_in, const int* in_sizes, int n_in,
                              void* d_out, int out_size, void* d_ws, size_t ws_size,
                              hipStream_t stream) {
  const int*   ids  = (const int*)d_in[0];
  const int*   tgt  = (const int*)d_in[1];
  const float* emb  = (const float*)d_in[2];
  const float* W    = (const float*)d_in[3];   // [2][2048][4096]
  const float* brnn = (const float*)d_in[4];   // [2][4096]
  const float* lng  = (const float*)d_in[5];   // [2][5][1024]
  const float* lnb  = (const float*)d_in[6];
  const float* sw   = (const float*)d_in[7];   // [1024][32000]
  const float* sb   = (const float*)d_in[8];   // [32000]
  float* out = (float*)d_out;

  char* ws = (char*)d_ws;
  size_t o = 0;
  auto take = [&](size_t n) { char* p = ws + o; o += (n + 255) & ~(size_t)255; return p; };
  unsigned short* WxT0 = (unsigned short*)take((size_t)G4H_ * H_ * 2);
  unsigned short* WhT0 = (unsigned short*)take((size_t)G4H_ * H_ * 2);
  unsigned short* WxT1 = (unsigned short*)take((size_t)G4H_ * H_ * 2);
  unsigned short* WhT1 = (unsigned short*)take((size_t)G4H_ * H_ * 2);
  unsigned short* WsT  = (unsigned short*)take((size_t)V_ * H_ * 2);
  unsigned short* Xemb = (unsigned short*)take((size_t)BT_ * H_ * 2);
  float*          Gbuf = (float*)take((size_t)BT_ * G4H_ * 4);
  unsigned short* Hb0  = (unsigned short*)take((size_t)BT_ * H_ * 2);
  unsigned short* Hb1  = (unsigned short*)take((size_t)BT_ * H_ * 2);
  float*          gf   = (float*)take((size_t)32 * G4H_ * 4);
  float*          lseb = (float*)take((size_t)BT_ * 4);
  unsigned*       bars = (unsigned*)take(32768);

  // zero the flag slots before EACH cooperative launch (stamps are monotonic
  // within one kernel run; each launch must restart at 0)
  hipMemsetAsync(bars, 0, 32768, stream);

  const dim3 tb(32, 8);
  // weight transposes + bf16 cast: W[l] rows 0..1023 = Wx, rows 1024..2047 = Wh
  k_transpose_cast<<<dim3(128, 32),  tb, 0, stream>>>(W,                    WxT0, 1024, 4096, 4096);
  k_transpose_cast<<<dim3(128, 32),  tb, 0, stream>>>(W + 1024 * 4096,      WhT0, 1024, 4096, 4096);
  k_transpose_cast<<<dim3(128, 32),  tb, 0, stream>>>(W + 2048 * 4096,      WxT1, 1024, 4096, 4096);
  k_transpose_cast<<<dim3(128, 32),  tb, 0, stream>>>(W + 3072 * 4096,      WhT1, 1024, 4096, 4096);
  k_transpose_cast<<<dim3(1000, 32), tb, 0, stream>>>(sw,                   WsT,  1024, V_,  V_);

  k_gather<<<BT_, 256, 0, stream>>>(ids, emb, Xemb);

  // layer 0
  k_gemm_bt<<<dim3(32, 32), 256, 0, stream>>>(Xemb, WxT0, brnn, Gbuf, BT_, G4H_, H_);
  {
    const float* G_ = Gbuf; const unsigned short* Wh_ = WhT0;
    const float* g_ = lng;  const float* b_ = lnb;
    float* gf_ = gf; unsigned short* Ho_ = Hb0; unsigned* bars_ = bars;
    void* args[] = {&G_, &Wh_, &g_, &b_, &gf_, &Ho_, &bars_};
    hipLaunchCooperativeKernel((void*)k_lstm, dim3(256), dim3(256), args, 0, stream);
  }
  // re-zero flag state for the second cooperative launch
  hipMemsetAsync(bars, 0, 32768, stream);

  // layer 1
  k_gemm_bt<<<dim3(32, 32), 256, 0, stream>>>(Hb0, WxT1, brnn + 4096, Gbuf, BT_, G4H_, H_);
  {
    const float* G_ = Gbuf; const unsigned short* Wh_ = WhT1;
    const float* g_ = lng + 5120; const float* b_ = lnb + 5120;
    float* gf_ = gf; unsigned short* Ho_ = Hb1; unsigned* bars_ = bars;
    void* args[] = {&G_, &Wh_, &g_, &b_, &gf_, &Ho_, &bars_};
    hipLaunchCooperativeKernel((void*)k_lstm, dim3(256), dim3(256), args, 0, stream);
  }

  // projection -> logits (d_out) ; then logsumexp + loss
  k_gemm_bt<<<dim3(250, 32), 256, 0, stream>>>(Hb1, WsT, sb, out, BT_, V_, H_);
  k_lse<<<BT_, 256, 0, stream>>>(out, lseb);
  k_loss<<<1, 256, 0, stream>>>(out, lseb, tgt, out);
}

// Round 6
// 3405.858 us; speedup vs baseline: 5.2005x; 1.8351x over previous
//
#include <hip/hip_runtime.h>
#include <hip/hip_cooperative_groups.h>

#define V_    32000
#define B_    32
#define T_    128
#define H_    1024
#define BT_   4096     // B_*T_
#define G4H_  4096     // 4*H_
#define EPS_  1e-5f
#define FB_   1.0f     // forget bias

typedef __bf16  bf16x8 __attribute__((ext_vector_type(8)));
typedef float   f32x4  __attribute__((ext_vector_type(4)));
typedef float   f32x2  __attribute__((ext_vector_type(2)));
typedef unsigned u32x2 __attribute__((ext_vector_type(2)));
typedef short   short8 __attribute__((ext_vector_type(8)));

__device__ __forceinline__ unsigned short f2bf(float f) {
  unsigned u = __builtin_bit_cast(unsigned, f);
  u = u + 0x7FFFu + ((u >> 16) & 1u);          // round-to-nearest-even
  return (unsigned short)(u >> 16);
}
__device__ __forceinline__ float sigm(float x) { return 1.0f / (1.0f + expf(-x)); }

// ---------------------------------------------------------------- LLC-coherent access
// sc0 sc1 loads/stores bypass L1+L2 and are served at the shared Infinity Cache,
// so cross-XCD producer/consumer needs NO buffer_wbl2/buffer_inv fences: producer
// drains vmcnt (sc-stores acked at LLC) via __syncthreads, then a relaxed agent
// flag store; consumer spins on the flag and sc-loads the data. Read-only data
// (G, lng, lnb, weights) keeps normal cached loads and stays L1/L2-resident.
__device__ __forceinline__ short8 ldg_coh16(const unsigned short* p) {
  short8 v;
  asm volatile("global_load_dwordx4 %0, %1, off sc0 sc1" : "=v"(v) : "v"(p) : "memory");
  return v;
}
__device__ __forceinline__ f32x4 ldg_coh16f(const float* p) {
  f32x4 v;
  asm volatile("global_load_dwordx4 %0, %1, off sc0 sc1" : "=v"(v) : "v"(p) : "memory");
  return v;
}
__device__ __forceinline__ void stg_coh8f(float* p, f32x2 v) {
  asm volatile("global_store_dwordx2 %0, %1, off sc0 sc1" :: "v"(p), "v"(v) : "memory");
}
__device__ __forceinline__ void stg_coh8u(unsigned short* p, u32x2 v) {
  asm volatile("global_store_dwordx2 %0, %1, off sc0 sc1" :: "v"(p), "v"(v) : "memory");
}
__device__ __forceinline__ void vmwait0() {
  asm volatile("s_waitcnt vmcnt(0)" ::: "memory");
  __builtin_amdgcn_sched_barrier(0);           // rule #18: pin consumers after the wait
}

// ---------------------------------------------------------------- dataflow flag sync
// flag_g[j] at flags[16*j] (j<256); flag_h[b] at flags[4096+16*b] (b<32).
// Stamps are monotonic within a launch; host zeroes before each cooperative launch.
__device__ __forceinline__ void wait_flags(unsigned* flags, int nslots, unsigned tgt) {
  const int lane = threadIdx.x & 63;
  for (;;) {
    unsigned v = 0xFFFFFFFFu;
    for (int s = lane; s < nslots; s += 64) {
      const unsigned x = __hip_atomic_load(&flags[16 * s], __ATOMIC_RELAXED, __HIP_MEMORY_SCOPE_AGENT);
      v = x < v ? x : v;
    }
    if (__all((int)(v >= tgt))) break;
    __builtin_amdgcn_s_sleep(1);
  }
}

// ---------------------------------------------------------------- transpose+cast
__global__ void k_transpose_cast(const float* __restrict__ in, unsigned short* __restrict__ out,
                                 int R, int C, int ldin) {
  __shared__ float tl[32][33];
  const int tx = threadIdx.x, ty = threadIdx.y;
  const int r0 = blockIdx.y * 32, c0 = blockIdx.x * 32;
#pragma unroll
  for (int i = 0; i < 4; ++i)
    tl[ty + 8 * i][tx] = in[(size_t)(r0 + ty + 8 * i) * ldin + c0 + tx];
  __syncthreads();
#pragma unroll
  for (int i = 0; i < 4; ++i)
    out[(size_t)(c0 + ty + 8 * i) * R + r0 + tx] = f2bf(tl[tx][ty + 8 * i]);
}

// ---------------------------------------------------------------- embedding gather
__global__ void k_gather(const int* __restrict__ ids, const float* __restrict__ emb,
                         unsigned short* __restrict__ x) {
  const int r = blockIdx.x;
  const int t4 = threadIdx.x * 4;
  const int row = ids[r];
  const float4 v = *(const float4*)&emb[(size_t)row * H_ + t4];
  ushort4 o;
  o.x = f2bf(v.x); o.y = f2bf(v.y); o.z = f2bf(v.z); o.w = f2bf(v.w);
  *(ushort4*)&x[(size_t)r * H_ + t4] = o;
}

// ---------------------------------------------------------------- bf16 GEMM, C = A * BT^T + bias
__global__ __launch_bounds__(256)
void k_gemm_bt(const unsigned short* __restrict__ A, const unsigned short* __restrict__ BT,
               const float* __restrict__ bias, float* __restrict__ C,
               int M, int N, int K) {
  __shared__ unsigned short As[128 * 32];
  __shared__ unsigned short Bs[128 * 32];
  const int tid = threadIdx.x;
  const int lane = tid & 63, wid = tid >> 6;
  const int wr = wid >> 1, wc = wid & 1;
  const int la = lane & 15, lb = lane >> 4;
  const int m0 = blockIdx.y * 128, n0 = blockIdx.x * 128;

  f32x4 acc[4][4];
#pragma unroll
  for (int i = 0; i < 4; ++i)
#pragma unroll
    for (int j = 0; j < 4; ++j) acc[i][j] = f32x4{0.f, 0.f, 0.f, 0.f};

  for (int k0 = 0; k0 < K; k0 += 32) {
    __syncthreads();
#pragma unroll
    for (int i = 0; i < 2; ++i) {
      const int off = i * 2048 + tid * 8;
      const int row = off >> 5, col = off & 31;
      *(short8*)&As[off] = *(const short8*)&A[(size_t)(m0 + row) * K + k0 + col];
      *(short8*)&Bs[off] = *(const short8*)&BT[(size_t)(n0 + row) * K + k0 + col];
    }
    __syncthreads();
    bf16x8 a[4], b[4];
#pragma unroll
    for (int mm = 0; mm < 4; ++mm) a[mm] = *(bf16x8*)&As[(wr * 64 + mm * 16 + la) * 32 + lb * 8];
#pragma unroll
    for (int nn = 0; nn < 4; ++nn) b[nn] = *(bf16x8*)&Bs[(wc * 64 + nn * 16 + la) * 32 + lb * 8];
#pragma unroll
    for (int mm = 0; mm < 4; ++mm)
#pragma unroll
      for (int nn = 0; nn < 4; ++nn)
        acc[mm][nn] = __builtin_amdgcn_mfma_f32_16x16x32_bf16(a[mm], b[nn], acc[mm][nn], 0, 0, 0);
  }
#pragma unroll
  for (int mm = 0; mm < 4; ++mm)
#pragma unroll
    for (int nn = 0; nn < 4; ++nn) {
      const int row = m0 + wr * 64 + mm * 16 + lb * 4;
      const int col = n0 + wc * 64 + nn * 16 + la;
      const float bs = bias ? bias[col] : 0.f;
#pragma unroll
      for (int r = 0; r < 4; ++r)
        C[(size_t)(row + r) * N + col] = acc[mm][nn][r] + bs;
    }
}

// ---------------------------------------------------------------- persistent LN-LSTM layer
// Cooperative, grid=256 blocks x 256 threads, 1 block/CU (LDS ~108KB).
// Block j holds WhT cols [16j,16j+16) in LDS (XOR-swizzled rows) for all T steps.
// Per step (dataflow-synced, fence-free; all mutable data via sc0sc1 LLC ops):
//   P1 (all blocks): wait flag_h >= t; sc-load h -> LDS (swizzled); gf = G[t] + h@Wh
//                    (sc-store); syncthreads (drain); flag_g[bid]=t+1
//   P2 (blocks 0-31): wait all flag_g >= t+1; sc-load gf; LN gates -> pointwise ->
//                    cell LN -> h (sc-store); syncthreads; flag_h[bid]=t+1
__global__ __launch_bounds__(256)
void k_lstm(const float* __restrict__ G, const unsigned short* __restrict__ WhT,
            const float* __restrict__ lng, const float* __restrict__ lnb,
            float* __restrict__ gf, unsigned short* __restrict__ Hout,
            unsigned* flags) {
  __shared__ unsigned short wh[16 * 1024];   // [col][k^((col&7)<<3)]
  __shared__ unsigned short hs[32 * 1024];   // [b][k^((b&7)<<3)] bf16
  __shared__ float crow[1024];               // cell state for row bid (blocks 0..31)
  __shared__ float red[4][32][16];           // cross-wave partials
  __shared__ float rsc[64];

  const int tid = threadIdx.x;
  const int bid = blockIdx.x;
  const int lane = tid & 63, w = tid >> 6;
  const int la = lane & 15, lb = lane >> 4;
  unsigned* flag_g = flags;                  // 256 slots
  unsigned* flag_h = flags + 4096;           // 32 slots

  // stage weights (swizzled rows to kill the 2048B-stride 16-way bank conflict)
  for (int i = tid * 8; i < 16 * 1024; i += 2048) {
    const int cl = i >> 10, k = i & 1023;
    *(short8*)&wh[cl * 1024 + (k ^ ((cl & 7) << 3))] = *(const short8*)&WhT[(size_t)bid * 16384 + i];
  }
  if (bid < 32)
    for (int e = tid; e < 1024; e += 256) crow[e] = 0.0f;

  for (int t = 0; t < T_; ++t) {
    // ---- wait for h(t-1), then stage it (bf16 [32][1024], swizzled)
    if (t == 0) {
      const short8 z = {0, 0, 0, 0, 0, 0, 0, 0};
      for (int i = tid * 8; i < 32 * 1024; i += 2048) *(short8*)&hs[i] = z;
    } else {
      if (w == 0) wait_flags(flag_h, 32, (unsigned)t);
      __syncthreads();
      short8 tmp[16];
#pragma unroll
      for (int j = 0; j < 16; ++j) {
        const int i = tid * 8 + j * 2048;
        const int b = i >> 10, k = i & 1023;
        tmp[j] = ldg_coh16(&Hout[((size_t)(b * T_ + (t - 1))) * H_ + k]);
      }
      vmwait0();
#pragma unroll
      for (int j = 0; j < 16; ++j) {
        const int i = tid * 8 + j * 2048;
        const int b = i >> 10, k = i & 1023;
        *(short8*)&hs[b * 1024 + (k ^ ((b & 7) << 3))] = tmp[j];
      }
    }
    __syncthreads();

    // ---- phase 1: recurrent matmul, wave w covers k in [256w, 256w+256)
    f32x4 acc0 = {0.f, 0.f, 0.f, 0.f}, acc1 = {0.f, 0.f, 0.f, 0.f};
#pragma unroll
    for (int kk = 0; kk < 8; ++kk) {
      const int k = w * 256 + kk * 32 + lb * 8;
      const int kx = k ^ ((la & 7) << 3);          // (16+la)&7 == la&7
      const bf16x8 bv = *(bf16x8*)&wh[la * 1024 + kx];
      const bf16x8 a0 = *(bf16x8*)&hs[la * 1024 + kx];
      const bf16x8 a1 = *(bf16x8*)&hs[(16 + la) * 1024 + kx];
      acc0 = __builtin_amdgcn_mfma_f32_16x16x32_bf16(a0, bv, acc0, 0, 0, 0);
      acc1 = __builtin_amdgcn_mfma_f32_16x16x32_bf16(a1, bv, acc1, 0, 0, 0);
    }
#pragma unroll
    for (int r = 0; r < 4; ++r) {
      red[w][lb * 4 + r][la] = acc0[r];
      red[w][16 + lb * 4 + r][la] = acc1[r];
    }
    __syncthreads();
    {
      const int b2 = tid >> 3, c2 = (tid & 7) * 2;   // 32 rows x 8 col-pairs
      f32x2 sv;
      sv.x = red[0][b2][c2]     + red[1][b2][c2]     + red[2][b2][c2]     + red[3][b2][c2]
           + G[((size_t)(b2 * T_ + t)) * G4H_ + bid * 16 + c2];
      sv.y = red[0][b2][c2 + 1] + red[1][b2][c2 + 1] + red[2][b2][c2 + 1] + red[3][b2][c2 + 1]
           + G[((size_t)(b2 * T_ + t)) * G4H_ + bid * 16 + c2 + 1];
      stg_coh8f(&gf[b2 * G4H_ + bid * 16 + c2], sv);
    }
    __syncthreads();                         // drains sc-stores (vmcnt0 per wave) -> at LLC
    if (tid == 0)
      __hip_atomic_store(&flag_g[16 * bid], (unsigned)(t + 1), __ATOMIC_RELAXED, __HIP_MEMORY_SCOPE_AGENT);

    // ---- phase 2: LN + pointwise, block b < 32 handles batch row b
    if (bid < 32) {
      if (w == 0) wait_flags(flag_g, 256, (unsigned)(t + 1));
      __syncthreads();
      const int b = bid;
      const int e0 = tid * 4;                // 4 contiguous elements per thread
      const f32x4 iv = ldg_coh16f(&gf[(size_t)b * G4H_ + e0]);
      const f32x4 jv = ldg_coh16f(&gf[(size_t)b * G4H_ + 1024 + e0]);
      const f32x4 fv = ldg_coh16f(&gf[(size_t)b * G4H_ + 2048 + e0]);
      const f32x4 ov = ldg_coh16f(&gf[(size_t)b * G4H_ + 3072 + e0]);
      vmwait0();

      float vals[8] = {0, 0, 0, 0, 0, 0, 0, 0};
#pragma unroll
      for (int u = 0; u < 4; ++u) {
        vals[0] += iv[u]; vals[4] += iv[u] * iv[u];
        vals[1] += jv[u]; vals[5] += jv[u] * jv[u];
        vals[2] += fv[u]; vals[6] += fv[u] * fv[u];
        vals[3] += ov[u]; vals[7] += ov[u] * ov[u];
      }
#pragma unroll
      for (int i = 0; i < 8; ++i) {
        float x = vals[i];
        for (int off = 32; off > 0; off >>= 1) x += __shfl_down(x, off);
        if (lane == 0) rsc[w * 8 + i] = x;
      }
      __syncthreads();
#pragma unroll
      for (int i = 0; i < 8; ++i)
        vals[i] = rsc[i] + rsc[8 + i] + rsc[16 + i] + rsc[24 + i];
      __syncthreads();
      const float m0 = vals[0] * (1.f / 1024), m1 = vals[1] * (1.f / 1024);
      const float m2 = vals[2] * (1.f / 1024), m3 = vals[3] * (1.f / 1024);
      const float r0 = rsqrtf(vals[4] * (1.f / 1024) - m0 * m0 + EPS_);
      const float r1 = rsqrtf(vals[5] * (1.f / 1024) - m1 * m1 + EPS_);
      const float r2 = rsqrtf(vals[6] * (1.f / 1024) - m2 * m2 + EPS_);
      const float r3 = rsqrtf(vals[7] * (1.f / 1024) - m3 * m3 + EPS_);

      const float4 gI = *(const float4*)&lng[e0];
      const float4 gJ = *(const float4*)&lng[1024 + e0];
      const float4 gF = *(const float4*)&lng[2048 + e0];
      const float4 gO = *(const float4*)&lng[3072 + e0];
      const float4 gC = *(const float4*)&lng[4096 + e0];
      const float4 bI = *(const float4*)&lnb[e0];
      const float4 bJ = *(const float4*)&lnb[1024 + e0];
      const float4 bF = *(const float4*)&lnb[2048 + e0];
      const float4 bO = *(const float4*)&lnb[3072 + e0];
      const float4 bC = *(const float4*)&lnb[4096 + e0];
      const float4 cr = *(const float4*)&crow[e0];

      float nc[4], oo[4];
      float cs = 0.f, cq = 0.f;
      {
        const float gi[4] = {gI.x, gI.y, gI.z, gI.w}, bi[4] = {bI.x, bI.y, bI.z, bI.w};
        const float gj[4] = {gJ.x, gJ.y, gJ.z, gJ.w}, bj[4] = {bJ.x, bJ.y, bJ.z, bJ.w};
        const float gff[4] = {gF.x, gF.y, gF.z, gF.w}, bf[4] = {bF.x, bF.y, bF.z, bF.w};
        const float go[4] = {gO.x, gO.y, gO.z, gO.w}, bo[4] = {bO.x, bO.y, bO.z, bO.w};
        const float cv[4] = {cr.x, cr.y, cr.z, cr.w};
#pragma unroll
        for (int u = 0; u < 4; ++u) {
          const float xi = gi[u] * ((iv[u] - m0) * r0) + bi[u];
          const float xj = gj[u] * ((jv[u] - m1) * r1) + bj[u];
          const float xf = gff[u] * ((fv[u] - m2) * r2) + bf[u];
          const float xo = go[u] * ((ov[u] - m3) * r3) + bo[u];
          const float ncv = cv[u] * sigm(xf + FB_) + sigm(xi) * tanhf(xj);
          nc[u] = ncv; oo[u] = xo;
          cs += ncv; cq += ncv * ncv;
        }
      }
      {
        float x = cs, y = cq;
        for (int off = 32; off > 0; off >>= 1) { x += __shfl_down(x, off); y += __shfl_down(y, off); }
        if (lane == 0) { rsc[w * 2] = x; rsc[w * 2 + 1] = y; }
      }
      __syncthreads();
      cs = rsc[0] + rsc[2] + rsc[4] + rsc[6];
      cq = rsc[1] + rsc[3] + rsc[5] + rsc[7];
      const float mc = cs * (1.f / 1024);
      const float rc = rsqrtf(cq * (1.f / 1024) - mc * mc + EPS_);
      {
        const float gc[4] = {gC.x, gC.y, gC.z, gC.w}, bc[4] = {bC.x, bC.y, bC.z, bC.w};
        unsigned short hb[4];
#pragma unroll
        for (int u = 0; u < 4; ++u) {
          const float nh = tanhf(gc[u] * ((nc[u] - mc) * rc) + bc[u]) * sigm(oo[u]);
          hb[u] = f2bf(nh);
        }
        u32x2 hv;
        hv[0] = (unsigned)hb[0] | ((unsigned)hb[1] << 16);
        hv[1] = (unsigned)hb[2] | ((unsigned)hb[3] << 16);
        stg_coh8u(&Hout[((size_t)(b * T_ + t)) * H_ + e0], hv);
        *(float4*)&crow[e0] = float4{nc[0], nc[1], nc[2], nc[3]};
      }
      __syncthreads();                       // drain Hout sc-stores
      if (tid == 0)
        __hip_atomic_store(&flag_h[16 * bid], (unsigned)(t + 1), __ATOMIC_RELAXED, __HIP_MEMORY_SCOPE_AGENT);
    }
  }
}

// ---------------------------------------------------------------- per-row logsumexp
__global__ __launch_bounds__(256)
void k_lse(const float* __restrict__ logits, float* __restrict__ lse) {
  __shared__ float rm[4];
  __shared__ float rs[4];
  const int r = blockIdx.x, tid = threadIdx.x;
  const float* row = logits + (size_t)r * V_;
  float mx = -1e30f;
  for (int e = tid; e < V_; e += 256) mx = fmaxf(mx, row[e]);
  for (int off = 32; off > 0; off >>= 1) mx = fmaxf(mx, __shfl_down(mx, off));
  if ((tid & 63) == 0) rm[tid >> 6] = mx;
  __syncthreads();
  mx = fmaxf(fmaxf(rm[0], rm[1]), fmaxf(rm[2], rm[3]));
  float s = 0.f;
  for (int e = tid; e < V_; e += 256) s += expf(row[e] - mx);
  for (int off = 32; off > 0; off >>= 1) s += __shfl_down(s, off);
  if ((tid & 63) == 0) rs[tid >> 6] = s;
  __syncthreads();
  if (tid == 0) lse[r] = mx + logf(rs[0] + rs[1] + rs[2] + rs[3]);
}

// ---------------------------------------------------------------- loss (mean NLL)
__global__ __launch_bounds__(256)
void k_loss(const float* __restrict__ logits, const float* __restrict__ lse,
            const int* __restrict__ tgt, float* __restrict__ out) {
  __shared__ float rsc[4];
  const int tid = threadIdx.x;
  float s = 0.f;
  for (int r = tid; r < BT_; r += 256)
    s += lse[r] - logits[(size_t)r * V_ + tgt[r]];
  for (int off = 32; off > 0; off >>= 1) s += __shfl_down(s, off);
  if ((tid & 63) == 0) rsc[tid >> 6] = s;
  __syncthreads();
  if (tid == 0) out[(size_t)BT_ * V_] = (rsc[0] + rsc[1] + rsc[2] + rsc[3]) / (float)BT_;
}

// ================================================================ launch
extern "C" void kernel_launch(void* const* d_in, const int* in_sizes, int n_in,
                              void* d_out, int out_size, void* d_ws, size_t ws_size,
                              hipStream_t stream) {
  const int*   ids  = (const int*)d_in[0];
  const int*   tgt  = (const int*)d_in[1];
  const float* emb  = (const float*)d_in[2];
  const float* W    = (const float*)d_in[3];   // [2][2048][4096]
  const float* brnn = (const float*)d_in[4];   // [2][4096]
  const float* lng  = (const float*)d_in[5];   // [2][5][1024]
  const float* lnb  = (const float*)d_in[6];
  const float* sw   = (const float*)d_in[7];   // [1024][32000]
  const float* sb   = (const float*)d_in[8];   // [32000]
  float* out = (float*)d_out;

  char* ws = (char*)d_ws;
  size_t o = 0;
  auto take = [&](size_t n) { char* p = ws + o; o += (n + 255) & ~(size_t)255; return p; };
  unsigned short* WxT0 = (unsigned short*)take((size_t)G4H_ * H_ * 2);
  unsigned short* WhT0 = (unsigned short*)take((size_t)G4H_ * H_ * 2);
  unsigned short* WxT1 = (unsigned short*)take((size_t)G4H_ * H_ * 2);
  unsigned short* WhT1 = (unsigned short*)take((size_t)G4H_ * H_ * 2);
  unsigned short* WsT  = (unsigned short*)take((size_t)V_ * H_ * 2);
  unsigned short* Xemb = (unsigned short*)take((size_t)BT_ * H_ * 2);
  float*          Gbuf = (float*)take((size_t)BT_ * G4H_ * 4);
  unsigned short* Hb0  = (unsigned short*)take((size_t)BT_ * H_ * 2);
  unsigned short* Hb1  = (unsigned short*)take((size_t)BT_ * H_ * 2);
  float*          gf   = (float*)take((size_t)32 * G4H_ * 4);
  float*          lseb = (float*)take((size_t)BT_ * 4);
  unsigned*       bars = (unsigned*)take(32768);

  // zero the flag slots before EACH cooperative launch (stamps restart at 0)
  hipMemsetAsync(bars, 0, 32768, stream);

  const dim3 tb(32, 8);
  // weight transposes + bf16 cast: W[l] rows 0..1023 = Wx, rows 1024..2047 = Wh
  k_transpose_cast<<<dim3(128, 32),  tb, 0, stream>>>(W,                    WxT0, 1024, 4096, 4096);
  k_transpose_cast<<<dim3(128, 32),  tb, 0, stream>>>(W + 1024 * 4096,      WhT0, 1024, 4096, 4096);
  k_transpose_cast<<<dim3(128, 32),  tb, 0, stream>>>(W + 2048 * 4096,      WxT1, 1024, 4096, 4096);
  k_transpose_cast<<<dim3(128, 32),  tb, 0, stream>>>(W + 3072 * 4096,      WhT1, 1024, 4096, 4096);
  k_transpose_cast<<<dim3(1000, 32), tb, 0, stream>>>(sw,                   WsT,  1024, V_,  V_);

  k_gather<<<BT_, 256, 0, stream>>>(ids, emb, Xemb);

  // layer 0
  k_gemm_bt<<<dim3(32, 32), 256, 0, stream>>>(Xemb, WxT0, brnn, Gbuf, BT_, G4H_, H_);
  {
    const float* G_ = Gbuf; const unsigned short* Wh_ = WhT0;
    const float* g_ = lng;  const float* b_ = lnb;
    float* gf_ = gf; unsigned short* Ho_ = Hb0; unsigned* bars_ = bars;
    void* args[] = {&G_, &Wh_, &g_, &b_, &gf_, &Ho_, &bars_};
    hipLaunchCooperativeKernel((void*)k_lstm, dim3(256), dim3(256), args, 0, stream);
  }
  // re-zero flag state for the second cooperative launch
  hipMemsetAsync(bars, 0, 32768, stream);

  // layer 1
  k_gemm_bt<<<dim3(32, 32), 256, 0, stream>>>(Hb0, WxT1, brnn + 4096, Gbuf, BT_, G4H_, H_);
  {
    const float* G_ = Gbuf; const unsigned short* Wh_ = WhT1;
    const float* g_ = lng + 5120; const float* b_ = lnb + 5120;
    float* gf_ = gf; unsigned short* Ho_ = Hb1; unsigned* bars_ = bars;
    void* args[] = {&G_, &Wh_, &g_, &b_, &gf_, &Ho_, &bars_};
    hipLaunchCooperativeKernel((void*)k_lstm, dim3(256), dim3(256), args, 0, stream);
  }

  // projection -> logits (d_out) ; then logsumexp + loss
  k_gemm_bt<<<dim3(250, 32), 256, 0, stream>>>(Hb1, WsT, sb, out, BT_, V_, H_);
  k_lse<<<BT_, 256, 0, stream>>>(out, lseb);
  k_loss<<<1, 256, 0, stream>>>(out, lseb, tgt, out);
}

// Round 10
// 2580.846 us; speedup vs baseline: 6.8629x; 1.3197x over previous
//
#include <hip/hip_runtime.h>
#include <hip/hip_cooperative_groups.h>

#define V_    32000
#define B_    32
#define T_    128
#define H_    1024
#define BT_   4096     // B_*T_
#define G4H_  4096     // 4*H_
#define EPS_  1e-5f
#define FB_   1.0f     // forget bias

typedef __bf16  bf16x8 __attribute__((ext_vector_type(8)));
typedef float   f32x4  __attribute__((ext_vector_type(4)));
typedef float   f32x2  __attribute__((ext_vector_type(2)));
typedef unsigned u32x2 __attribute__((ext_vector_type(2)));
typedef short   short8 __attribute__((ext_vector_type(8)));

__device__ __forceinline__ unsigned short f2bf(float f) {
  unsigned u = __builtin_bit_cast(unsigned, f);
  u = u + 0x7FFFu + ((u >> 16) & 1u);          // round-to-nearest-even
  return (unsigned short)(u >> 16);
}
__device__ __forceinline__ float sigm(float x) { return 1.0f / (1.0f + expf(-x)); }

// ---------------------------------------------------------------- LLC-coherent access
__device__ __forceinline__ short8 ldg_coh16(const unsigned short* p) {
  short8 v;
  asm volatile("global_load_dwordx4 %0, %1, off sc0 sc1" : "=v"(v) : "v"(p) : "memory");
  return v;
}
__device__ __forceinline__ f32x4 ldg_coh16f(const float* p) {
  f32x4 v;
  asm volatile("global_load_dwordx4 %0, %1, off sc0 sc1" : "=v"(v) : "v"(p) : "memory");
  return v;
}
__device__ __forceinline__ void stg_coh8f(float* p, f32x2 v) {
  asm volatile("global_store_dwordx2 %0, %1, off sc0 sc1" :: "v"(p), "v"(v) : "memory");
}
__device__ __forceinline__ void stg_coh8u(unsigned short* p, u32x2 v) {
  asm volatile("global_store_dwordx2 %0, %1, off sc0 sc1" :: "v"(p), "v"(v) : "memory");
}
__device__ __forceinline__ void vmwait0() {
  asm volatile("s_waitcnt vmcnt(0)" ::: "memory");
  __builtin_amdgcn_sched_barrier(0);           // rule #18: pin consumers after the wait
}

// ---------------------------------------------------------------- dataflow flag sync
// 64B-padded slots: flags[16*i]. Stamps monotonic within a launch; host zeroes
// (stream-ordered) before each cooperative launch.
__device__ __forceinline__ void wait_flags(unsigned* flags, int nslots, unsigned tgt) {
  const int lane = threadIdx.x & 63;
  for (;;) {
    unsigned v = 0xFFFFFFFFu;
    for (int s = lane; s < nslots; s += 64) {
      const unsigned x = __hip_atomic_load(&flags[16 * s], __ATOMIC_RELAXED, __HIP_MEMORY_SCOPE_AGENT);
      v = x < v ? x : v;
    }
    if (__all((int)(v >= tgt))) break;
    __builtin_amdgcn_s_sleep(1);
  }
}

// ---------------------------------------------------------------- transpose+cast
__global__ void k_transpose_cast(const float* __restrict__ in, unsigned short* __restrict__ out,
                                 int R, int C, int ldin) {
  __shared__ float tl[32][33];
  const int tx = threadIdx.x, ty = threadIdx.y;
  const int r0 = blockIdx.y * 32, c0 = blockIdx.x * 32;
#pragma unroll
  for (int i = 0; i < 4; ++i)
    tl[ty + 8 * i][tx] = in[(size_t)(r0 + ty + 8 * i) * ldin + c0 + tx];
  __syncthreads();
#pragma unroll
  for (int i = 0; i < 4; ++i)
    out[(size_t)(c0 + ty + 8 * i) * R + r0 + tx] = f2bf(tl[tx][ty + 8 * i]);
}

// ---------------------------------------------------------------- embedding gather
__global__ void k_gather(const int* __restrict__ ids, const float* __restrict__ emb,
                         unsigned short* __restrict__ x) {
  const int r = blockIdx.x;
  const int t4 = threadIdx.x * 4;
  const int row = ids[r];
  const float4 v = *(const float4*)&emb[(size_t)row * H_ + t4];
  ushort4 o;
  o.x = f2bf(v.x); o.y = f2bf(v.y); o.z = f2bf(v.z); o.w = f2bf(v.w);
  *(ushort4*)&x[(size_t)r * H_ + t4] = o;
}

// ---------------------------------------------------------------- bf16 GEMM, C = A * BT^T + bias
__global__ __launch_bounds__(256)
void k_gemm_bt(const unsigned short* __restrict__ A, const unsigned short* __restrict__ BT,
               const float* __restrict__ bias, float* __restrict__ C,
               int M, int N, int K) {
  __shared__ unsigned short As[128 * 32];
  __shared__ unsigned short Bs[128 * 32];
  const int tid = threadIdx.x;
  const int lane = tid & 63, wid = tid >> 6;
  const int wr = wid >> 1, wc = wid & 1;
  const int la = lane & 15, lb = lane >> 4;
  const int m0 = blockIdx.y * 128, n0 = blockIdx.x * 128;

  f32x4 acc[4][4];
#pragma unroll
  for (int i = 0; i < 4; ++i)
#pragma unroll
    for (int j = 0; j < 4; ++j) acc[i][j] = f32x4{0.f, 0.f, 0.f, 0.f};

  for (int k0 = 0; k0 < K; k0 += 32) {
    __syncthreads();
#pragma unroll
    for (int i = 0; i < 2; ++i) {
      const int off = i * 2048 + tid * 8;
      const int row = off >> 5, col = off & 31;
      *(short8*)&As[off] = *(const short8*)&A[(size_t)(m0 + row) * K + k0 + col];
      *(short8*)&Bs[off] = *(const short8*)&BT[(size_t)(n0 + row) * K + k0 + col];
    }
    __syncthreads();
    bf16x8 a[4], b[4];
#pragma unroll
    for (int mm = 0; mm < 4; ++mm) a[mm] = *(bf16x8*)&As[(wr * 64 + mm * 16 + la) * 32 + lb * 8];
#pragma unroll
    for (int nn = 0; nn < 4; ++nn) b[nn] = *(bf16x8*)&Bs[(wc * 64 + nn * 16 + la) * 32 + lb * 8];
#pragma unroll
    for (int mm = 0; mm < 4; ++mm)
#pragma unroll
      for (int nn = 0; nn < 4; ++nn)
        acc[mm][nn] = __builtin_amdgcn_mfma_f32_16x16x32_bf16(a[mm], b[nn], acc[mm][nn], 0, 0, 0);
  }
#pragma unroll
  for (int mm = 0; mm < 4; ++mm)
#pragma unroll
    for (int nn = 0; nn < 4; ++nn) {
      const int row = m0 + wr * 64 + mm * 16 + lb * 4;
      const int col = n0 + wc * 64 + nn * 16 + la;
      const float bs = bias ? bias[col] : 0.f;
#pragma unroll
      for (int r = 0; r < 4; ++r)
        C[(size_t)(row + r) * N + col] = acc[mm][nn][r] + bs;
    }
}

// ---------------------------------------------------------------- persistent LN-LSTM layer
// (r6-proven kernel, kept verbatim as the fallback path.)
__global__ __launch_bounds__(256)
void k_lstm(const float* __restrict__ G, const unsigned short* __restrict__ WhT,
            const float* __restrict__ lng, const float* __restrict__ lnb,
            float* __restrict__ gf, unsigned short* __restrict__ Hout,
            unsigned* flags) {
  __shared__ unsigned short wh[16 * 1024];   // [col][k^((col&7)<<3)]
  __shared__ unsigned short hs[32 * 1024];   // [b][k^((b&7)<<3)] bf16
  __shared__ float crow[1024];
  __shared__ float red[4][32][16];
  __shared__ float rsc[64];

  const int tid = threadIdx.x;
  const int bid = blockIdx.x;
  const int lane = tid & 63, w = tid >> 6;
  const int la = lane & 15, lb = lane >> 4;
  unsigned* flag_g = flags;                  // 256 slots
  unsigned* flag_h = flags + 4096;           // 32 slots

  for (int i = tid * 8; i < 16 * 1024; i += 2048) {
    const int cl = i >> 10, k = i & 1023;
    *(short8*)&wh[cl * 1024 + (k ^ ((cl & 7) << 3))] = *(const short8*)&WhT[(size_t)bid * 16384 + i];
  }
  if (bid < 32)
    for (int e = tid; e < 1024; e += 256) crow[e] = 0.0f;

  for (int t = 0; t < T_; ++t) {
    if (t == 0) {
      const short8 z = {0, 0, 0, 0, 0, 0, 0, 0};
      for (int i = tid * 8; i < 32 * 1024; i += 2048) *(short8*)&hs[i] = z;
    } else {
      if (w == 0) wait_flags(flag_h, 32, (unsigned)t);
      __syncthreads();
      short8 tmp[16];
#pragma unroll
      for (int j = 0; j < 16; ++j) {
        const int i = tid * 8 + j * 2048;
        const int b = i >> 10, k = i & 1023;
        tmp[j] = ldg_coh16(&Hout[((size_t)(b * T_ + (t - 1))) * H_ + k]);
      }
      vmwait0();
#pragma unroll
      for (int j = 0; j < 16; ++j) {
        const int i = tid * 8 + j * 2048;
        const int b = i >> 10, k = i & 1023;
        *(short8*)&hs[b * 1024 + (k ^ ((b & 7) << 3))] = tmp[j];
      }
    }
    __syncthreads();

    f32x4 acc0 = {0.f, 0.f, 0.f, 0.f}, acc1 = {0.f, 0.f, 0.f, 0.f};
#pragma unroll
    for (int kk = 0; kk < 8; ++kk) {
      const int k = w * 256 + kk * 32 + lb * 8;
      const int kx = k ^ ((la & 7) << 3);
      const bf16x8 bv = *(bf16x8*)&wh[la * 1024 + kx];
      const bf16x8 a0 = *(bf16x8*)&hs[la * 1024 + kx];
      const bf16x8 a1 = *(bf16x8*)&hs[(16 + la) * 1024 + kx];
      acc0 = __builtin_amdgcn_mfma_f32_16x16x32_bf16(a0, bv, acc0, 0, 0, 0);
      acc1 = __builtin_amdgcn_mfma_f32_16x16x32_bf16(a1, bv, acc1, 0, 0, 0);
    }
#pragma unroll
    for (int r = 0; r < 4; ++r) {
      red[w][lb * 4 + r][la] = acc0[r];
      red[w][16 + lb * 4 + r][la] = acc1[r];
    }
    __syncthreads();
    {
      const int b2 = tid >> 3, c2 = (tid & 7) * 2;
      f32x2 sv;
      sv.x = red[0][b2][c2]     + red[1][b2][c2]     + red[2][b2][c2]     + red[3][b2][c2]
           + G[((size_t)(b2 * T_ + t)) * G4H_ + bid * 16 + c2];
      sv.y = red[0][b2][c2 + 1] + red[1][b2][c2 + 1] + red[2][b2][c2 + 1] + red[3][b2][c2 + 1]
           + G[((size_t)(b2 * T_ + t)) * G4H_ + bid * 16 + c2 + 1];
      stg_coh8f(&gf[b2 * G4H_ + bid * 16 + c2], sv);
    }
    __syncthreads();
    if (tid == 0)
      __hip_atomic_store(&flag_g[16 * bid], (unsigned)(t + 1), __ATOMIC_RELAXED, __HIP_MEMORY_SCOPE_AGENT);

    if (bid < 32) {
      if (w == 0) wait_flags(flag_g, 256, (unsigned)(t + 1));
      __syncthreads();
      const int b = bid;
      const int e0 = tid * 4;
      const f32x4 iv = ldg_coh16f(&gf[(size_t)b * G4H_ + e0]);
      const f32x4 jv = ldg_coh16f(&gf[(size_t)b * G4H_ + 1024 + e0]);
      const f32x4 fv = ldg_coh16f(&gf[(size_t)b * G4H_ + 2048 + e0]);
      const f32x4 ov = ldg_coh16f(&gf[(size_t)b * G4H_ + 3072 + e0]);
      vmwait0();

      float vals[8] = {0, 0, 0, 0, 0, 0, 0, 0};
#pragma unroll
      for (int u = 0; u < 4; ++u) {
        vals[0] += iv[u]; vals[4] += iv[u] * iv[u];
        vals[1] += jv[u]; vals[5] += jv[u] * jv[u];
        vals[2] += fv[u]; vals[6] += fv[u] * fv[u];
        vals[3] += ov[u]; vals[7] += ov[u] * ov[u];
      }
#pragma unroll
      for (int i = 0; i < 8; ++i) {
        float x = vals[i];
        for (int off = 32; off > 0; off >>= 1) x += __shfl_down(x, off);
        if (lane == 0) rsc[w * 8 + i] = x;
      }
      __syncthreads();
#pragma unroll
      for (int i = 0; i < 8; ++i)
        vals[i] = rsc[i] + rsc[8 + i] + rsc[16 + i] + rsc[24 + i];
      __syncthreads();
      const float m0 = vals[0] * (1.f / 1024), m1 = vals[1] * (1.f / 1024);
      const float m2 = vals[2] * (1.f / 1024), m3 = vals[3] * (1.f / 1024);
      const float r0 = rsqrtf(vals[4] * (1.f / 1024) - m0 * m0 + EPS_);
      const float r1 = rsqrtf(vals[5] * (1.f / 1024) - m1 * m1 + EPS_);
      const float r2 = rsqrtf(vals[6] * (1.f / 1024) - m2 * m2 + EPS_);
      const float r3 = rsqrtf(vals[7] * (1.f / 1024) - m3 * m3 + EPS_);

      const float4 gI = *(const float4*)&lng[e0];
      const float4 gJ = *(const float4*)&lng[1024 + e0];
      const float4 gF = *(const float4*)&lng[2048 + e0];
      const float4 gO = *(const float4*)&lng[3072 + e0];
      const float4 gC = *(const float4*)&lng[4096 + e0];
      const float4 bI = *(const float4*)&lnb[e0];
      const float4 bJ = *(const float4*)&lnb[1024 + e0];
      const float4 bF = *(const float4*)&lnb[2048 + e0];
      const float4 bO = *(const float4*)&lnb[3072 + e0];
      const float4 bC = *(const float4*)&lnb[4096 + e0];
      const float4 cr = *(const float4*)&crow[e0];

      float nc[4], oo[4];
      float cs = 0.f, cq = 0.f;
      {
        const float gi[4] = {gI.x, gI.y, gI.z, gI.w}, bi[4] = {bI.x, bI.y, bI.z, bI.w};
        const float gj[4] = {gJ.x, gJ.y, gJ.z, gJ.w}, bj[4] = {bJ.x, bJ.y, bJ.z, bJ.w};
        const float gff[4] = {gF.x, gF.y, gF.z, gF.w}, bf[4] = {bF.x, bF.y, bF.z, bF.w};
        const float go[4] = {gO.x, gO.y, gO.z, gO.w}, bo[4] = {bO.x, bO.y, bO.z, bO.w};
        const float cv[4] = {cr.x, cr.y, cr.z, cr.w};
#pragma unroll
        for (int u = 0; u < 4; ++u) {
          const float xi = gi[u] * ((iv[u] - m0) * r0) + bi[u];
          const float xj = gj[u] * ((jv[u] - m1) * r1) + bj[u];
          const float xf = gff[u] * ((fv[u] - m2) * r2) + bf[u];
          const float xo = go[u] * ((ov[u] - m3) * r3) + bo[u];
          const float ncv = cv[u] * sigm(xf + FB_) + sigm(xi) * tanhf(xj);
          nc[u] = ncv; oo[u] = xo;
          cs += ncv; cq += ncv * ncv;
        }
      }
      {
        float x = cs, y = cq;
        for (int off = 32; off > 0; off >>= 1) { x += __shfl_down(x, off); y += __shfl_down(y, off); }
        if (lane == 0) { rsc[w * 2] = x; rsc[w * 2 + 1] = y; }
      }
      __syncthreads();
      cs = rsc[0] + rsc[2] + rsc[4] + rsc[6];
      cq = rsc[1] + rsc[3] + rsc[5] + rsc[7];
      const float mc = cs * (1.f / 1024);
      const float rc = rsqrtf(cq * (1.f / 1024) - mc * mc + EPS_);
      {
        const float gc[4] = {gC.x, gC.y, gC.z, gC.w}, bc[4] = {bC.x, bC.y, bC.z, bC.w};
        unsigned short hb[4];
#pragma unroll
        for (int u = 0; u < 4; ++u) {
          const float nh = tanhf(gc[u] * ((nc[u] - mc) * rc) + bc[u]) * sigm(oo[u]);
          hb[u] = f2bf(nh);
        }
        u32x2 hv;
        hv[0] = (unsigned)hb[0] | ((unsigned)hb[1] << 16);
        hv[1] = (unsigned)hb[2] | ((unsigned)hb[3] << 16);
        stg_coh8u(&Hout[((size_t)(b * T_ + t)) * H_ + e0], hv);
        *(float4*)&crow[e0] = float4{nc[0], nc[1], nc[2], nc[3]};
      }
      __syncthreads();
      if (tid == 0)
        __hip_atomic_store(&flag_h[16 * bid], (unsigned)(t + 1), __ATOMIC_RELAXED, __HIP_MEMORY_SCOPE_AGENT);
    }
  }
}

// ---------------------------------------------------------------- fused 2-layer LN-LSTM
// Register-reduced: K-loop split into 2 halves (4 kk each) so only 16 staged
// short8 live at once (64 VGPRs), targeting total VGPR < 256 (suspected cause
// of the silent cooperative-launch rejections in r3/r7/r8/r9).
__global__ __launch_bounds__(256)
void k_lstm2(const float* __restrict__ G, const unsigned short* __restrict__ WhT0,
             const unsigned short* __restrict__ WxT1, const unsigned short* __restrict__ WhT1,
             const float* __restrict__ b1,
             const float* __restrict__ lng, const float* __restrict__ lnb,
             float* __restrict__ gf0, float* __restrict__ gf1,
             unsigned short* __restrict__ Hb0, unsigned short* __restrict__ Hb1,
             unsigned* flags) {
  __shared__ unsigned short wh0[16 * 1024];  // [col][k^((col&7)<<3)]
  __shared__ unsigned short wx1[16 * 1024];
  __shared__ unsigned short wh1[16 * 1024];
  __shared__ float red[4][32][16];
  __shared__ float crow[1024];
  __shared__ float rsc[64];

  const int tid = threadIdx.x, bid = blockIdx.x;
  const int lane = tid & 63, w = tid >> 6;
  const int la = lane & 15, lb = lane >> 4;
  unsigned* flag_g0 = flags;                 // 256 slots
  unsigned* flag_g1 = flags + 4096;          // 256 slots
  unsigned* flag_h0 = flags + 8192;          // 32 slots
  unsigned* flag_h1 = flags + 8704;          // 32 slots

  for (int i = tid * 8; i < 16 * 1024; i += 2048) {
    const int cl = i >> 10, k = i & 1023;
    const int dst = cl * 1024 + (k ^ ((cl & 7) << 3));
    *(short8*)&wh0[dst] = *(const short8*)&WhT0[(size_t)bid * 16384 + i];
    *(short8*)&wx1[dst] = *(const short8*)&WxT1[(size_t)bid * 16384 + i];
    *(short8*)&wh1[dst] = *(const short8*)&WhT1[(size_t)bid * 16384 + i];
  }
  if (bid < 64)
    for (int e = tid; e < 1024; e += 256) crow[e] = 0.0f;
  __syncthreads();

  for (int s = 0; s <= T_; ++s) {
    if (w == 0) {
      if (s >= 1) wait_flags(flag_h0, 32, (unsigned)s);        // h0(s-1) ready
      if (s >= 2) wait_flags(flag_h1, 32, (unsigned)(s - 1));  // h1(s-2) ready
    }
    __syncthreads();

    f32x4 accA0 = {0.f,0.f,0.f,0.f}, accA1 = {0.f,0.f,0.f,0.f};
    f32x4 accB0 = {0.f,0.f,0.f,0.f}, accB1 = {0.f,0.f,0.f,0.f};
    f32x4 accC0 = {0.f,0.f,0.f,0.f}, accC1 = {0.f,0.f,0.f,0.f};
    if (s >= 1) {
      const int kw = w * 256 + lb * 8;
      const size_t t0 = (size_t)(s - 1);
      const size_t t1 = (size_t)(s - 2);
#pragma unroll
      for (int half = 0; half < 2; ++half) {
        short8 a0[4], a1[4], c0v[4], c1v[4];
        const int kb = kw + half * 128;
#pragma unroll
        for (int kk = 0; kk < 4; ++kk) {
          a0[kk] = ldg_coh16(&Hb0[((size_t)la * T_ + t0) * H_ + kb + kk * 32]);
          a1[kk] = ldg_coh16(&Hb0[((size_t)(16 + la) * T_ + t0) * H_ + kb + kk * 32]);
        }
        if (s >= 2) {
#pragma unroll
          for (int kk = 0; kk < 4; ++kk) {
            c0v[kk] = ldg_coh16(&Hb1[((size_t)la * T_ + t1) * H_ + kb + kk * 32]);
            c1v[kk] = ldg_coh16(&Hb1[((size_t)(16 + la) * T_ + t1) * H_ + kb + kk * 32]);
          }
        }
        vmwait0();
#pragma unroll
        for (int kk = 0; kk < 4; ++kk) {
          const int kx = (kb + kk * 32) ^ ((la & 7) << 3);
          const bf16x8 va0 = __builtin_bit_cast(bf16x8, a0[kk]);
          const bf16x8 va1 = __builtin_bit_cast(bf16x8, a1[kk]);
          const bf16x8 bB = *(bf16x8*)&wx1[la * 1024 + kx];
          accB0 = __builtin_amdgcn_mfma_f32_16x16x32_bf16(va0, bB, accB0, 0, 0, 0);
          accB1 = __builtin_amdgcn_mfma_f32_16x16x32_bf16(va1, bB, accB1, 0, 0, 0);
          if (s < T_) {
            const bf16x8 bA = *(bf16x8*)&wh0[la * 1024 + kx];
            accA0 = __builtin_amdgcn_mfma_f32_16x16x32_bf16(va0, bA, accA0, 0, 0, 0);
            accA1 = __builtin_amdgcn_mfma_f32_16x16x32_bf16(va1, bA, accA1, 0, 0, 0);
          }
          if (s >= 2) {
            const bf16x8 bC = *(bf16x8*)&wh1[la * 1024 + kx];
            const bf16x8 vc0 = __builtin_bit_cast(bf16x8, c0v[kk]);
            const bf16x8 vc1 = __builtin_bit_cast(bf16x8, c1v[kk]);
            accC0 = __builtin_amdgcn_mfma_f32_16x16x32_bf16(vc0, bC, accC0, 0, 0, 0);
            accC1 = __builtin_amdgcn_mfma_f32_16x16x32_bf16(vc1, bC, accC1, 0, 0, 0);
          }
        }
      }
    }

    // ---- gf0 = G[s] + A
#pragma unroll
    for (int r = 0; r < 4; ++r) {
      red[w][lb * 4 + r][la] = accA0[r];
      red[w][16 + lb * 4 + r][la] = accA1[r];
    }
    __syncthreads();
    if (s < T_) {
      const int b2 = tid >> 3, c2 = (tid & 7) * 2;
      f32x2 sv;
      sv.x = red[0][b2][c2]     + red[1][b2][c2]     + red[2][b2][c2]     + red[3][b2][c2]
           + G[((size_t)(b2 * T_ + s)) * G4H_ + bid * 16 + c2];
      sv.y = red[0][b2][c2 + 1] + red[1][b2][c2 + 1] + red[2][b2][c2 + 1] + red[3][b2][c2 + 1]
           + G[((size_t)(b2 * T_ + s)) * G4H_ + bid * 16 + c2 + 1];
      stg_coh8f(&gf0[b2 * G4H_ + bid * 16 + c2], sv);
    }
    __syncthreads();
    if (tid == 0 && s < T_)
      __hip_atomic_store(&flag_g0[16 * bid], (unsigned)(s + 1), __ATOMIC_RELAXED, __HIP_MEMORY_SCOPE_AGENT);

    // ---- gf1 = b1 + B + C
#pragma unroll
    for (int r = 0; r < 4; ++r) {
      red[w][lb * 4 + r][la] = accB0[r] + accC0[r];
      red[w][16 + lb * 4 + r][la] = accB1[r] + accC1[r];
    }
    __syncthreads();
    if (s >= 1) {
      const int b2 = tid >> 3, c2 = (tid & 7) * 2;
      f32x2 sv;
      sv.x = red[0][b2][c2]     + red[1][b2][c2]     + red[2][b2][c2]     + red[3][b2][c2]
           + b1[bid * 16 + c2];
      sv.y = red[0][b2][c2 + 1] + red[1][b2][c2 + 1] + red[2][b2][c2 + 1] + red[3][b2][c2 + 1]
           + b1[bid * 16 + c2 + 1];
      stg_coh8f(&gf1[b2 * G4H_ + bid * 16 + c2], sv);
    }
    __syncthreads();
    if (tid == 0 && s >= 1)
      __hip_atomic_store(&flag_g1[16 * bid], (unsigned)(s + 1), __ATOMIC_RELAXED, __HIP_MEMORY_SCOPE_AGENT);

    // ---- phase 2: LN + pointwise (blocks 0-31: L0 time s; 32-63: L1 time s-1)
    const bool isP2 = (bid < 32) ? (s < T_) : (bid < 64 ? (s >= 1) : false);
    if (isP2) {
      const bool L1p = (bid >= 32);
      const int b = L1p ? (bid - 32) : bid;
      if (w == 0) wait_flags(L1p ? flag_g1 : flag_g0, 256, (unsigned)(s + 1));
      __syncthreads();
      const float* gfp = (L1p ? gf1 : gf0) + (size_t)b * G4H_;
      const float* g_ = L1p ? (lng + 5120) : lng;
      const float* b_ = L1p ? (lnb + 5120) : lnb;
      const int tt = L1p ? (s - 1) : s;
      unsigned short* hout = (L1p ? Hb1 : Hb0) + ((size_t)b * T_ + tt) * H_;

      const int e0 = tid * 4;
      const f32x4 iv = ldg_coh16f(&gfp[e0]);
      const f32x4 jv = ldg_coh16f(&gfp[1024 + e0]);
      const f32x4 fv = ldg_coh16f(&gfp[2048 + e0]);
      const f32x4 ov = ldg_coh16f(&gfp[3072 + e0]);
      vmwait0();

      float vals[8] = {0, 0, 0, 0, 0, 0, 0, 0};
#pragma unroll
      for (int u = 0; u < 4; ++u) {
        vals[0] += iv[u]; vals[4] += iv[u] * iv[u];
        vals[1] += jv[u]; vals[5] += jv[u] * jv[u];
        vals[2] += fv[u]; vals[6] += fv[u] * fv[u];
        vals[3] += ov[u]; vals[7] += ov[u] * ov[u];
      }
#pragma unroll
      for (int i = 0; i < 8; ++i) {
        float x = vals[i];
        for (int off = 32; off > 0; off >>= 1) x += __shfl_down(x, off);
        if (lane == 0) rsc[w * 8 + i] = x;
      }
      __syncthreads();
#pragma unroll
      for (int i = 0; i < 8; ++i)
        vals[i] = rsc[i] + rsc[8 + i] + rsc[16 + i] + rsc[24 + i];
      __syncthreads();
      const float m0 = vals[0] * (1.f / 1024), m1 = vals[1] * (1.f / 1024);
      const float m2 = vals[2] * (1.f / 1024), m3 = vals[3] * (1.f / 1024);
      const float r0 = rsqrtf(vals[4] * (1.f / 1024) - m0 * m0 + EPS_);
      const float r1 = rsqrtf(vals[5] * (1.f / 1024) - m1 * m1 + EPS_);
      const float r2 = rsqrtf(vals[6] * (1.f / 1024) - m2 * m2 + EPS_);
      const float r3 = rsqrtf(vals[7] * (1.f / 1024) - m3 * m3 + EPS_);

      const float4 gI = *(const float4*)&g_[e0];
      const float4 gJ = *(const float4*)&g_[1024 + e0];
      const float4 gF = *(const float4*)&g_[2048 + e0];
      const float4 gO = *(const float4*)&g_[3072 + e0];
      const float4 gC = *(const float4*)&g_[4096 + e0];
      const float4 bI = *(const float4*)&b_[e0];
      const float4 bJ = *(const float4*)&b_[1024 + e0];
      const float4 bF = *(const float4*)&b_[2048 + e0];
      const float4 bO = *(const float4*)&b_[3072 + e0];
      const float4 bC = *(const float4*)&b_[4096 + e0];
      const float4 cr = *(const float4*)&crow[e0];

      float nc[4], oo[4];
      float cs = 0.f, cq = 0.f;
      {
        const float gi[4] = {gI.x, gI.y, gI.z, gI.w}, bi[4] = {bI.x, bI.y, bI.z, bI.w};
        const float gj[4] = {gJ.x, gJ.y, gJ.z, gJ.w}, bj[4] = {bJ.x, bJ.y, bJ.z, bJ.w};
        const float gff[4] = {gF.x, gF.y, gF.z, gF.w}, bf[4] = {bF.x, bF.y, bF.z, bF.w};
        const float go[4] = {gO.x, gO.y, gO.z, gO.w}, bo[4] = {bO.x, bO.y, bO.z, bO.w};
        const float cv[4] = {cr.x, cr.y, cr.z, cr.w};
#pragma unroll
        for (int u = 0; u < 4; ++u) {
          const float xi = gi[u] * ((iv[u] - m0) * r0) + bi[u];
          const float xj = gj[u] * ((jv[u] - m1) * r1) + bj[u];
          const float xf = gff[u] * ((fv[u] - m2) * r2) + bf[u];
          const float xo = go[u] * ((ov[u] - m3) * r3) + bo[u];
          const float ncv = cv[u] * sigm(xf + FB_) + sigm(xi) * tanhf(xj);
          nc[u] = ncv; oo[u] = xo;
          cs += ncv; cq += ncv * ncv;
        }
      }
      {
        float x = cs, y = cq;
        for (int off = 32; off > 0; off >>= 1) { x += __shfl_down(x, off); y += __shfl_down(y, off); }
        if (lane == 0) { rsc[w * 2] = x; rsc[w * 2 + 1] = y; }
      }
      __syncthreads();
      cs = rsc[0] + rsc[2] + rsc[4] + rsc[6];
      cq = rsc[1] + rsc[3] + rsc[5] + rsc[7];
      const float mc = cs * (1.f / 1024);
      const float rc = rsqrtf(cq * (1.f / 1024) - mc * mc + EPS_);
      {
        const float gc[4] = {gC.x, gC.y, gC.z, gC.w}, bc[4] = {bC.x, bC.y, bC.z, bC.w};
        unsigned short hb[4];
#pragma unroll
        for (int u = 0; u < 4; ++u) {
          const float nh = tanhf(gc[u] * ((nc[u] - mc) * rc) + bc[u]) * sigm(oo[u]);
          hb[u] = f2bf(nh);
        }
        u32x2 hv;
        hv[0] = (unsigned)hb[0] | ((unsigned)hb[1] << 16);
        hv[1] = (unsigned)hb[2] | ((unsigned)hb[3] << 16);
        stg_coh8u(&hout[e0], hv);
        *(float4*)&crow[e0] = float4{nc[0], nc[1], nc[2], nc[3]};
      }
      __syncthreads();
      if (tid == 0) {
        if (L1p)
          __hip_atomic_store(&flag_h1[16 * b], (unsigned)s, __ATOMIC_RELAXED, __HIP_MEMORY_SCOPE_AGENT);
        else
          __hip_atomic_store(&flag_h0[16 * b], (unsigned)(s + 1), __ATOMIC_RELAXED, __HIP_MEMORY_SCOPE_AGENT);
      }
    }
  }
}

// ---------------------------------------------------------------- per-row logsumexp
__global__ __launch_bounds__(256)
void k_lse(const float* __restrict__ logits, float* __restrict__ lse) {
  __shared__ float rm[4];
  __shared__ float rs[4];
  const int r = blockIdx.x, tid = threadIdx.x;
  const float* row = logits + (size_t)r * V_;
  float mx = -1e30f;
  for (int e = tid; e < V_; e += 256) mx = fmaxf(mx, row[e]);
  for (int off = 32; off > 0; off >>= 1) mx = fmaxf(mx, __shfl_down(mx, off));
  if ((tid & 63) == 0) rm[tid >> 6] = mx;
  __syncthreads();
  mx = fmaxf(fmaxf(rm[0], rm[1]), fmaxf(rm[2], rm[3]));
  float s = 0.f;
  for (int e = tid; e < V_; e += 256) s += expf(row[e] - mx);
  for (int off = 32; off > 0; off >>= 1) s += __shfl_down(s, off);
  if ((tid & 63) == 0) rs[tid >> 6] = s;
  __syncthreads();
  if (tid == 0) lse[r] = mx + logf(rs[0] + rs[1] + rs[2] + rs[3]);
}

// ---------------------------------------------------------------- loss (mean NLL)
__global__ __launch_bounds__(256)
void k_loss(const float* __restrict__ logits, const float* __restrict__ lse,
            const int* __restrict__ tgt, float* __restrict__ out) {
  __shared__ float rsc[4];
  const int tid = threadIdx.x;
  float s = 0.f;
  for (int r = tid; r < BT_; r += 256)
    s += lse[r] - logits[(size_t)r * V_ + tgt[r]];
  for (int off = 32; off > 0; off >>= 1) s += __shfl_down(s, off);
  if ((tid & 63) == 0) rsc[tid >> 6] = s;
  __syncthreads();
  if (tid == 0) out[(size_t)BT_ * V_] = (rsc[0] + rsc[1] + rsc[2] + rsc[3]) / (float)BT_;
}

// ================================================================ launch
// Fused cooperative kernel attempt with CHECKED launch; on rejection, fall back
// to the r6-proven two-kernel sequence (identical outputs either way).
extern "C" void kernel_launch(void* const* d_in, const int* in_sizes, int n_in,
                              void* d_out, int out_size, void* d_ws, size_t ws_size,
                              hipStream_t stream) {
  const int*   ids  = (const int*)d_in[0];
  const int*   tgt  = (const int*)d_in[1];
  const float* emb  = (const float*)d_in[2];
  const float* W    = (const float*)d_in[3];   // [2][2048][4096]
  const float* brnn = (const float*)d_in[4];   // [2][4096]
  const float* lng  = (const float*)d_in[5];   // [2][5][1024]
  const float* lnb  = (const float*)d_in[6];
  const float* sw   = (const float*)d_in[7];   // [1024][32000]
  const float* sb   = (const float*)d_in[8];   // [32000]
  float* out = (float*)d_out;

  char* ws = (char*)d_ws;
  size_t o = 0;
  auto take = [&](size_t n) { char* p = ws + o; o += (n + 255) & ~(size_t)255; return p; };
  unsigned short* WxT0 = (unsigned short*)take((size_t)G4H_ * H_ * 2);       // 8 MB
  unsigned short* WhT0 = (unsigned short*)take((size_t)G4H_ * H_ * 2);       // 8 MB
  unsigned short* WxT1 = (unsigned short*)take((size_t)G4H_ * H_ * 2);       // 8 MB
  unsigned short* WhT1 = (unsigned short*)take((size_t)G4H_ * H_ * 2);       // 8 MB
  unsigned short* WsT  = (unsigned short*)take((size_t)V_ * H_ * 2);         // 65.5 MB
  unsigned short* Xemb = (unsigned short*)take((size_t)BT_ * H_ * 2);        // 8 MB
  float*          Gbuf = (float*)take((size_t)BT_ * G4H_ * 4);               // 64 MB
  unsigned short* Hb0  = (unsigned short*)take((size_t)BT_ * H_ * 2);        // 8 MB
  unsigned short* Hb1  = (unsigned short*)take((size_t)BT_ * H_ * 2);        // 8 MB
  // aliased into the Xemb region (dead after the L0 x-part GEMM)
  char* xregion = (char*)Xemb;
  float*    gf0  = (float*)(xregion);                    // 524,288 B
  float*    gf1  = (float*)(xregion + 524288);           // 524,288 B
  unsigned* bars = (unsigned*)(xregion + 1048576);       //  40,960 B
  float*    lseb = (float*)(xregion + 1089536);          //  16,384 B

  const dim3 tb(32, 8);
  k_transpose_cast<<<dim3(128, 32),  tb, 0, stream>>>(W,                    WxT0, 1024, 4096, 4096);
  k_transpose_cast<<<dim3(128, 32),  tb, 0, stream>>>(W + 1024 * 4096,      WhT0, 1024, 4096, 4096);
  k_transpose_cast<<<dim3(128, 32),  tb, 0, stream>>>(W + 2048 * 4096,      WxT1, 1024, 4096, 4096);
  k_transpose_cast<<<dim3(128, 32),  tb, 0, stream>>>(W + 3072 * 4096,      WhT1, 1024, 4096, 4096);
  k_transpose_cast<<<dim3(1000, 32), tb, 0, stream>>>(sw,                   WsT,  1024, V_,  V_);

  k_gather<<<BT_, 256, 0, stream>>>(ids, emb, Xemb);

  // layer-0 x-part precompute: Gbuf = Xemb @ Wx0^T + b0  (last use of Xemb)
  k_gemm_bt<<<dim3(32, 32), 256, 0, stream>>>(Xemb, WxT0, brnn, Gbuf, BT_, G4H_, H_);

  // Xemb region now dead: zero the flag slots (stream-ordered)
  hipMemsetAsync(bars, 0, 40960, stream);

  // ---- try the fused 2-layer cooperative kernel
  const float* G_ = Gbuf;
  const unsigned short* Wh0_ = WhT0; const unsigned short* Wx1_ = WxT1; const unsigned short* Wh1_ = WhT1;
  const float* b1_ = brnn + 4096;
  const float* g0_ = lng;        const float* bb0_ = lnb;
  const float* g1_ = lng + 5120; const float* bb1_ = lnb + 5120;
  float* gf0_ = gf0; float* gf1_ = gf1;
  unsigned short* H0_ = Hb0; unsigned short* H1_ = Hb1;
  unsigned* bars_ = bars;

  hipError_t ce;
  {
    void* args[] = {&G_, &Wh0_, &Wx1_, &Wh1_, &b1_, &g0_, &bb0_, &gf0_, &gf1_, &H0_, &H1_, &bars_};
    ce = hipLaunchCooperativeKernel((void*)k_lstm2, dim3(256), dim3(256), args, 0, stream);
  }
  if (ce != hipSuccess) {
    // ---- fallback: r6-proven two-kernel sequence (bars already zeroed)
    {
      void* a0[] = {&G_, &Wh0_, &g0_, &bb0_, &gf0_, &H0_, &bars_};
      hipLaunchCooperativeKernel((void*)k_lstm, dim3(256), dim3(256), a0, 0, stream);
    }
    hipMemsetAsync(bars, 0, 40960, stream);
    k_gemm_bt<<<dim3(32, 32), 256, 0, stream>>>(Hb0, WxT1, brnn + 4096, Gbuf, BT_, G4H_, H_);
    {
      void* a1[] = {&G_, &Wh1_, &g1_, &bb1_, &gf0_, &H1_, &bars_};
      hipLaunchCooperativeKernel((void*)k_lstm, dim3(256), dim3(256), a1, 0, stream);
    }
  }

  // projection -> logits (d_out) ; then logsumexp + loss
  k_gemm_bt<<<dim3(250, 32), 256, 0, stream>>>(Hb1, WsT, sb, out, BT_, V_, H_);
  k_lse<<<BT_, 256, 0, stream>>>(out, lseb);
  k_loss<<<1, 256, 0, stream>>>(out, lseb, tgt, out);
}

// Round 11
// 2441.097 us; speedup vs baseline: 7.2558x; 1.0572x over previous
//
#include <hip/hip_runtime.h>
#include <hip/hip_cooperative_groups.h>

#define V_    32000
#define B_    32
#define T_    128
#define H_    1024
#define BT_   4096     // B_*T_
#define G4H_  4096     // 4*H_
#define EPS_  1e-5f
#define FB_   1.0f     // forget bias

typedef __bf16  bf16x8 __attribute__((ext_vector_type(8)));
typedef float   f32x4  __attribute__((ext_vector_type(4)));
typedef float   f32x2  __attribute__((ext_vector_type(2)));
typedef unsigned u32x2 __attribute__((ext_vector_type(2)));
typedef short   short8 __attribute__((ext_vector_type(8)));

__device__ __forceinline__ unsigned short f2bf(float f) {
  unsigned u = __builtin_bit_cast(unsigned, f);
  u = u + 0x7FFFu + ((u >> 16) & 1u);          // round-to-nearest-even
  return (unsigned short)(u >> 16);
}
__device__ __forceinline__ float sigm(float x) { return 1.0f / (1.0f + expf(-x)); }

// ---------------------------------------------------------------- LLC-coherent access
__device__ __forceinline__ short8 ldg_coh16(const unsigned short* p) {
  short8 v;
  asm volatile("global_load_dwordx4 %0, %1, off sc0 sc1" : "=v"(v) : "v"(p) : "memory");
  return v;
}
__device__ __forceinline__ f32x4 ldg_coh16f(const float* p) {
  f32x4 v;
  asm volatile("global_load_dwordx4 %0, %1, off sc0 sc1" : "=v"(v) : "v"(p) : "memory");
  return v;
}
__device__ __forceinline__ void stg_coh8f(float* p, f32x2 v) {
  asm volatile("global_store_dwordx2 %0, %1, off sc0 sc1" :: "v"(p), "v"(v) : "memory");
}
__device__ __forceinline__ void stg_coh8u(unsigned short* p, u32x2 v) {
  asm volatile("global_store_dwordx2 %0, %1, off sc0 sc1" :: "v"(p), "v"(v) : "memory");
}
__device__ __forceinline__ void vmwait0() {
  asm volatile("s_waitcnt vmcnt(0)" ::: "memory");
  __builtin_amdgcn_sched_barrier(0);           // rule #18: pin consumers after the wait
}

// ---------------------------------------------------------------- dataflow flag sync
__device__ __forceinline__ void wait_flags(unsigned* flags, int nslots, unsigned tgt) {
  const int lane = threadIdx.x & 63;
  for (;;) {
    unsigned v = 0xFFFFFFFFu;
    for (int s = lane; s < nslots; s += 64) {
      const unsigned x = __hip_atomic_load(&flags[16 * s], __ATOMIC_RELAXED, __HIP_MEMORY_SCOPE_AGENT);
      v = x < v ? x : v;
    }
    if (__all((int)(v >= tgt))) break;
    __builtin_amdgcn_s_sleep(1);
  }
}

// ---------------------------------------------------------------- transpose+cast
__global__ void k_transpose_cast(const float* __restrict__ in, unsigned short* __restrict__ out,
                                 int R, int C, int ldin) {
  __shared__ float tl[32][33];
  const int tx = threadIdx.x, ty = threadIdx.y;
  const int r0 = blockIdx.y * 32, c0 = blockIdx.x * 32;
#pragma unroll
  for (int i = 0; i < 4; ++i)
    tl[ty + 8 * i][tx] = in[(size_t)(r0 + ty + 8 * i) * ldin + c0 + tx];
  __syncthreads();
#pragma unroll
  for (int i = 0; i < 4; ++i)
    out[(size_t)(c0 + ty + 8 * i) * R + r0 + tx] = f2bf(tl[tx][ty + 8 * i]);
}

// ---------------------------------------------------------------- embedding gather
__global__ void k_gather(const int* __restrict__ ids, const float* __restrict__ emb,
                         unsigned short* __restrict__ x) {
  const int r = blockIdx.x;
  const int t4 = threadIdx.x * 4;
  const int row = ids[r];
  const float4 v = *(const float4*)&emb[(size_t)row * H_ + t4];
  ushort4 o;
  o.x = f2bf(v.x); o.y = f2bf(v.y); o.z = f2bf(v.z); o.w = f2bf(v.w);
  *(ushort4*)&x[(size_t)r * H_ + t4] = o;
}

// ---------------------------------------------------------------- bf16 GEMM, C = A * BT^T + bias
// Staging upgraded to width-16 global_load_lds (async global->LDS, no VGPR
// round-trip). LDS layout is linear in lane order: thread tid's 16B lands at
// byte i*4096 + tid*16 = wave-uniform base + lane*16, matching the HW pattern.
__global__ __launch_bounds__(256)
void k_gemm_bt(const unsigned short* __restrict__ A, const unsigned short* __restrict__ BT,
               const float* __restrict__ bias, float* __restrict__ C,
               int M, int N, int K) {
  __shared__ unsigned short As[128 * 32];
  __shared__ unsigned short Bs[128 * 32];
  const int tid = threadIdx.x;
  const int lane = tid & 63, wid = tid >> 6;
  const int wr = wid >> 1, wc = wid & 1;
  const int la = lane & 15, lb = lane >> 4;
  const int m0 = blockIdx.y * 128, n0 = blockIdx.x * 128;

  f32x4 acc[4][4];
#pragma unroll
  for (int i = 0; i < 4; ++i)
#pragma unroll
    for (int j = 0; j < 4; ++j) acc[i][j] = f32x4{0.f, 0.f, 0.f, 0.f};

  for (int k0 = 0; k0 < K; k0 += 32) {
    __syncthreads();
#pragma unroll
    for (int i = 0; i < 2; ++i) {
      const int off = i * 2048 + tid * 8;
      const int row = off >> 5, col = off & 31;
      __builtin_amdgcn_global_load_lds(
          (const __attribute__((address_space(1))) void*)&A[(size_t)(m0 + row) * K + k0 + col],
          (__attribute__((address_space(3))) void*)&As[off], 16, 0, 0);
      __builtin_amdgcn_global_load_lds(
          (const __attribute__((address_space(1))) void*)&BT[(size_t)(n0 + row) * K + k0 + col],
          (__attribute__((address_space(3))) void*)&Bs[off], 16, 0, 0);
    }
    __syncthreads();
    bf16x8 a[4], b[4];
#pragma unroll
    for (int mm = 0; mm < 4; ++mm) a[mm] = *(bf16x8*)&As[(wr * 64 + mm * 16 + la) * 32 + lb * 8];
#pragma unroll
    for (int nn = 0; nn < 4; ++nn) b[nn] = *(bf16x8*)&Bs[(wc * 64 + nn * 16 + la) * 32 + lb * 8];
#pragma unroll
    for (int mm = 0; mm < 4; ++mm)
#pragma unroll
      for (int nn = 0; nn < 4; ++nn)
        acc[mm][nn] = __builtin_amdgcn_mfma_f32_16x16x32_bf16(a[mm], b[nn], acc[mm][nn], 0, 0, 0);
  }
#pragma unroll
  for (int mm = 0; mm < 4; ++mm)
#pragma unroll
    for (int nn = 0; nn < 4; ++nn) {
      const int row = m0 + wr * 64 + mm * 16 + lb * 4;
      const int col = n0 + wc * 64 + nn * 16 + la;
      const float bs = bias ? bias[col] : 0.f;
#pragma unroll
      for (int r = 0; r < 4; ++r)
        C[(size_t)(row + r) * N + col] = acc[mm][nn][r] + bs;
    }
}

// ---------------------------------------------------------------- persistent LN-LSTM layer
// (r6-proven kernel, kept verbatim as the fallback path.)
__global__ __launch_bounds__(256)
void k_lstm(const float* __restrict__ G, const unsigned short* __restrict__ WhT,
            const float* __restrict__ lng, const float* __restrict__ lnb,
            float* __restrict__ gf, unsigned short* __restrict__ Hout,
            unsigned* flags) {
  __shared__ unsigned short wh[16 * 1024];   // [col][k^((col&7)<<3)]
  __shared__ unsigned short hs[32 * 1024];   // [b][k^((b&7)<<3)] bf16
  __shared__ float crow[1024];
  __shared__ float red[4][32][16];
  __shared__ float rsc[64];

  const int tid = threadIdx.x;
  const int bid = blockIdx.x;
  const int lane = tid & 63, w = tid >> 6;
  const int la = lane & 15, lb = lane >> 4;
  unsigned* flag_g = flags;                  // 256 slots
  unsigned* flag_h = flags + 4096;           // 32 slots

  for (int i = tid * 8; i < 16 * 1024; i += 2048) {
    const int cl = i >> 10, k = i & 1023;
    *(short8*)&wh[cl * 1024 + (k ^ ((cl & 7) << 3))] = *(const short8*)&WhT[(size_t)bid * 16384 + i];
  }
  if (bid < 32)
    for (int e = tid; e < 1024; e += 256) crow[e] = 0.0f;

  for (int t = 0; t < T_; ++t) {
    if (t == 0) {
      const short8 z = {0, 0, 0, 0, 0, 0, 0, 0};
      for (int i = tid * 8; i < 32 * 1024; i += 2048) *(short8*)&hs[i] = z;
    } else {
      if (w == 0) wait_flags(flag_h, 32, (unsigned)t);
      __syncthreads();
      short8 tmp[16];
#pragma unroll
      for (int j = 0; j < 16; ++j) {
        const int i = tid * 8 + j * 2048;
        const int b = i >> 10, k = i & 1023;
        tmp[j] = ldg_coh16(&Hout[((size_t)(b * T_ + (t - 1))) * H_ + k]);
      }
      vmwait0();
#pragma unroll
      for (int j = 0; j < 16; ++j) {
        const int i = tid * 8 + j * 2048;
        const int b = i >> 10, k = i & 1023;
        *(short8*)&hs[b * 1024 + (k ^ ((b & 7) << 3))] = tmp[j];
      }
    }
    __syncthreads();

    f32x4 acc0 = {0.f, 0.f, 0.f, 0.f}, acc1 = {0.f, 0.f, 0.f, 0.f};
#pragma unroll
    for (int kk = 0; kk < 8; ++kk) {
      const int k = w * 256 + kk * 32 + lb * 8;
      const int kx = k ^ ((la & 7) << 3);
      const bf16x8 bv = *(bf16x8*)&wh[la * 1024 + kx];
      const bf16x8 a0 = *(bf16x8*)&hs[la * 1024 + kx];
      const bf16x8 a1 = *(bf16x8*)&hs[(16 + la) * 1024 + kx];
      acc0 = __builtin_amdgcn_mfma_f32_16x16x32_bf16(a0, bv, acc0, 0, 0, 0);
      acc1 = __builtin_amdgcn_mfma_f32_16x16x32_bf16(a1, bv, acc1, 0, 0, 0);
    }
#pragma unroll
    for (int r = 0; r < 4; ++r) {
      red[w][lb * 4 + r][la] = acc0[r];
      red[w][16 + lb * 4 + r][la] = acc1[r];
    }
    __syncthreads();
    {
      const int b2 = tid >> 3, c2 = (tid & 7) * 2;
      f32x2 sv;
      sv.x = red[0][b2][c2]     + red[1][b2][c2]     + red[2][b2][c2]     + red[3][b2][c2]
           + G[((size_t)(b2 * T_ + t)) * G4H_ + bid * 16 + c2];
      sv.y = red[0][b2][c2 + 1] + red[1][b2][c2 + 1] + red[2][b2][c2 + 1] + red[3][b2][c2 + 1]
           + G[((size_t)(b2 * T_ + t)) * G4H_ + bid * 16 + c2 + 1];
      stg_coh8f(&gf[b2 * G4H_ + bid * 16 + c2], sv);
    }
    __syncthreads();
    if (tid == 0)
      __hip_atomic_store(&flag_g[16 * bid], (unsigned)(t + 1), __ATOMIC_RELAXED, __HIP_MEMORY_SCOPE_AGENT);

    if (bid < 32) {
      if (w == 0) wait_flags(flag_g, 256, (unsigned)(t + 1));
      __syncthreads();
      const int b = bid;
      const int e0 = tid * 4;
      const f32x4 iv = ldg_coh16f(&gf[(size_t)b * G4H_ + e0]);
      const f32x4 jv = ldg_coh16f(&gf[(size_t)b * G4H_ + 1024 + e0]);
      const f32x4 fv = ldg_coh16f(&gf[(size_t)b * G4H_ + 2048 + e0]);
      const f32x4 ov = ldg_coh16f(&gf[(size_t)b * G4H_ + 3072 + e0]);
      vmwait0();

      float vals[8] = {0, 0, 0, 0, 0, 0, 0, 0};
#pragma unroll
      for (int u = 0; u < 4; ++u) {
        vals[0] += iv[u]; vals[4] += iv[u] * iv[u];
        vals[1] += jv[u]; vals[5] += jv[u] * jv[u];
        vals[2] += fv[u]; vals[6] += fv[u] * fv[u];
        vals[3] += ov[u]; vals[7] += ov[u] * ov[u];
      }
#pragma unroll
      for (int i = 0; i < 8; ++i) {
        float x = vals[i];
        for (int off = 32; off > 0; off >>= 1) x += __shfl_down(x, off);
        if (lane == 0) rsc[w * 8 + i] = x;
      }
      __syncthreads();
#pragma unroll
      for (int i = 0; i < 8; ++i)
        vals[i] = rsc[i] + rsc[8 + i] + rsc[16 + i] + rsc[24 + i];
      __syncthreads();
      const float m0 = vals[0] * (1.f / 1024), m1 = vals[1] * (1.f / 1024);
      const float m2 = vals[2] * (1.f / 1024), m3 = vals[3] * (1.f / 1024);
      const float r0 = rsqrtf(vals[4] * (1.f / 1024) - m0 * m0 + EPS_);
      const float r1 = rsqrtf(vals[5] * (1.f / 1024) - m1 * m1 + EPS_);
      const float r2 = rsqrtf(vals[6] * (1.f / 1024) - m2 * m2 + EPS_);
      const float r3 = rsqrtf(vals[7] * (1.f / 1024) - m3 * m3 + EPS_);

      const float4 gI = *(const float4*)&lng[e0];
      const float4 gJ = *(const float4*)&lng[1024 + e0];
      const float4 gF = *(const float4*)&lng[2048 + e0];
      const float4 gO = *(const float4*)&lng[3072 + e0];
      const float4 gC = *(const float4*)&lng[4096 + e0];
      const float4 bI = *(const float4*)&lnb[e0];
      const float4 bJ = *(const float4*)&lnb[1024 + e0];
      const float4 bF = *(const float4*)&lnb[2048 + e0];
      const float4 bO = *(const float4*)&lnb[3072 + e0];
      const float4 bC = *(const float4*)&lnb[4096 + e0];
      const float4 cr = *(const float4*)&crow[e0];

      float nc[4], oo[4];
      float cs = 0.f, cq = 0.f;
      {
        const float gi[4] = {gI.x, gI.y, gI.z, gI.w}, bi[4] = {bI.x, bI.y, bI.z, bI.w};
        const float gj[4] = {gJ.x, gJ.y, gJ.z, gJ.w}, bj[4] = {bJ.x, bJ.y, bJ.z, bJ.w};
        const float gff[4] = {gF.x, gF.y, gF.z, gF.w}, bf[4] = {bF.x, bF.y, bF.z, bF.w};
        const float go[4] = {gO.x, gO.y, gO.z, gO.w}, bo[4] = {bO.x, bO.y, bO.z, bO.w};
        const float cv[4] = {cr.x, cr.y, cr.z, cr.w};
#pragma unroll
        for (int u = 0; u < 4; ++u) {
          const float xi = gi[u] * ((iv[u] - m0) * r0) + bi[u];
          const float xj = gj[u] * ((jv[u] - m1) * r1) + bj[u];
          const float xf = gff[u] * ((fv[u] - m2) * r2) + bf[u];
          const float xo = go[u] * ((ov[u] - m3) * r3) + bo[u];
          const float ncv = cv[u] * sigm(xf + FB_) + sigm(xi) * tanhf(xj);
          nc[u] = ncv; oo[u] = xo;
          cs += ncv; cq += ncv * ncv;
        }
      }
      {
        float x = cs, y = cq;
        for (int off = 32; off > 0; off >>= 1) { x += __shfl_down(x, off); y += __shfl_down(y, off); }
        if (lane == 0) { rsc[w * 2] = x; rsc[w * 2 + 1] = y; }
      }
      __syncthreads();
      cs = rsc[0] + rsc[2] + rsc[4] + rsc[6];
      cq = rsc[1] + rsc[3] + rsc[5] + rsc[7];
      const float mc = cs * (1.f / 1024);
      const float rc = rsqrtf(cq * (1.f / 1024) - mc * mc + EPS_);
      {
        const float gc[4] = {gC.x, gC.y, gC.z, gC.w}, bc[4] = {bC.x, bC.y, bC.z, bC.w};
        unsigned short hb[4];
#pragma unroll
        for (int u = 0; u < 4; ++u) {
          const float nh = tanhf(gc[u] * ((nc[u] - mc) * rc) + bc[u]) * sigm(oo[u]);
          hb[u] = f2bf(nh);
        }
        u32x2 hv;
        hv[0] = (unsigned)hb[0] | ((unsigned)hb[1] << 16);
        hv[1] = (unsigned)hb[2] | ((unsigned)hb[3] << 16);
        stg_coh8u(&Hout[((size_t)(b * T_ + t)) * H_ + e0], hv);
        *(float4*)&crow[e0] = float4{nc[0], nc[1], nc[2], nc[3]};
      }
      __syncthreads();
      if (tid == 0)
        __hip_atomic_store(&flag_h[16 * bid], (unsigned)(t + 1), __ATOMIC_RELAXED, __HIP_MEMORY_SCOPE_AGENT);
    }
  }
}

// ---------------------------------------------------------------- fused 2-layer LN-LSTM
// (r10-proven: register-reduced K-loop halves, VGPR=140, launches cooperatively.)
__global__ __launch_bounds__(256)
void k_lstm2(const float* __restrict__ G, const unsigned short* __restrict__ WhT0,
             const unsigned short* __restrict__ WxT1, const unsigned short* __restrict__ WhT1,
             const float* __restrict__ b1,
             const float* __restrict__ lng, const float* __restrict__ lnb,
             float* __restrict__ gf0, float* __restrict__ gf1,
             unsigned short* __restrict__ Hb0, unsigned short* __restrict__ Hb1,
             unsigned* flags) {
  __shared__ unsigned short wh0[16 * 1024];  // [col][k^((col&7)<<3)]
  __shared__ unsigned short wx1[16 * 1024];
  __shared__ unsigned short wh1[16 * 1024];
  __shared__ float red[4][32][16];
  __shared__ float crow[1024];
  __shared__ float rsc[64];

  const int tid = threadIdx.x, bid = blockIdx.x;
  const int lane = tid & 63, w = tid >> 6;
  const int la = lane & 15, lb = lane >> 4;
  unsigned* flag_g0 = flags;                 // 256 slots
  unsigned* flag_g1 = flags + 4096;          // 256 slots
  unsigned* flag_h0 = flags + 8192;          // 32 slots
  unsigned* flag_h1 = flags + 8704;          // 32 slots

  for (int i = tid * 8; i < 16 * 1024; i += 2048) {
    const int cl = i >> 10, k = i & 1023;
    const int dst = cl * 1024 + (k ^ ((cl & 7) << 3));
    *(short8*)&wh0[dst] = *(const short8*)&WhT0[(size_t)bid * 16384 + i];
    *(short8*)&wx1[dst] = *(const short8*)&WxT1[(size_t)bid * 16384 + i];
    *(short8*)&wh1[dst] = *(const short8*)&WhT1[(size_t)bid * 16384 + i];
  }
  if (bid < 64)
    for (int e = tid; e < 1024; e += 256) crow[e] = 0.0f;
  __syncthreads();

  for (int s = 0; s <= T_; ++s) {
    if (w == 0) {
      if (s >= 1) wait_flags(flag_h0, 32, (unsigned)s);        // h0(s-1) ready
      if (s >= 2) wait_flags(flag_h1, 32, (unsigned)(s - 1));  // h1(s-2) ready
    }
    __syncthreads();

    f32x4 accA0 = {0.f,0.f,0.f,0.f}, accA1 = {0.f,0.f,0.f,0.f};
    f32x4 accB0 = {0.f,0.f,0.f,0.f}, accB1 = {0.f,0.f,0.f,0.f};
    f32x4 accC0 = {0.f,0.f,0.f,0.f}, accC1 = {0.f,0.f,0.f,0.f};
    if (s >= 1) {
      const int kw = w * 256 + lb * 8;
      const size_t t0 = (size_t)(s - 1);
      const size_t t1 = (size_t)(s - 2);
#pragma unroll
      for (int half = 0; half < 2; ++half) {
        short8 a0[4], a1[4], c0v[4], c1v[4];
        const int kb = kw + half * 128;
#pragma unroll
        for (int kk = 0; kk < 4; ++kk) {
          a0[kk] = ldg_coh16(&Hb0[((size_t)la * T_ + t0) * H_ + kb + kk * 32]);
          a1[kk] = ldg_coh16(&Hb0[((size_t)(16 + la) * T_ + t0) * H_ + kb + kk * 32]);
        }
        if (s >= 2) {
#pragma unroll
          for (int kk = 0; kk < 4; ++kk) {
            c0v[kk] = ldg_coh16(&Hb1[((size_t)la * T_ + t1) * H_ + kb + kk * 32]);
            c1v[kk] = ldg_coh16(&Hb1[((size_t)(16 + la) * T_ + t1) * H_ + kb + kk * 32]);
          }
        }
        vmwait0();
#pragma unroll
        for (int kk = 0; kk < 4; ++kk) {
          const int kx = (kb + kk * 32) ^ ((la & 7) << 3);
          const bf16x8 va0 = __builtin_bit_cast(bf16x8, a0[kk]);
          const bf16x8 va1 = __builtin_bit_cast(bf16x8, a1[kk]);
          const bf16x8 bB = *(bf16x8*)&wx1[la * 1024 + kx];
          accB0 = __builtin_amdgcn_mfma_f32_16x16x32_bf16(va0, bB, accB0, 0, 0, 0);
          accB1 = __builtin_amdgcn_mfma_f32_16x16x32_bf16(va1, bB, accB1, 0, 0, 0);
          if (s < T_) {
            const bf16x8 bA = *(bf16x8*)&wh0[la * 1024 + kx];
            accA0 = __builtin_amdgcn_mfma_f32_16x16x32_bf16(va0, bA, accA0, 0, 0, 0);
            accA1 = __builtin_amdgcn_mfma_f32_16x16x32_bf16(va1, bA, accA1, 0, 0, 0);
          }
          if (s >= 2) {
            const bf16x8 bC = *(bf16x8*)&wh1[la * 1024 + kx];
            const bf16x8 vc0 = __builtin_bit_cast(bf16x8, c0v[kk]);
            const bf16x8 vc1 = __builtin_bit_cast(bf16x8, c1v[kk]);
            accC0 = __builtin_amdgcn_mfma_f32_16x16x32_bf16(vc0, bC, accC0, 0, 0, 0);
            accC1 = __builtin_amdgcn_mfma_f32_16x16x32_bf16(vc1, bC, accC1, 0, 0, 0);
          }
        }
      }
    }

    // ---- gf0 = G[s] + A
#pragma unroll
    for (int r = 0; r < 4; ++r) {
      red[w][lb * 4 + r][la] = accA0[r];
      red[w][16 + lb * 4 + r][la] = accA1[r];
    }
    __syncthreads();
    if (s < T_) {
      const int b2 = tid >> 3, c2 = (tid & 7) * 2;
      f32x2 sv;
      sv.x = red[0][b2][c2]     + red[1][b2][c2]     + red[2][b2][c2]     + red[3][b2][c2]
           + G[((size_t)(b2 * T_ + s)) * G4H_ + bid * 16 + c2];
      sv.y = red[0][b2][c2 + 1] + red[1][b2][c2 + 1] + red[2][b2][c2 + 1] + red[3][b2][c2 + 1]
           + G[((size_t)(b2 * T_ + s)) * G4H_ + bid * 16 + c2 + 1];
      stg_coh8f(&gf0[b2 * G4H_ + bid * 16 + c2], sv);
    }
    __syncthreads();
    if (tid == 0 && s < T_)
      __hip_atomic_store(&flag_g0[16 * bid], (unsigned)(s + 1), __ATOMIC_RELAXED, __HIP_MEMORY_SCOPE_AGENT);

    // ---- gf1 = b1 + B + C
#pragma unroll
    for (int r = 0; r < 4; ++r) {
      red[w][lb * 4 + r][la] = accB0[r] + accC0[r];
      red[w][16 + lb * 4 + r][la] = accB1[r] + accC1[r];
    }
    __syncthreads();
    if (s >= 1) {
      const int b2 = tid >> 3, c2 = (tid & 7) * 2;
      f32x2 sv;
      sv.x = red[0][b2][c2]     + red[1][b2][c2]     + red[2][b2][c2]     + red[3][b2][c2]
           + b1[bid * 16 + c2];
      sv.y = red[0][b2][c2 + 1] + red[1][b2][c2 + 1] + red[2][b2][c2 + 1] + red[3][b2][c2 + 1]
           + b1[bid * 16 + c2 + 1];
      stg_coh8f(&gf1[b2 * G4H_ + bid * 16 + c2], sv);
    }
    __syncthreads();
    if (tid == 0 && s >= 1)
      __hip_atomic_store(&flag_g1[16 * bid], (unsigned)(s + 1), __ATOMIC_RELAXED, __HIP_MEMORY_SCOPE_AGENT);

    // ---- phase 2: LN + pointwise (blocks 0-31: L0 time s; 32-63: L1 time s-1)
    const bool isP2 = (bid < 32) ? (s < T_) : (bid < 64 ? (s >= 1) : false);
    if (isP2) {
      const bool L1p = (bid >= 32);
      const int b = L1p ? (bid - 32) : bid;
      if (w == 0) wait_flags(L1p ? flag_g1 : flag_g0, 256, (unsigned)(s + 1));
      __syncthreads();
      const float* gfp = (L1p ? gf1 : gf0) + (size_t)b * G4H_;
      const float* g_ = L1p ? (lng + 5120) : lng;
      const float* b_ = L1p ? (lnb + 5120) : lnb;
      const int tt = L1p ? (s - 1) : s;
      unsigned short* hout = (L1p ? Hb1 : Hb0) + ((size_t)b * T_ + tt) * H_;

      const int e0 = tid * 4;
      const f32x4 iv = ldg_coh16f(&gfp[e0]);
      const f32x4 jv = ldg_coh16f(&gfp[1024 + e0]);
      const f32x4 fv = ldg_coh16f(&gfp[2048 + e0]);
      const f32x4 ov = ldg_coh16f(&gfp[3072 + e0]);
      vmwait0();

      float vals[8] = {0, 0, 0, 0, 0, 0, 0, 0};
#pragma unroll
      for (int u = 0; u < 4; ++u) {
        vals[0] += iv[u]; vals[4] += iv[u] * iv[u];
        vals[1] += jv[u]; vals[5] += jv[u] * jv[u];
        vals[2] += fv[u]; vals[6] += fv[u] * fv[u];
        vals[3] += ov[u]; vals[7] += ov[u] * ov[u];
      }
#pragma unroll
      for (int i = 0; i < 8; ++i) {
        float x = vals[i];
        for (int off = 32; off > 0; off >>= 1) x += __shfl_down(x, off);
        if (lane == 0) rsc[w * 8 + i] = x;
      }
      __syncthreads();
#pragma unroll
      for (int i = 0; i < 8; ++i)
        vals[i] = rsc[i] + rsc[8 + i] + rsc[16 + i] + rsc[24 + i];
      __syncthreads();
      const float m0 = vals[0] * (1.f / 1024), m1 = vals[1] * (1.f / 1024);
      const float m2 = vals[2] * (1.f / 1024), m3 = vals[3] * (1.f / 1024);
      const float r0 = rsqrtf(vals[4] * (1.f / 1024) - m0 * m0 + EPS_);
      const float r1 = rsqrtf(vals[5] * (1.f / 1024) - m1 * m1 + EPS_);
      const float r2 = rsqrtf(vals[6] * (1.f / 1024) - m2 * m2 + EPS_);
      const float r3 = rsqrtf(vals[7] * (1.f / 1024) - m3 * m3 + EPS_);

      const float4 gI = *(const float4*)&g_[e0];
      const float4 gJ = *(const float4*)&g_[1024 + e0];
      const float4 gF = *(const float4*)&g_[2048 + e0];
      const float4 gO = *(const float4*)&g_[3072 + e0];
      const float4 gC = *(const float4*)&g_[4096 + e0];
      const float4 bI = *(const float4*)&b_[e0];
      const float4 bJ = *(const float4*)&b_[1024 + e0];
      const float4 bF = *(const float4*)&b_[2048 + e0];
      const float4 bO = *(const float4*)&b_[3072 + e0];
      const float4 bC = *(const float4*)&b_[4096 + e0];
      const float4 cr = *(const float4*)&crow[e0];

      float nc[4], oo[4];
      float cs = 0.f, cq = 0.f;
      {
        const float gi[4] = {gI.x, gI.y, gI.z, gI.w}, bi[4] = {bI.x, bI.y, bI.z, bI.w};
        const float gj[4] = {gJ.x, gJ.y, gJ.z, gJ.w}, bj[4] = {bJ.x, bJ.y, bJ.z, bJ.w};
        const float gff[4] = {gF.x, gF.y, gF.z, gF.w}, bf[4] = {bF.x, bF.y, bF.z, bF.w};
        const float go[4] = {gO.x, gO.y, gO.z, gO.w}, bo[4] = {bO.x, bO.y, bO.z, bO.w};
        const float cv[4] = {cr.x, cr.y, cr.z, cr.w};
#pragma unroll
        for (int u = 0; u < 4; ++u) {
          const float xi = gi[u] * ((iv[u] - m0) * r0) + bi[u];
          const float xj = gj[u] * ((jv[u] - m1) * r1) + bj[u];
          const float xf = gff[u] * ((fv[u] - m2) * r2) + bf[u];
          const float xo = go[u] * ((ov[u] - m3) * r3) + bo[u];
          const float ncv = cv[u] * sigm(xf + FB_) + sigm(xi) * tanhf(xj);
          nc[u] = ncv; oo[u] = xo;
          cs += ncv; cq += ncv * ncv;
        }
      }
      {
        float x = cs, y = cq;
        for (int off = 32; off > 0; off >>= 1) { x += __shfl_down(x, off); y += __shfl_down(y, off); }
        if (lane == 0) { rsc[w * 2] = x; rsc[w * 2 + 1] = y; }
      }
      __syncthreads();
      cs = rsc[0] + rsc[2] + rsc[4] + rsc[6];
      cq = rsc[1] + rsc[3] + rsc[5] + rsc[7];
      const float mc = cs * (1.f / 1024);
      const float rc = rsqrtf(cq * (1.f / 1024) - mc * mc + EPS_);
      {
        const float gc[4] = {gC.x, gC.y, gC.z, gC.w}, bc[4] = {bC.x, bC.y, bC.z, bC.w};
        unsigned short hb[4];
#pragma unroll
        for (int u = 0; u < 4; ++u) {
          const float nh = tanhf(gc[u] * ((nc[u] - mc) * rc) + bc[u]) * sigm(oo[u]);
          hb[u] = f2bf(nh);
        }
        u32x2 hv;
        hv[0] = (unsigned)hb[0] | ((unsigned)hb[1] << 16);
        hv[1] = (unsigned)hb[2] | ((unsigned)hb[3] << 16);
        stg_coh8u(&hout[e0], hv);
        *(float4*)&crow[e0] = float4{nc[0], nc[1], nc[2], nc[3]};
      }
      __syncthreads();
      if (tid == 0) {
        if (L1p)
          __hip_atomic_store(&flag_h1[16 * b], (unsigned)s, __ATOMIC_RELAXED, __HIP_MEMORY_SCOPE_AGENT);
        else
          __hip_atomic_store(&flag_h0[16 * b], (unsigned)(s + 1), __ATOMIC_RELAXED, __HIP_MEMORY_SCOPE_AGENT);
      }
    }
  }
}

// ---------------------------------------------------------------- per-row logsumexp (single-pass online)
__global__ __launch_bounds__(256)
void k_lse(const float* __restrict__ logits, float* __restrict__ lse) {
  __shared__ float rm[4];
  __shared__ float rs[4];
  const int r = blockIdx.x, tid = threadIdx.x;
  const int lane = tid & 63, w = tid >> 6;
  const float* row = logits + (size_t)r * V_;
  float m = -1e30f, s = 0.f;
  for (int e = tid * 4; e < V_; e += 1024) {
    const float4 v = *(const float4*)&row[e];
    const float xs[4] = {v.x, v.y, v.z, v.w};
#pragma unroll
    for (int j = 0; j < 4; ++j) {
      const float x = xs[j];
      const float nm = fmaxf(m, x);
      s = s * __expf(m - nm) + __expf(x - nm);
      m = nm;
    }
  }
  for (int off = 32; off > 0; off >>= 1) {
    const float m2 = __shfl_down(m, off);
    const float s2 = __shfl_down(s, off);
    const float nm = fmaxf(m, m2);
    s = s * __expf(m - nm) + s2 * __expf(m2 - nm);
    m = nm;
  }
  if (lane == 0) { rm[w] = m; rs[w] = s; }
  __syncthreads();
  if (tid == 0) {
    float M = rm[0], S = rs[0];
#pragma unroll
    for (int i = 1; i < 4; ++i) {
      const float nm = fmaxf(M, rm[i]);
      S = S * __expf(M - nm) + rs[i] * __expf(rm[i] - nm);
      M = nm;
    }
    lse[r] = M + logf(S);
  }
}

// ---------------------------------------------------------------- loss (mean NLL)
__global__ __launch_bounds__(256)
void k_loss(const float* __restrict__ logits, const float* __restrict__ lse,
            const int* __restrict__ tgt, float* __restrict__ out) {
  __shared__ float rsc[4];
  const int tid = threadIdx.x;
  float s = 0.f;
  for (int r = tid; r < BT_; r += 256)
    s += lse[r] - logits[(size_t)r * V_ + tgt[r]];
  for (int off = 32; off > 0; off >>= 1) s += __shfl_down(s, off);
  if ((tid & 63) == 0) rsc[tid >> 6] = s;
  __syncthreads();
  if (tid == 0) out[(size_t)BT_ * V_] = (rsc[0] + rsc[1] + rsc[2] + rsc[3]) / (float)BT_;
}

// ================================================================ launch
// Fused cooperative kernel with CHECKED launch; on rejection, fall back to the
// r6-proven two-kernel sequence (identical outputs either way).
// ws layout totals ~191.4 MB (ws budget ~192 MB — r3/r7/r8 lesson): gf0/gf1/
// bars/lseb alias the Xemb region, dead after the L0 x-part GEMM.
extern "C" void kernel_launch(void* const* d_in, const int* in_sizes, int n_in,
                              void* d_out, int out_size, void* d_ws, size_t ws_size,
                              hipStream_t stream) {
  const int*   ids  = (const int*)d_in[0];
  const int*   tgt  = (const int*)d_in[1];
  const float* emb  = (const float*)d_in[2];
  const float* W    = (const float*)d_in[3];   // [2][2048][4096]
  const float* brnn = (const float*)d_in[4];   // [2][4096]
  const float* lng  = (const float*)d_in[5];   // [2][5][1024]
  const float* lnb  = (const float*)d_in[6];
  const float* sw   = (const float*)d_in[7];   // [1024][32000]
  const float* sb   = (const float*)d_in[8];   // [32000]
  float* out = (float*)d_out;

  char* ws = (char*)d_ws;
  size_t o = 0;
  auto take = [&](size_t n) { char* p = ws + o; o += (n + 255) & ~(size_t)255; return p; };
  unsigned short* WxT0 = (unsigned short*)take((size_t)G4H_ * H_ * 2);       // 8 MB
  unsigned short* WhT0 = (unsigned short*)take((size_t)G4H_ * H_ * 2);       // 8 MB
  unsigned short* WxT1 = (unsigned short*)take((size_t)G4H_ * H_ * 2);       // 8 MB
  unsigned short* WhT1 = (unsigned short*)take((size_t)G4H_ * H_ * 2);       // 8 MB
  unsigned short* WsT  = (unsigned short*)take((size_t)V_ * H_ * 2);         // 65.5 MB
  unsigned short* Xemb = (unsigned short*)take((size_t)BT_ * H_ * 2);        // 8 MB
  float*          Gbuf = (float*)take((size_t)BT_ * G4H_ * 4);               // 64 MB
  unsigned short* Hb0  = (unsigned short*)take((size_t)BT_ * H_ * 2);        // 8 MB
  unsigned short* Hb1  = (unsigned short*)take((size_t)BT_ * H_ * 2);        // 8 MB
  // aliased into the Xemb region (dead after the L0 x-part GEMM)
  char* xregion = (char*)Xemb;
  float*    gf0  = (float*)(xregion);                    // 524,288 B
  float*    gf1  = (float*)(xregion + 524288);           // 524,288 B
  unsigned* bars = (unsigned*)(xregion + 1048576);       //  40,960 B
  float*    lseb = (float*)(xregion + 1089536);          //  16,384 B

  const dim3 tb(32, 8);
  k_transpose_cast<<<dim3(128, 32),  tb, 0, stream>>>(W,                    WxT0, 1024, 4096, 4096);
  k_transpose_cast<<<dim3(128, 32),  tb, 0, stream>>>(W + 1024 * 4096,      WhT0, 1024, 4096, 4096);
  k_transpose_cast<<<dim3(128, 32),  tb, 0, stream>>>(W + 2048 * 4096,      WxT1, 1024, 4096, 4096);
  k_transpose_cast<<<dim3(128, 32),  tb, 0, stream>>>(W + 3072 * 4096,      WhT1, 1024, 4096, 4096);
  k_transpose_cast<<<dim3(1000, 32), tb, 0, stream>>>(sw,                   WsT,  1024, V_,  V_);

  k_gather<<<BT_, 256, 0, stream>>>(ids, emb, Xemb);

  // layer-0 x-part precompute: Gbuf = Xemb @ Wx0^T + b0  (last use of Xemb)
  k_gemm_bt<<<dim3(32, 32), 256, 0, stream>>>(Xemb, WxT0, brnn, Gbuf, BT_, G4H_, H_);

  // Xemb region now dead: zero the flag slots (stream-ordered)
  hipMemsetAsync(bars, 0, 40960, stream);

  // ---- try the fused 2-layer cooperative kernel
  const float* G_ = Gbuf;
  const unsigned short* Wh0_ = WhT0; const unsigned short* Wx1_ = WxT1; const unsigned short* Wh1_ = WhT1;
  const float* b1_ = brnn + 4096;
  const float* g0_ = lng;        const float* bb0_ = lnb;
  const float* g1_ = lng + 5120; const float* bb1_ = lnb + 5120;
  float* gf0_ = gf0; float* gf1_ = gf1;
  unsigned short* H0_ = Hb0; unsigned short* H1_ = Hb1;
  unsigned* bars_ = bars;

  hipError_t ce;
  {
    void* args[] = {&G_, &Wh0_, &Wx1_, &Wh1_, &b1_, &g0_, &bb0_, &gf0_, &gf1_, &H0_, &H1_, &bars_};
    ce = hipLaunchCooperativeKernel((void*)k_lstm2, dim3(256), dim3(256), args, 0, stream);
  }
  if (ce != hipSuccess) {
    // ---- fallback: r6-proven two-kernel sequence (bars already zeroed)
    {
      void* a0[] = {&G_, &Wh0_, &g0_, &bb0_, &gf0_, &H0_, &bars_};
      hipLaunchCooperativeKernel((void*)k_lstm, dim3(256), dim3(256), a0, 0, stream);
    }
    hipMemsetAsync(bars, 0, 40960, stream);
    k_gemm_bt<<<dim3(32, 32), 256, 0, stream>>>(Hb0, WxT1, brnn + 4096, Gbuf, BT_, G4H_, H_);
    {
      void* a1[] = {&G_, &Wh1_, &g1_, &bb1_, &gf0_, &H1_, &bars_};
      hipLaunchCooperativeKernel((void*)k_lstm, dim3(256), dim3(256), a1, 0, stream);
    }
  }

  // projection -> logits (d_out) ; then logsumexp + loss
  k_gemm_bt<<<dim3(250, 32), 256, 0, stream>>>(Hb1, WsT, sb, out, BT_, V_, H_);
  k_lse<<<BT_, 256, 0, stream>>>(out, lseb);
  k_loss<<<1, 256, 0, stream>>>(out, lseb, tgt, out);
}

// Round 12
// 2422.988 us; speedup vs baseline: 7.3100x; 1.0075x over previous
//
#include <hip/hip_runtime.h>
#include <hip/hip_cooperative_groups.h>

#define V_    32000
#define B_    32
#define T_    128
#define H_    1024
#define BT_   4096     // B_*T_
#define G4H_  4096     // 4*H_
#define EPS_  1e-5f
#define FB_   1.0f     // forget bias

typedef __bf16  bf16x8 __attribute__((ext_vector_type(8)));
typedef float   f32x4  __attribute__((ext_vector_type(4)));
typedef float   f32x2  __attribute__((ext_vector_type(2)));
typedef unsigned u32x2 __attribute__((ext_vector_type(2)));
typedef short   short8 __attribute__((ext_vector_type(8)));

__device__ __forceinline__ unsigned short f2bf(float f) {
  unsigned u = __builtin_bit_cast(unsigned, f);
  u = u + 0x7FFFu + ((u >> 16) & 1u);          // round-to-nearest-even
  return (unsigned short)(u >> 16);
}
__device__ __forceinline__ float sigm(float x) { return 1.0f / (1.0f + expf(-x)); }

// ---------------------------------------------------------------- LLC-coherent access
__device__ __forceinline__ short8 ldg_coh16(const unsigned short* p) {
  short8 v;
  asm volatile("global_load_dwordx4 %0, %1, off sc0 sc1" : "=v"(v) : "v"(p) : "memory");
  return v;
}
__device__ __forceinline__ f32x4 ldg_coh16f(const float* p) {
  f32x4 v;
  asm volatile("global_load_dwordx4 %0, %1, off sc0 sc1" : "=v"(v) : "v"(p) : "memory");
  return v;
}
__device__ __forceinline__ void stg_coh8f(float* p, f32x2 v) {
  asm volatile("global_store_dwordx2 %0, %1, off sc0 sc1" :: "v"(p), "v"(v) : "memory");
}
__device__ __forceinline__ void stg_coh8u(unsigned short* p, u32x2 v) {
  asm volatile("global_store_dwordx2 %0, %1, off sc0 sc1" :: "v"(p), "v"(v) : "memory");
}
__device__ __forceinline__ void vmwait0() {
  asm volatile("s_waitcnt vmcnt(0)" ::: "memory");
  __builtin_amdgcn_sched_barrier(0);           // rule #18: pin consumers after the wait
}

// ---------------------------------------------------------------- dataflow flag sync
__device__ __forceinline__ void wait_flags(unsigned* flags, int nslots, unsigned tgt) {
  const int lane = threadIdx.x & 63;
  for (;;) {
    unsigned v = 0xFFFFFFFFu;
    for (int s = lane; s < nslots; s += 64) {
      const unsigned x = __hip_atomic_load(&flags[16 * s], __ATOMIC_RELAXED, __HIP_MEMORY_SCOPE_AGENT);
      v = x < v ? x : v;
    }
    if (__all((int)(v >= tgt))) break;
    __builtin_amdgcn_s_sleep(1);
  }
}

// ---------------------------------------------------------------- transpose+cast
__global__ void k_transpose_cast(const float* __restrict__ in, unsigned short* __restrict__ out,
                                 int R, int C, int ldin) {
  __shared__ float tl[32][33];
  const int tx = threadIdx.x, ty = threadIdx.y;
  const int r0 = blockIdx.y * 32, c0 = blockIdx.x * 32;
#pragma unroll
  for (int i = 0; i < 4; ++i)
    tl[ty + 8 * i][tx] = in[(size_t)(r0 + ty + 8 * i) * ldin + c0 + tx];
  __syncthreads();
#pragma unroll
  for (int i = 0; i < 4; ++i)
    out[(size_t)(c0 + ty + 8 * i) * R + r0 + tx] = f2bf(tl[tx][ty + 8 * i]);
}

// ---------------------------------------------------------------- embedding gather
__global__ void k_gather(const int* __restrict__ ids, const float* __restrict__ emb,
                         unsigned short* __restrict__ x) {
  const int r = blockIdx.x;
  const int t4 = threadIdx.x * 4;
  const int row = ids[r];
  const float4 v = *(const float4*)&emb[(size_t)row * H_ + t4];
  ushort4 o;
  o.x = f2bf(v.x); o.y = f2bf(v.y); o.z = f2bf(v.z); o.w = f2bf(v.w);
  *(ushort4*)&x[(size_t)r * H_ + t4] = o;
}

// ---------------------------------------------------------------- bf16 GEMM, C = A * BT^T + bias
// width-16 global_load_lds staging; XCD-aware bijective block swizzle (nwg%8==0
// in all call sites); optional fused per-row online-LSE partials (lse_part !=
// nullptr): per (row, col-tile, wc-wave) one float2{max, expsum} written to
// lse_part[row*512 + bx*2 + wc] (500 of 512 slots used; combined by k_lse_finish).
__global__ __launch_bounds__(256)
void k_gemm_bt(const unsigned short* __restrict__ A, const unsigned short* __restrict__ BT,
               const float* __restrict__ bias, float* __restrict__ C,
               int M, int N, int K, float* __restrict__ lse_part) {
  __shared__ unsigned short As[128 * 32];
  __shared__ unsigned short Bs[128 * 32];
  const int tid = threadIdx.x;
  const int lane = tid & 63, wid = tid >> 6;
  const int wr = wid >> 1, wc = wid & 1;
  const int la = lane & 15, lb = lane >> 4;

  // XCD swizzle: original flat id's %8 = XCD; give each XCD a contiguous chunk.
  int flat = blockIdx.y * gridDim.x + blockIdx.x;
  const int nwg = gridDim.x * gridDim.y;       // divisible by 8 at all call sites
  const int cpx = nwg >> 3;
  flat = (flat & 7) * cpx + (flat >> 3);
  const int bx = flat % gridDim.x, by = flat / gridDim.x;
  const int m0 = by * 128, n0 = bx * 128;

  f32x4 acc[4][4];
#pragma unroll
  for (int i = 0; i < 4; ++i)
#pragma unroll
    for (int j = 0; j < 4; ++j) acc[i][j] = f32x4{0.f, 0.f, 0.f, 0.f};

  for (int k0 = 0; k0 < K; k0 += 32) {
    __syncthreads();
#pragma unroll
    for (int i = 0; i < 2; ++i) {
      const int off = i * 2048 + tid * 8;
      const int row = off >> 5, col = off & 31;
      __builtin_amdgcn_global_load_lds(
          (const __attribute__((address_space(1))) void*)&A[(size_t)(m0 + row) * K + k0 + col],
          (__attribute__((address_space(3))) void*)&As[off], 16, 0, 0);
      __builtin_amdgcn_global_load_lds(
          (const __attribute__((address_space(1))) void*)&BT[(size_t)(n0 + row) * K + k0 + col],
          (__attribute__((address_space(3))) void*)&Bs[off], 16, 0, 0);
    }
    __syncthreads();
    bf16x8 a[4], b[4];
#pragma unroll
    for (int mm = 0; mm < 4; ++mm) a[mm] = *(bf16x8*)&As[(wr * 64 + mm * 16 + la) * 32 + lb * 8];
#pragma unroll
    for (int nn = 0; nn < 4; ++nn) b[nn] = *(bf16x8*)&Bs[(wc * 64 + nn * 16 + la) * 32 + lb * 8];
#pragma unroll
    for (int mm = 0; mm < 4; ++mm)
#pragma unroll
      for (int nn = 0; nn < 4; ++nn)
        acc[mm][nn] = __builtin_amdgcn_mfma_f32_16x16x32_bf16(a[mm], b[nn], acc[mm][nn], 0, 0, 0);
  }
#pragma unroll
  for (int mm = 0; mm < 4; ++mm)
#pragma unroll
    for (int nn = 0; nn < 4; ++nn) {
      const int row = m0 + wr * 64 + mm * 16 + lb * 4;
      const int col = n0 + wc * 64 + nn * 16 + la;
      const float bs = bias ? bias[col] : 0.f;
#pragma unroll
      for (int r = 0; r < 4; ++r)
        C[(size_t)(row + r) * N + col] = acc[mm][nn][r] + bs;
    }

  // ---- fused online-LSE partials (per row: max + expsum over this tile's 128 cols)
  if (lse_part) {
#pragma unroll
    for (int mm = 0; mm < 4; ++mm)
#pragma unroll
      for (int r = 0; r < 4; ++r) {
        float vv[4];
        float mx = -1e30f;
#pragma unroll
        for (int nn = 0; nn < 4; ++nn) {
          vv[nn] = acc[mm][nn][r] + (bias ? bias[n0 + wc * 64 + nn * 16 + la] : 0.f);
          mx = fmaxf(mx, vv[nn]);
        }
        float ss = 0.f;
#pragma unroll
        for (int nn = 0; nn < 4; ++nn) ss += __expf(vv[nn] - mx);
        // reduce across the 16 la-lanes (lane = lb*16+la; xor masks stay in-group)
#pragma unroll
        for (int msk = 1; msk < 16; msk <<= 1) {
          const float m2 = __shfl_xor(mx, msk);
          const float s2 = __shfl_xor(ss, msk);
          const float nm = fmaxf(mx, m2);
          ss = ss * __expf(mx - nm) + s2 * __expf(m2 - nm);
          mx = nm;
        }
        if (la == 0) {
          const int row = m0 + wr * 64 + mm * 16 + lb * 4 + r;
          *(float2*)&lse_part[((size_t)row * 512 + (size_t)bx * 2 + wc) * 2] = float2{mx, ss};
        }
      }
  }
}

// ---------------------------------------------------------------- persistent LN-LSTM layer
// (r6-proven kernel, kept verbatim as the fallback path.)
__global__ __launch_bounds__(256)
void k_lstm(const float* __restrict__ G, const unsigned short* __restrict__ WhT,
            const float* __restrict__ lng, const float* __restrict__ lnb,
            float* __restrict__ gf, unsigned short* __restrict__ Hout,
            unsigned* flags) {
  __shared__ unsigned short wh[16 * 1024];   // [col][k^((col&7)<<3)]
  __shared__ unsigned short hs[32 * 1024];   // [b][k^((b&7)<<3)] bf16
  __shared__ float crow[1024];
  __shared__ float red[4][32][16];
  __shared__ float rsc[64];

  const int tid = threadIdx.x;
  const int bid = blockIdx.x;
  const int lane = tid & 63, w = tid >> 6;
  const int la = lane & 15, lb = lane >> 4;
  unsigned* flag_g = flags;                  // 256 slots
  unsigned* flag_h = flags + 4096;           // 32 slots

  for (int i = tid * 8; i < 16 * 1024; i += 2048) {
    const int cl = i >> 10, k = i & 1023;
    *(short8*)&wh[cl * 1024 + (k ^ ((cl & 7) << 3))] = *(const short8*)&WhT[(size_t)bid * 16384 + i];
  }
  if (bid < 32)
    for (int e = tid; e < 1024; e += 256) crow[e] = 0.0f;

  for (int t = 0; t < T_; ++t) {
    if (t == 0) {
      const short8 z = {0, 0, 0, 0, 0, 0, 0, 0};
      for (int i = tid * 8; i < 32 * 1024; i += 2048) *(short8*)&hs[i] = z;
    } else {
      if (w == 0) wait_flags(flag_h, 32, (unsigned)t);
      __syncthreads();
      short8 tmp[16];
#pragma unroll
      for (int j = 0; j < 16; ++j) {
        const int i = tid * 8 + j * 2048;
        const int b = i >> 10, k = i & 1023;
        tmp[j] = ldg_coh16(&Hout[((size_t)(b * T_ + (t - 1))) * H_ + k]);
      }
      vmwait0();
#pragma unroll
      for (int j = 0; j < 16; ++j) {
        const int i = tid * 8 + j * 2048;
        const int b = i >> 10, k = i & 1023;
        *(short8*)&hs[b * 1024 + (k ^ ((b & 7) << 3))] = tmp[j];
      }
    }
    __syncthreads();

    f32x4 acc0 = {0.f, 0.f, 0.f, 0.f}, acc1 = {0.f, 0.f, 0.f, 0.f};
#pragma unroll
    for (int kk = 0; kk < 8; ++kk) {
      const int k = w * 256 + kk * 32 + lb * 8;
      const int kx = k ^ ((la & 7) << 3);
      const bf16x8 bv = *(bf16x8*)&wh[la * 1024 + kx];
      const bf16x8 a0 = *(bf16x8*)&hs[la * 1024 + kx];
      const bf16x8 a1 = *(bf16x8*)&hs[(16 + la) * 1024 + kx];
      acc0 = __builtin_amdgcn_mfma_f32_16x16x32_bf16(a0, bv, acc0, 0, 0, 0);
      acc1 = __builtin_amdgcn_mfma_f32_16x16x32_bf16(a1, bv, acc1, 0, 0, 0);
    }
#pragma unroll
    for (int r = 0; r < 4; ++r) {
      red[w][lb * 4 + r][la] = acc0[r];
      red[w][16 + lb * 4 + r][la] = acc1[r];
    }
    __syncthreads();
    {
      const int b2 = tid >> 3, c2 = (tid & 7) * 2;
      f32x2 sv;
      sv.x = red[0][b2][c2]     + red[1][b2][c2]     + red[2][b2][c2]     + red[3][b2][c2]
           + G[((size_t)(b2 * T_ + t)) * G4H_ + bid * 16 + c2];
      sv.y = red[0][b2][c2 + 1] + red[1][b2][c2 + 1] + red[2][b2][c2 + 1] + red[3][b2][c2 + 1]
           + G[((size_t)(b2 * T_ + t)) * G4H_ + bid * 16 + c2 + 1];
      stg_coh8f(&gf[b2 * G4H_ + bid * 16 + c2], sv);
    }
    __syncthreads();
    if (tid == 0)
      __hip_atomic_store(&flag_g[16 * bid], (unsigned)(t + 1), __ATOMIC_RELAXED, __HIP_MEMORY_SCOPE_AGENT);

    if (bid < 32) {
      if (w == 0) wait_flags(flag_g, 256, (unsigned)(t + 1));
      __syncthreads();
      const int b = bid;
      const int e0 = tid * 4;
      const f32x4 iv = ldg_coh16f(&gf[(size_t)b * G4H_ + e0]);
      const f32x4 jv = ldg_coh16f(&gf[(size_t)b * G4H_ + 1024 + e0]);
      const f32x4 fv = ldg_coh16f(&gf[(size_t)b * G4H_ + 2048 + e0]);
      const f32x4 ov = ldg_coh16f(&gf[(size_t)b * G4H_ + 3072 + e0]);
      vmwait0();

      float vals[8] = {0, 0, 0, 0, 0, 0, 0, 0};
#pragma unroll
      for (int u = 0; u < 4; ++u) {
        vals[0] += iv[u]; vals[4] += iv[u] * iv[u];
        vals[1] += jv[u]; vals[5] += jv[u] * jv[u];
        vals[2] += fv[u]; vals[6] += fv[u] * fv[u];
        vals[3] += ov[u]; vals[7] += ov[u] * ov[u];
      }
#pragma unroll
      for (int i = 0; i < 8; ++i) {
        float x = vals[i];
        for (int off = 32; off > 0; off >>= 1) x += __shfl_down(x, off);
        if (lane == 0) rsc[w * 8 + i] = x;
      }
      __syncthreads();
#pragma unroll
      for (int i = 0; i < 8; ++i)
        vals[i] = rsc[i] + rsc[8 + i] + rsc[16 + i] + rsc[24 + i];
      __syncthreads();
      const float m0 = vals[0] * (1.f / 1024), m1 = vals[1] * (1.f / 1024);
      const float m2 = vals[2] * (1.f / 1024), m3 = vals[3] * (1.f / 1024);
      const float r0 = rsqrtf(vals[4] * (1.f / 1024) - m0 * m0 + EPS_);
      const float r1 = rsqrtf(vals[5] * (1.f / 1024) - m1 * m1 + EPS_);
      const float r2 = rsqrtf(vals[6] * (1.f / 1024) - m2 * m2 + EPS_);
      const float r3 = rsqrtf(vals[7] * (1.f / 1024) - m3 * m3 + EPS_);

      const float4 gI = *(const float4*)&lng[e0];
      const float4 gJ = *(const float4*)&lng[1024 + e0];
      const float4 gF = *(const float4*)&lng[2048 + e0];
      const float4 gO = *(const float4*)&lng[3072 + e0];
      const float4 gC = *(const float4*)&lng[4096 + e0];
      const float4 bI = *(const float4*)&lnb[e0];
      const float4 bJ = *(const float4*)&lnb[1024 + e0];
      const float4 bF = *(const float4*)&lnb[2048 + e0];
      const float4 bO = *(const float4*)&lnb[3072 + e0];
      const float4 bC = *(const float4*)&lnb[4096 + e0];
      const float4 cr = *(const float4*)&crow[e0];

      float nc[4], oo[4];
      float cs = 0.f, cq = 0.f;
      {
        const float gi[4] = {gI.x, gI.y, gI.z, gI.w}, bi[4] = {bI.x, bI.y, bI.z, bI.w};
        const float gj[4] = {gJ.x, gJ.y, gJ.z, gJ.w}, bj[4] = {bJ.x, bJ.y, bJ.z, bJ.w};
        const float gff[4] = {gF.x, gF.y, gF.z, gF.w}, bf[4] = {bF.x, bF.y, bF.z, bF.w};
        const float go[4] = {gO.x, gO.y, gO.z, gO.w}, bo[4] = {bO.x, bO.y, bO.z, bO.w};
        const float cv[4] = {cr.x, cr.y, cr.z, cr.w};
#pragma unroll
        for (int u = 0; u < 4; ++u) {
          const float xi = gi[u] * ((iv[u] - m0) * r0) + bi[u];
          const float xj = gj[u] * ((jv[u] - m1) * r1) + bj[u];
          const float xf = gff[u] * ((fv[u] - m2) * r2) + bf[u];
          const float xo = go[u] * ((ov[u] - m3) * r3) + bo[u];
          const float ncv = cv[u] * sigm(xf + FB_) + sigm(xi) * tanhf(xj);
          nc[u] = ncv; oo[u] = xo;
          cs += ncv; cq += ncv * ncv;
        }
      }
      {
        float x = cs, y = cq;
        for (int off = 32; off > 0; off >>= 1) { x += __shfl_down(x, off); y += __shfl_down(y, off); }
        if (lane == 0) { rsc[w * 2] = x; rsc[w * 2 + 1] = y; }
      }
      __syncthreads();
      cs = rsc[0] + rsc[2] + rsc[4] + rsc[6];
      cq = rsc[1] + rsc[3] + rsc[5] + rsc[7];
      const float mc = cs * (1.f / 1024);
      const float rc = rsqrtf(cq * (1.f / 1024) - mc * mc + EPS_);
      {
        const float gc[4] = {gC.x, gC.y, gC.z, gC.w}, bc[4] = {bC.x, bC.y, bC.z, bC.w};
        unsigned short hb[4];
#pragma unroll
        for (int u = 0; u < 4; ++u) {
          const float nh = tanhf(gc[u] * ((nc[u] - mc) * rc) + bc[u]) * sigm(oo[u]);
          hb[u] = f2bf(nh);
        }
        u32x2 hv;
        hv[0] = (unsigned)hb[0] | ((unsigned)hb[1] << 16);
        hv[1] = (unsigned)hb[2] | ((unsigned)hb[3] << 16);
        stg_coh8u(&Hout[((size_t)(b * T_ + t)) * H_ + e0], hv);
        *(float4*)&crow[e0] = float4{nc[0], nc[1], nc[2], nc[3]};
      }
      __syncthreads();
      if (tid == 0)
        __hip_atomic_store(&flag_h[16 * bid], (unsigned)(t + 1), __ATOMIC_RELAXED, __HIP_MEMORY_SCOPE_AGENT);
    }
  }
}

// ---------------------------------------------------------------- fused 2-layer LN-LSTM
// (r10-proven: register-reduced K-loop halves, VGPR=140, launches cooperatively.)
__global__ __launch_bounds__(256)
void k_lstm2(const float* __restrict__ G, const unsigned short* __restrict__ WhT0,
             const unsigned short* __restrict__ WxT1, const unsigned short* __restrict__ WhT1,
             const float* __restrict__ b1,
             const float* __restrict__ lng, const float* __restrict__ lnb,
             float* __restrict__ gf0, float* __restrict__ gf1,
             unsigned short* __restrict__ Hb0, unsigned short* __restrict__ Hb1,
             unsigned* flags) {
  __shared__ unsigned short wh0[16 * 1024];  // [col][k^((col&7)<<3)]
  __shared__ unsigned short wx1[16 * 1024];
  __shared__ unsigned short wh1[16 * 1024];
  __shared__ float red[4][32][16];
  __shared__ float crow[1024];
  __shared__ float rsc[64];

  const int tid = threadIdx.x, bid = blockIdx.x;
  const int lane = tid & 63, w = tid >> 6;
  const int la = lane & 15, lb = lane >> 4;
  unsigned* flag_g0 = flags;                 // 256 slots
  unsigned* flag_g1 = flags + 4096;          // 256 slots
  unsigned* flag_h0 = flags + 8192;          // 32 slots
  unsigned* flag_h1 = flags + 8704;          // 32 slots

  for (int i = tid * 8; i < 16 * 1024; i += 2048) {
    const int cl = i >> 10, k = i & 1023;
    const int dst = cl * 1024 + (k ^ ((cl & 7) << 3));
    *(short8*)&wh0[dst] = *(const short8*)&WhT0[(size_t)bid * 16384 + i];
    *(short8*)&wx1[dst] = *(const short8*)&WxT1[(size_t)bid * 16384 + i];
    *(short8*)&wh1[dst] = *(const short8*)&WhT1[(size_t)bid * 16384 + i];
  }
  if (bid < 64)
    for (int e = tid; e < 1024; e += 256) crow[e] = 0.0f;
  __syncthreads();

  for (int s = 0; s <= T_; ++s) {
    if (w == 0) {
      if (s >= 1) wait_flags(flag_h0, 32, (unsigned)s);        // h0(s-1) ready
      if (s >= 2) wait_flags(flag_h1, 32, (unsigned)(s - 1));  // h1(s-2) ready
    }
    __syncthreads();

    f32x4 accA0 = {0.f,0.f,0.f,0.f}, accA1 = {0.f,0.f,0.f,0.f};
    f32x4 accB0 = {0.f,0.f,0.f,0.f}, accB1 = {0.f,0.f,0.f,0.f};
    f32x4 accC0 = {0.f,0.f,0.f,0.f}, accC1 = {0.f,0.f,0.f,0.f};
    if (s >= 1) {
      const int kw = w * 256 + lb * 8;
      const size_t t0 = (size_t)(s - 1);
      const size_t t1 = (size_t)(s - 2);
#pragma unroll
      for (int half = 0; half < 2; ++half) {
        short8 a0[4], a1[4], c0v[4], c1v[4];
        const int kb = kw + half * 128;
#pragma unroll
        for (int kk = 0; kk < 4; ++kk) {
          a0[kk] = ldg_coh16(&Hb0[((size_t)la * T_ + t0) * H_ + kb + kk * 32]);
          a1[kk] = ldg_coh16(&Hb0[((size_t)(16 + la) * T_ + t0) * H_ + kb + kk * 32]);
        }
        if (s >= 2) {
#pragma unroll
          for (int kk = 0; kk < 4; ++kk) {
            c0v[kk] = ldg_coh16(&Hb1[((size_t)la * T_ + t1) * H_ + kb + kk * 32]);
            c1v[kk] = ldg_coh16(&Hb1[((size_t)(16 + la) * T_ + t1) * H_ + kb + kk * 32]);
          }
        }
        vmwait0();
#pragma unroll
        for (int kk = 0; kk < 4; ++kk) {
          const int kx = (kb + kk * 32) ^ ((la & 7) << 3);
          const bf16x8 va0 = __builtin_bit_cast(bf16x8, a0[kk]);
          const bf16x8 va1 = __builtin_bit_cast(bf16x8, a1[kk]);
          const bf16x8 bB = *(bf16x8*)&wx1[la * 1024 + kx];
          accB0 = __builtin_amdgcn_mfma_f32_16x16x32_bf16(va0, bB, accB0, 0, 0, 0);
          accB1 = __builtin_amdgcn_mfma_f32_16x16x32_bf16(va1, bB, accB1, 0, 0, 0);
          if (s < T_) {
            const bf16x8 bA = *(bf16x8*)&wh0[la * 1024 + kx];
            accA0 = __builtin_amdgcn_mfma_f32_16x16x32_bf16(va0, bA, accA0, 0, 0, 0);
            accA1 = __builtin_amdgcn_mfma_f32_16x16x32_bf16(va1, bA, accA1, 0, 0, 0);
          }
          if (s >= 2) {
            const bf16x8 bC = *(bf16x8*)&wh1[la * 1024 + kx];
            const bf16x8 vc0 = __builtin_bit_cast(bf16x8, c0v[kk]);
            const bf16x8 vc1 = __builtin_bit_cast(bf16x8, c1v[kk]);
            accC0 = __builtin_amdgcn_mfma_f32_16x16x32_bf16(vc0, bC, accC0, 0, 0, 0);
            accC1 = __builtin_amdgcn_mfma_f32_16x16x32_bf16(vc1, bC, accC1, 0, 0, 0);
          }
        }
      }
    }

    // ---- gf0 = G[s] + A
#pragma unroll
    for (int r = 0; r < 4; ++r) {
      red[w][lb * 4 + r][la] = accA0[r];
      red[w][16 + lb * 4 + r][la] = accA1[r];
    }
    __syncthreads();
    if (s < T_) {
      const int b2 = tid >> 3, c2 = (tid & 7) * 2;
      f32x2 sv;
      sv.x = red[0][b2][c2]     + red[1][b2][c2]     + red[2][b2][c2]     + red[3][b2][c2]
           + G[((size_t)(b2 * T_ + s)) * G4H_ + bid * 16 + c2];
      sv.y = red[0][b2][c2 + 1] + red[1][b2][c2 + 1] + red[2][b2][c2 + 1] + red[3][b2][c2 + 1]
           + G[((size_t)(b2 * T_ + s)) * G4H_ + bid * 16 + c2 + 1];
      stg_coh8f(&gf0[b2 * G4H_ + bid * 16 + c2], sv);
    }
    __syncthreads();
    if (tid == 0 && s < T_)
      __hip_atomic_store(&flag_g0[16 * bid], (unsigned)(s + 1), __ATOMIC_RELAXED, __HIP_MEMORY_SCOPE_AGENT);

    // ---- gf1 = b1 + B + C
#pragma unroll
    for (int r = 0; r < 4; ++r) {
      red[w][lb * 4 + r][la] = accB0[r] + accC0[r];
      red[w][16 + lb * 4 + r][la] = accB1[r] + accC1[r];
    }
    __syncthreads();
    if (s >= 1) {
      const int b2 = tid >> 3, c2 = (tid & 7) * 2;
      f32x2 sv;
      sv.x = red[0][b2][c2]     + red[1][b2][c2]     + red[2][b2][c2]     + red[3][b2][c2]
           + b1[bid * 16 + c2];
      sv.y = red[0][b2][c2 + 1] + red[1][b2][c2 + 1] + red[2][b2][c2 + 1] + red[3][b2][c2 + 1]
           + b1[bid * 16 + c2 + 1];
      stg_coh8f(&gf1[b2 * G4H_ + bid * 16 + c2], sv);
    }
    __syncthreads();
    if (tid == 0 && s >= 1)
      __hip_atomic_store(&flag_g1[16 * bid], (unsigned)(s + 1), __ATOMIC_RELAXED, __HIP_MEMORY_SCOPE_AGENT);

    // ---- phase 2: LN + pointwise (blocks 0-31: L0 time s; 32-63: L1 time s-1)
    const bool isP2 = (bid < 32) ? (s < T_) : (bid < 64 ? (s >= 1) : false);
    if (isP2) {
      const bool L1p = (bid >= 32);
      const int b = L1p ? (bid - 32) : bid;
      if (w == 0) wait_flags(L1p ? flag_g1 : flag_g0, 256, (unsigned)(s + 1));
      __syncthreads();
      const float* gfp = (L1p ? gf1 : gf0) + (size_t)b * G4H_;
      const float* g_ = L1p ? (lng + 5120) : lng;
      const float* b_ = L1p ? (lnb + 5120) : lnb;
      const int tt = L1p ? (s - 1) : s;
      unsigned short* hout = (L1p ? Hb1 : Hb0) + ((size_t)b * T_ + tt) * H_;

      const int e0 = tid * 4;
      const f32x4 iv = ldg_coh16f(&gfp[e0]);
      const f32x4 jv = ldg_coh16f(&gfp[1024 + e0]);
      const f32x4 fv = ldg_coh16f(&gfp[2048 + e0]);
      const f32x4 ov = ldg_coh16f(&gfp[3072 + e0]);
      vmwait0();

      float vals[8] = {0, 0, 0, 0, 0, 0, 0, 0};
#pragma unroll
      for (int u = 0; u < 4; ++u) {
        vals[0] += iv[u]; vals[4] += iv[u] * iv[u];
        vals[1] += jv[u]; vals[5] += jv[u] * jv[u];
        vals[2] += fv[u]; vals[6] += fv[u] * fv[u];
        vals[3] += ov[u]; vals[7] += ov[u] * ov[u];
      }
#pragma unroll
      for (int i = 0; i < 8; ++i) {
        float x = vals[i];
        for (int off = 32; off > 0; off >>= 1) x += __shfl_down(x, off);
        if (lane == 0) rsc[w * 8 + i] = x;
      }
      __syncthreads();
#pragma unroll
      for (int i = 0; i < 8; ++i)
        vals[i] = rsc[i] + rsc[8 + i] + rsc[16 + i] + rsc[24 + i];
      __syncthreads();
      const float m0 = vals[0] * (1.f / 1024), m1 = vals[1] * (1.f / 1024);
      const float m2 = vals[2] * (1.f / 1024), m3 = vals[3] * (1.f / 1024);
      const float r0 = rsqrtf(vals[4] * (1.f / 1024) - m0 * m0 + EPS_);
      const float r1 = rsqrtf(vals[5] * (1.f / 1024) - m1 * m1 + EPS_);
      const float r2 = rsqrtf(vals[6] * (1.f / 1024) - m2 * m2 + EPS_);
      const float r3 = rsqrtf(vals[7] * (1.f / 1024) - m3 * m3 + EPS_);

      const float4 gI = *(const float4*)&g_[e0];
      const float4 gJ = *(const float4*)&g_[1024 + e0];
      const float4 gF = *(const float4*)&g_[2048 + e0];
      const float4 gO = *(const float4*)&g_[3072 + e0];
      const float4 gC = *(const float4*)&g_[4096 + e0];
      const float4 bI = *(const float4*)&b_[e0];
      const float4 bJ = *(const float4*)&b_[1024 + e0];
      const float4 bF = *(const float4*)&b_[2048 + e0];
      const float4 bO = *(const float4*)&b_[3072 + e0];
      const float4 bC = *(const float4*)&b_[4096 + e0];
      const float4 cr = *(const float4*)&crow[e0];

      float nc[4], oo[4];
      float cs = 0.f, cq = 0.f;
      {
        const float gi[4] = {gI.x, gI.y, gI.z, gI.w}, bi[4] = {bI.x, bI.y, bI.z, bI.w};
        const float gj[4] = {gJ.x, gJ.y, gJ.z, gJ.w}, bj[4] = {bJ.x, bJ.y, bJ.z, bJ.w};
        const float gff[4] = {gF.x, gF.y, gF.z, gF.w}, bf[4] = {bF.x, bF.y, bF.z, bF.w};
        const float go[4] = {gO.x, gO.y, gO.z, gO.w}, bo[4] = {bO.x, bO.y, bO.z, bO.w};
        const float cv[4] = {cr.x, cr.y, cr.z, cr.w};
#pragma unroll
        for (int u = 0; u < 4; ++u) {
          const float xi = gi[u] * ((iv[u] - m0) * r0) + bi[u];
          const float xj = gj[u] * ((jv[u] - m1) * r1) + bj[u];
          const float xf = gff[u] * ((fv[u] - m2) * r2) + bf[u];
          const float xo = go[u] * ((ov[u] - m3) * r3) + bo[u];
          const float ncv = cv[u] * sigm(xf + FB_) + sigm(xi) * tanhf(xj);
          nc[u] = ncv; oo[u] = xo;
          cs += ncv; cq += ncv * ncv;
        }
      }
      {
        float x = cs, y = cq;
        for (int off = 32; off > 0; off >>= 1) { x += __shfl_down(x, off); y += __shfl_down(y, off); }
        if (lane == 0) { rsc[w * 2] = x; rsc[w * 2 + 1] = y; }
      }
      __syncthreads();
      cs = rsc[0] + rsc[2] + rsc[4] + rsc[6];
      cq = rsc[1] + rsc[3] + rsc[5] + rsc[7];
      const float mc = cs * (1.f / 1024);
      const float rc = rsqrtf(cq * (1.f / 1024) - mc * mc + EPS_);
      {
        const float gc[4] = {gC.x, gC.y, gC.z, gC.w}, bc[4] = {bC.x, bC.y, bC.z, bC.w};
        unsigned short hb[4];
#pragma unroll
        for (int u = 0; u < 4; ++u) {
          const float nh = tanhf(gc[u] * ((nc[u] - mc) * rc) + bc[u]) * sigm(oo[u]);
          hb[u] = f2bf(nh);
        }
        u32x2 hv;
        hv[0] = (unsigned)hb[0] | ((unsigned)hb[1] << 16);
        hv[1] = (unsigned)hb[2] | ((unsigned)hb[3] << 16);
        stg_coh8u(&hout[e0], hv);
        *(float4*)&crow[e0] = float4{nc[0], nc[1], nc[2], nc[3]};
      }
      __syncthreads();
      if (tid == 0) {
        if (L1p)
          __hip_atomic_store(&flag_h1[16 * b], (unsigned)s, __ATOMIC_RELAXED, __HIP_MEMORY_SCOPE_AGENT);
        else
          __hip_atomic_store(&flag_h0[16 * b], (unsigned)(s + 1), __ATOMIC_RELAXED, __HIP_MEMORY_SCOPE_AGENT);
      }
    }
  }
}

// ---------------------------------------------------------------- LSE finish (combine 500 tile partials per row)
__global__ __launch_bounds__(256)
void k_lse_finish(const float* __restrict__ part, float* __restrict__ lse) {
  __shared__ float rm[4];
  __shared__ float rs[4];
  const int r = blockIdx.x, tid = threadIdx.x;
  const int lane = tid & 63, w = tid >> 6;
  float m = -1e30f, s = 0.f;
  for (int i = tid; i < 500; i += 256) {
    const float2 p = *(const float2*)&part[((size_t)r * 512 + i) * 2];
    const float nm = fmaxf(m, p.x);
    s = s * __expf(m - nm) + p.y * __expf(p.x - nm);
    m = nm;
  }
  for (int off = 32; off > 0; off >>= 1) {
    const float m2 = __shfl_down(m, off), s2 = __shfl_down(s, off);
    const float nm = fmaxf(m, m2);
    s = s * __expf(m - nm) + s2 * __expf(m2 - nm);
    m = nm;
  }
  if (lane == 0) { rm[w] = m; rs[w] = s; }
  __syncthreads();
  if (tid == 0) {
    float M = rm[0], S = rs[0];
#pragma unroll
    for (int i = 1; i < 4; ++i) {
      const float nm = fmaxf(M, rm[i]);
      S = S * __expf(M - nm) + rs[i] * __expf(rm[i] - nm);
      M = nm;
    }
    lse[r] = M + logf(S);
  }
}

// ---------------------------------------------------------------- loss (mean NLL)
__global__ __launch_bounds__(256)
void k_loss(const float* __restrict__ logits, const float* __restrict__ lse,
            const int* __restrict__ tgt, float* __restrict__ out) {
  __shared__ float rsc[4];
  const int tid = threadIdx.x;
  float s = 0.f;
  for (int r = tid; r < BT_; r += 256)
    s += lse[r] - logits[(size_t)r * V_ + tgt[r]];
  for (int off = 32; off > 0; off >>= 1) s += __shfl_down(s, off);
  if ((tid & 63) == 0) rsc[tid >> 6] = s;
  __syncthreads();
  if (tid == 0) out[(size_t)BT_ * V_] = (rsc[0] + rsc[1] + rsc[2] + rsc[3]) / (float)BT_;
}

// ================================================================ launch
// Fused cooperative kernel with CHECKED launch; on rejection, fall back to the
// r6-proven two-kernel sequence (identical outputs either way).
// ws layout ~191.4 MB (budget ~192 MB): gf0/gf1/bars/lseb alias the Xemb region
// (dead after the L0 x-part GEMM); LSE partials alias Gbuf (dead after LSTM).
extern "C" void kernel_launch(void* const* d_in, const int* in_sizes, int n_in,
                              void* d_out, int out_size, void* d_ws, size_t ws_size,
                              hipStream_t stream) {
  const int*   ids  = (const int*)d_in[0];
  const int*   tgt  = (const int*)d_in[1];
  const float* emb  = (const float*)d_in[2];
  const float* W    = (const float*)d_in[3];   // [2][2048][4096]
  const float* brnn = (const float*)d_in[4];   // [2][4096]
  const float* lng  = (const float*)d_in[5];   // [2][5][1024]
  const float* lnb  = (const float*)d_in[6];
  const float* sw   = (const float*)d_in[7];   // [1024][32000]
  const float* sb   = (const float*)d_in[8];   // [32000]
  float* out = (float*)d_out;

  char* ws = (char*)d_ws;
  size_t o = 0;
  auto take = [&](size_t n) { char* p = ws + o; o += (n + 255) & ~(size_t)255; return p; };
  unsigned short* WxT0 = (unsigned short*)take((size_t)G4H_ * H_ * 2);       // 8 MB
  unsigned short* WhT0 = (unsigned short*)take((size_t)G4H_ * H_ * 2);       // 8 MB
  unsigned short* WxT1 = (unsigned short*)take((size_t)G4H_ * H_ * 2);       // 8 MB
  unsigned short* WhT1 = (unsigned short*)take((size_t)G4H_ * H_ * 2);       // 8 MB
  unsigned short* WsT  = (unsigned short*)take((size_t)V_ * H_ * 2);         // 65.5 MB
  unsigned short* Xemb = (unsigned short*)take((size_t)BT_ * H_ * 2);        // 8 MB
  float*          Gbuf = (float*)take((size_t)BT_ * G4H_ * 4);               // 64 MB
  unsigned short* Hb0  = (unsigned short*)take((size_t)BT_ * H_ * 2);        // 8 MB
  unsigned short* Hb1  = (unsigned short*)take((size_t)BT_ * H_ * 2);        // 8 MB
  // aliased into the Xemb region (dead after the L0 x-part GEMM)
  char* xregion = (char*)Xemb;
  float*    gf0  = (float*)(xregion);                    // 524,288 B
  float*    gf1  = (float*)(xregion + 524288);           // 524,288 B
  unsigned* bars = (unsigned*)(xregion + 1048576);       //  40,960 B
  float*    lseb = (float*)(xregion + 1089536);          //  16,384 B
  // LSE partials alias Gbuf (dead after the LSTM): float2[4096][512] = 16 MB
  float*    lsepart = (float*)Gbuf;

  const dim3 tb(32, 8);
  k_transpose_cast<<<dim3(128, 32),  tb, 0, stream>>>(W,                    WxT0, 1024, 4096, 4096);
  k_transpose_cast<<<dim3(128, 32),  tb, 0, stream>>>(W + 1024 * 4096,      WhT0, 1024, 4096, 4096);
  k_transpose_cast<<<dim3(128, 32),  tb, 0, stream>>>(W + 2048 * 4096,      WxT1, 1024, 4096, 4096);
  k_transpose_cast<<<dim3(128, 32),  tb, 0, stream>>>(W + 3072 * 4096,      WhT1, 1024, 4096, 4096);
  k_transpose_cast<<<dim3(1000, 32), tb, 0, stream>>>(sw,                   WsT,  1024, V_,  V_);

  k_gather<<<BT_, 256, 0, stream>>>(ids, emb, Xemb);

  // layer-0 x-part precompute: Gbuf = Xemb @ Wx0^T + b0  (last use of Xemb)
  k_gemm_bt<<<dim3(32, 32), 256, 0, stream>>>(Xemb, WxT0, brnn, Gbuf, BT_, G4H_, H_, nullptr);

  // Xemb region now dead: zero the flag slots (stream-ordered)
  hipMemsetAsync(bars, 0, 40960, stream);

  // ---- try the fused 2-layer cooperative kernel
  const float* G_ = Gbuf;
  const unsigned short* Wh0_ = WhT0; const unsigned short* Wx1_ = WxT1; const unsigned short* Wh1_ = WhT1;
  const float* b1_ = brnn + 4096;
  const float* g0_ = lng;        const float* bb0_ = lnb;
  const float* g1_ = lng + 5120; const float* bb1_ = lnb + 5120;
  float* gf0_ = gf0; float* gf1_ = gf1;
  unsigned short* H0_ = Hb0; unsigned short* H1_ = Hb1;
  unsigned* bars_ = bars;

  hipError_t ce;
  {
    void* args[] = {&G_, &Wh0_, &Wx1_, &Wh1_, &b1_, &g0_, &bb0_, &gf0_, &gf1_, &H0_, &H1_, &bars_};
    ce = hipLaunchCooperativeKernel((void*)k_lstm2, dim3(256), dim3(256), args, 0, stream);
  }
  if (ce != hipSuccess) {
    // ---- fallback: r6-proven two-kernel sequence (bars already zeroed)
    {
      void* a0[] = {&G_, &Wh0_, &g0_, &bb0_, &gf0_, &H0_, &bars_};
      hipLaunchCooperativeKernel((void*)k_lstm, dim3(256), dim3(256), a0, 0, stream);
    }
    hipMemsetAsync(bars, 0, 40960, stream);
    k_gemm_bt<<<dim3(32, 32), 256, 0, stream>>>(Hb0, WxT1, brnn + 4096, Gbuf, BT_, G4H_, H_, nullptr);
    {
      void* a1[] = {&G_, &Wh1_, &g1_, &bb1_, &gf0_, &H1_, &bars_};
      hipLaunchCooperativeKernel((void*)k_lstm, dim3(256), dim3(256), a1, 0, stream);
    }
  }

  // projection -> logits (d_out) + fused per-tile LSE partials (into dead Gbuf)
  k_gemm_bt<<<dim3(250, 32), 256, 0, stream>>>(Hb1, WsT, sb, out, BT_, V_, H_, lsepart);
  k_lse_finish<<<BT_, 256, 0, stream>>>(lsepart, lseb);
  k_loss<<<1, 256, 0, stream>>>(out, lseb, tgt, out);
}

// Round 13
// 2126.489 us; speedup vs baseline: 8.3293x; 1.1394x over previous
//
#include <hip/hip_runtime.h>
#include <hip/hip_cooperative_groups.h>

#define V_    32000
#define B_    32
#define T_    128
#define H_    1024
#define BT_   4096     // B_*T_
#define G4H_  4096     // 4*H_
#define EPS_  1e-5f
#define FB_   1.0f     // forget bias

typedef __bf16  bf16x8 __attribute__((ext_vector_type(8)));
typedef float   f32x4  __attribute__((ext_vector_type(4)));
typedef float   f32x2  __attribute__((ext_vector_type(2)));
typedef unsigned u32x2 __attribute__((ext_vector_type(2)));
typedef short   short8 __attribute__((ext_vector_type(8)));

__device__ __forceinline__ unsigned short f2bf(float f) {
  unsigned u = __builtin_bit_cast(unsigned, f);
  u = u + 0x7FFFu + ((u >> 16) & 1u);          // round-to-nearest-even
  return (unsigned short)(u >> 16);
}
__device__ __forceinline__ float sigm(float x) { return 1.0f / (1.0f + expf(-x)); }

// ---------------------------------------------------------------- LLC-coherent access
__device__ __forceinline__ short8 ldg_coh16(const unsigned short* p) {
  short8 v;
  asm volatile("global_load_dwordx4 %0, %1, off sc0 sc1" : "=v"(v) : "v"(p) : "memory");
  return v;
}
__device__ __forceinline__ f32x4 ldg_coh16f(const float* p) {
  f32x4 v;
  asm volatile("global_load_dwordx4 %0, %1, off sc0 sc1" : "=v"(v) : "v"(p) : "memory");
  return v;
}
__device__ __forceinline__ void stg_coh8f(float* p, f32x2 v) {
  asm volatile("global_store_dwordx2 %0, %1, off sc0 sc1" :: "v"(p), "v"(v) : "memory");
}
__device__ __forceinline__ void stg_coh16f(float* p, f32x4 v) {
  asm volatile("global_store_dwordx4 %0, %1, off sc0 sc1" :: "v"(p), "v"(v) : "memory");
}
__device__ __forceinline__ void stg_coh8u(unsigned short* p, u32x2 v) {
  asm volatile("global_store_dwordx2 %0, %1, off sc0 sc1" :: "v"(p), "v"(v) : "memory");
}
__device__ __forceinline__ void vmwait0() {
  asm volatile("s_waitcnt vmcnt(0)" ::: "memory");
  __builtin_amdgcn_sched_barrier(0);           // rule #18: pin consumers after the wait
}

// ---------------------------------------------------------------- dataflow flag sync
__device__ __forceinline__ void wait_flags(unsigned* flags, int nslots, unsigned tgt) {
  const int lane = threadIdx.x & 63;
  for (;;) {
    unsigned v = 0xFFFFFFFFu;
    for (int s = lane; s < nslots; s += 64) {
      const unsigned x = __hip_atomic_load(&flags[16 * s], __ATOMIC_RELAXED, __HIP_MEMORY_SCOPE_AGENT);
      v = x < v ? x : v;
    }
    if (__all((int)(v >= tgt))) break;
    __builtin_amdgcn_s_sleep(1);
  }
}

// ---------------------------------------------------------------- transpose+cast
__global__ void k_transpose_cast(const float* __restrict__ in, unsigned short* __restrict__ out,
                                 int R, int C, int ldin) {
  __shared__ float tl[32][33];
  const int tx = threadIdx.x, ty = threadIdx.y;
  const int r0 = blockIdx.y * 32, c0 = blockIdx.x * 32;
#pragma unroll
  for (int i = 0; i < 4; ++i)
    tl[ty + 8 * i][tx] = in[(size_t)(r0 + ty + 8 * i) * ldin + c0 + tx];
  __syncthreads();
#pragma unroll
  for (int i = 0; i < 4; ++i)
    out[(size_t)(c0 + ty + 8 * i) * R + r0 + tx] = f2bf(tl[tx][ty + 8 * i]);
}

// ---------------------------------------------------------------- embedding gather
__global__ void k_gather(const int* __restrict__ ids, const float* __restrict__ emb,
                         unsigned short* __restrict__ x) {
  const int r = blockIdx.x;
  const int t4 = threadIdx.x * 4;
  const int row = ids[r];
  const float4 v = *(const float4*)&emb[(size_t)row * H_ + t4];
  ushort4 o;
  o.x = f2bf(v.x); o.y = f2bf(v.y); o.z = f2bf(v.z); o.w = f2bf(v.w);
  *(ushort4*)&x[(size_t)r * H_ + t4] = o;
}

// ---------------------------------------------------------------- bf16 GEMM, C = A * BT^T + bias
// width-16 global_load_lds staging; XCD-aware bijective block swizzle; optional
// fused per-row online-LSE partials -> lse_part[row*512 + bx*2 + wc] float2.
__global__ __launch_bounds__(256)
void k_gemm_bt(const unsigned short* __restrict__ A, const unsigned short* __restrict__ BT,
               const float* __restrict__ bias, float* __restrict__ C,
               int M, int N, int K, float* __restrict__ lse_part) {
  __shared__ unsigned short As[128 * 32];
  __shared__ unsigned short Bs[128 * 32];
  const int tid = threadIdx.x;
  const int lane = tid & 63, wid = tid >> 6;
  const int wr = wid >> 1, wc = wid & 1;
  const int la = lane & 15, lb = lane >> 4;

  int flat = blockIdx.y * gridDim.x + blockIdx.x;
  const int nwg = gridDim.x * gridDim.y;       // divisible by 8 at all call sites
  const int cpx = nwg >> 3;
  flat = (flat & 7) * cpx + (flat >> 3);
  const int bx = flat % gridDim.x, by = flat / gridDim.x;
  const int m0 = by * 128, n0 = bx * 128;

  f32x4 acc[4][4];
#pragma unroll
  for (int i = 0; i < 4; ++i)
#pragma unroll
    for (int j = 0; j < 4; ++j) acc[i][j] = f32x4{0.f, 0.f, 0.f, 0.f};

  for (int k0 = 0; k0 < K; k0 += 32) {
    __syncthreads();
#pragma unroll
    for (int i = 0; i < 2; ++i) {
      const int off = i * 2048 + tid * 8;
      const int row = off >> 5, col = off & 31;
      __builtin_amdgcn_global_load_lds(
          (const __attribute__((address_space(1))) void*)&A[(size_t)(m0 + row) * K + k0 + col],
          (__attribute__((address_space(3))) void*)&As[off], 16, 0, 0);
      __builtin_amdgcn_global_load_lds(
          (const __attribute__((address_space(1))) void*)&BT[(size_t)(n0 + row) * K + k0 + col],
          (__attribute__((address_space(3))) void*)&Bs[off], 16, 0, 0);
    }
    __syncthreads();
    bf16x8 a[4], b[4];
#pragma unroll
    for (int mm = 0; mm < 4; ++mm) a[mm] = *(bf16x8*)&As[(wr * 64 + mm * 16 + la) * 32 + lb * 8];
#pragma unroll
    for (int nn = 0; nn < 4; ++nn) b[nn] = *(bf16x8*)&Bs[(wc * 64 + nn * 16 + la) * 32 + lb * 8];
#pragma unroll
    for (int mm = 0; mm < 4; ++mm)
#pragma unroll
      for (int nn = 0; nn < 4; ++nn)
        acc[mm][nn] = __builtin_amdgcn_mfma_f32_16x16x32_bf16(a[mm], b[nn], acc[mm][nn], 0, 0, 0);
  }
#pragma unroll
  for (int mm = 0; mm < 4; ++mm)
#pragma unroll
    for (int nn = 0; nn < 4; ++nn) {
      const int row = m0 + wr * 64 + mm * 16 + lb * 4;
      const int col = n0 + wc * 64 + nn * 16 + la;
      const float bs = bias ? bias[col] : 0.f;
#pragma unroll
      for (int r = 0; r < 4; ++r)
        C[(size_t)(row + r) * N + col] = acc[mm][nn][r] + bs;
    }

  if (lse_part) {
#pragma unroll
    for (int mm = 0; mm < 4; ++mm)
#pragma unroll
      for (int r = 0; r < 4; ++r) {
        float vv[4];
        float mx = -1e30f;
#pragma unroll
        for (int nn = 0; nn < 4; ++nn) {
          vv[nn] = acc[mm][nn][r] + (bias ? bias[n0 + wc * 64 + nn * 16 + la] : 0.f);
          mx = fmaxf(mx, vv[nn]);
        }
        float ss = 0.f;
#pragma unroll
        for (int nn = 0; nn < 4; ++nn) ss += __expf(vv[nn] - mx);
#pragma unroll
        for (int msk = 1; msk < 16; msk <<= 1) {
          const float m2 = __shfl_xor(mx, msk);
          const float s2 = __shfl_xor(ss, msk);
          const float nm = fmaxf(mx, m2);
          ss = ss * __expf(mx - nm) + s2 * __expf(m2 - nm);
          mx = nm;
        }
        if (la == 0) {
          const int row = m0 + wr * 64 + mm * 16 + lb * 4 + r;
          *(float2*)&lse_part[((size_t)row * 512 + (size_t)bx * 2 + wc) * 2] = float2{mx, ss};
        }
      }
  }
}

// ---------------------------------------------------------------- shared LN+pointwise body
__device__ __forceinline__ void lstm_pointwise(
    const float* gfp, const float* g_, const float* b_, float* crow, float* rsc,
    unsigned short* hout, int tid, int lane, int w) {
  const int e0 = tid * 4;
  const f32x4 iv = ldg_coh16f(&gfp[e0]);
  const f32x4 jv = ldg_coh16f(&gfp[1024 + e0]);
  const f32x4 fv = ldg_coh16f(&gfp[2048 + e0]);
  const f32x4 ov = ldg_coh16f(&gfp[3072 + e0]);
  vmwait0();

  float vals[8] = {0, 0, 0, 0, 0, 0, 0, 0};
#pragma unroll
  for (int u = 0; u < 4; ++u) {
    vals[0] += iv[u]; vals[4] += iv[u] * iv[u];
    vals[1] += jv[u]; vals[5] += jv[u] * jv[u];
    vals[2] += fv[u]; vals[6] += fv[u] * fv[u];
    vals[3] += ov[u]; vals[7] += ov[u] * ov[u];
  }
#pragma unroll
  for (int i = 0; i < 8; ++i) {
    float x = vals[i];
    for (int off = 32; off > 0; off >>= 1) x += __shfl_down(x, off);
    if (lane == 0) rsc[w * 8 + i] = x;
  }
  __syncthreads();
#pragma unroll
  for (int i = 0; i < 8; ++i)
    vals[i] = rsc[i] + rsc[8 + i] + rsc[16 + i] + rsc[24 + i];
  __syncthreads();
  const float m0 = vals[0] * (1.f / 1024), m1 = vals[1] * (1.f / 1024);
  const float m2 = vals[2] * (1.f / 1024), m3 = vals[3] * (1.f / 1024);
  const float r0 = rsqrtf(vals[4] * (1.f / 1024) - m0 * m0 + EPS_);
  const float r1 = rsqrtf(vals[5] * (1.f / 1024) - m1 * m1 + EPS_);
  const float r2 = rsqrtf(vals[6] * (1.f / 1024) - m2 * m2 + EPS_);
  const float r3 = rsqrtf(vals[7] * (1.f / 1024) - m3 * m3 + EPS_);

  const float4 gI = *(const float4*)&g_[e0];
  const float4 gJ = *(const float4*)&g_[1024 + e0];
  const float4 gF = *(const float4*)&g_[2048 + e0];
  const float4 gO = *(const float4*)&g_[3072 + e0];
  const float4 gC = *(const float4*)&g_[4096 + e0];
  const float4 bI = *(const float4*)&b_[e0];
  const float4 bJ = *(const float4*)&b_[1024 + e0];
  const float4 bF = *(const float4*)&b_[2048 + e0];
  const float4 bO = *(const float4*)&b_[3072 + e0];
  const float4 bC = *(const float4*)&b_[4096 + e0];
  const float4 cr = *(const float4*)&crow[e0];

  float nc[4], oo[4];
  float cs = 0.f, cq = 0.f;
  {
    const float gi[4] = {gI.x, gI.y, gI.z, gI.w}, bi[4] = {bI.x, bI.y, bI.z, bI.w};
    const float gj[4] = {gJ.x, gJ.y, gJ.z, gJ.w}, bj[4] = {bJ.x, bJ.y, bJ.z, bJ.w};
    const float gff[4] = {gF.x, gF.y, gF.z, gF.w}, bf[4] = {bF.x, bF.y, bF.z, bF.w};
    const float go[4] = {gO.x, gO.y, gO.z, gO.w}, bo[4] = {bO.x, bO.y, bO.z, bO.w};
    const float cv[4] = {cr.x, cr.y, cr.z, cr.w};
#pragma unroll
    for (int u = 0; u < 4; ++u) {
      const float xi = gi[u] * ((iv[u] - m0) * r0) + bi[u];
      const float xj = gj[u] * ((jv[u] - m1) * r1) + bj[u];
      const float xf = gff[u] * ((fv[u] - m2) * r2) + bf[u];
      const float xo = go[u] * ((ov[u] - m3) * r3) + bo[u];
      const float ncv = cv[u] * sigm(xf + FB_) + sigm(xi) * tanhf(xj);
      nc[u] = ncv; oo[u] = xo;
      cs += ncv; cq += ncv * ncv;
    }
  }
  {
    float x = cs, y = cq;
    for (int off = 32; off > 0; off >>= 1) { x += __shfl_down(x, off); y += __shfl_down(y, off); }
    if (lane == 0) { rsc[w * 2] = x; rsc[w * 2 + 1] = y; }
  }
  __syncthreads();
  cs = rsc[0] + rsc[2] + rsc[4] + rsc[6];
  cq = rsc[1] + rsc[3] + rsc[5] + rsc[7];
  const float mc = cs * (1.f / 1024);
  const float rc = rsqrtf(cq * (1.f / 1024) - mc * mc + EPS_);
  {
    const float gc[4] = {gC.x, gC.y, gC.z, gC.w}, bc[4] = {bC.x, bC.y, bC.z, bC.w};
    unsigned short hb[4];
#pragma unroll
    for (int u = 0; u < 4; ++u) {
      const float nh = tanhf(gc[u] * ((nc[u] - mc) * rc) + bc[u]) * sigm(oo[u]);
      hb[u] = f2bf(nh);
    }
    u32x2 hv;
    hv[0] = (unsigned)hb[0] | ((unsigned)hb[1] << 16);
    hv[1] = (unsigned)hb[2] | ((unsigned)hb[3] << 16);
    stg_coh8u(&hout[e0], hv);
    *(float4*)&crow[e0] = float4{nc[0], nc[1], nc[2], nc[3]};
  }
  __syncthreads();                           // drain h stores before flag
}

// ---------------------------------------------------------------- layer-split fused LSTM
// Blocks 0-127: L0, 32 gate-cols each (Wh0 64KB LDS). Blocks 128-255: L1, 32
// cols each (Wx1+Wh1 128KB LDS, K=2048 in 4 register-quarters). P2-L0 on blocks
// 0-31; P2-L1 on blocks 128-159. Separate flag arrays take L1's matmul work OFF
// L0's recurrence-critical path (1-step skew absorbs L1 latency).
// Flags: g0[128]@0, g1[128]@+2048w, h0[32]@+4096w, h1[32]@+4608w.
// WAR: gf0 overwrite gated by all flag_h0>=s; gf1 by flag_h1>=s-1 (both waited).
__global__ __launch_bounds__(256)
void k_lstm3(const float* __restrict__ G, const unsigned short* __restrict__ WhT0,
             const unsigned short* __restrict__ WxT1, const unsigned short* __restrict__ WhT1,
             const float* __restrict__ b1,
             const float* __restrict__ lng, const float* __restrict__ lnb,
             float* __restrict__ gf0, float* __restrict__ gf1,
             unsigned short* __restrict__ Hb0, unsigned short* __restrict__ Hb1,
             unsigned* flags) {
  __shared__ unsigned short wA[32 * 1024];   // L0: Wh0 | L1: Wx1  (swizzled rows)
  __shared__ unsigned short wB[32 * 1024];   // L1: Wh1 (unused by L0 blocks)
  __shared__ float red[4][32][32];
  __shared__ float crow[1024];
  __shared__ float rsc[64];

  const int tid = threadIdx.x, bid = blockIdx.x;
  const int lane = tid & 63, w = tid >> 6;
  const int la = lane & 15, lb = lane >> 4;
  const bool isL1 = (bid >= 128);
  const int cb = (isL1 ? (bid - 128) : bid) * 32;    // gate-col base
  unsigned* flag_g0 = flags;                  // 128 slots
  unsigned* flag_g1 = flags + 2048;           // 128 slots
  unsigned* flag_h0 = flags + 4096;           // 32 slots
  unsigned* flag_h1 = flags + 4608;           // 32 slots

  // stage weights (32 cols x 1024 k), XOR-swizzled rows
  for (int i = tid * 8; i < 32 * 1024; i += 2048) {
    const int cl = i >> 10, k = i & 1023;
    const int dst = cl * 1024 + (k ^ ((cl & 7) << 3));
    if (!isL1) {
      *(short8*)&wA[dst] = *(const short8*)&WhT0[(size_t)(cb + cl) * 1024 + k];
    } else {
      *(short8*)&wA[dst] = *(const short8*)&WxT1[(size_t)(cb + cl) * 1024 + k];
      *(short8*)&wB[dst] = *(const short8*)&WhT1[(size_t)(cb + cl) * 1024 + k];
    }
  }
  if (bid < 32 || (bid >= 128 && bid < 160))
    for (int e = tid; e < 1024; e += 256) crow[e] = 0.0f;
  __syncthreads();

  for (int s = 0; s <= T_; ++s) {
    // ---- dependency waits (block-uniform)
    if (w == 0) {
      if (!isL1) {
        if (s >= 1 && s < T_) wait_flags(flag_h0, 32, (unsigned)s);
      } else {
        if (s >= 1) wait_flags(flag_h0, 32, (unsigned)s);
        if (s >= 2) wait_flags(flag_h1, 32, (unsigned)(s - 1));
      }
    }
    __syncthreads();

    // ---- matmul
    f32x4 acc[2][2] = {{{0.f,0.f,0.f,0.f},{0.f,0.f,0.f,0.f}},{{0.f,0.f,0.f,0.f},{0.f,0.f,0.f,0.f}}};
    const int kw = w * 256 + lb * 8;
    if (!isL1) {
      if (s >= 1 && s < T_) {
        const size_t t0 = (size_t)(s - 1);
#pragma unroll
        for (int half = 0; half < 2; ++half) {
          short8 a0[4], a1[4];
          const int kb = kw + half * 128;
#pragma unroll
          for (int kk = 0; kk < 4; ++kk) {
            a0[kk] = ldg_coh16(&Hb0[((size_t)la * T_ + t0) * H_ + kb + kk * 32]);
            a1[kk] = ldg_coh16(&Hb0[((size_t)(16 + la) * T_ + t0) * H_ + kb + kk * 32]);
          }
          vmwait0();
#pragma unroll
          for (int kk = 0; kk < 4; ++kk) {
            const int kx = (kb + kk * 32) ^ ((la & 7) << 3);
            const bf16x8 b0 = *(bf16x8*)&wA[la * 1024 + kx];
            const bf16x8 b1v = *(bf16x8*)&wA[(16 + la) * 1024 + kx];
            const bf16x8 va0 = __builtin_bit_cast(bf16x8, a0[kk]);
            const bf16x8 va1 = __builtin_bit_cast(bf16x8, a1[kk]);
            acc[0][0] = __builtin_amdgcn_mfma_f32_16x16x32_bf16(va0, b0, acc[0][0], 0, 0, 0);
            acc[0][1] = __builtin_amdgcn_mfma_f32_16x16x32_bf16(va0, b1v, acc[0][1], 0, 0, 0);
            acc[1][0] = __builtin_amdgcn_mfma_f32_16x16x32_bf16(va1, b0, acc[1][0], 0, 0, 0);
            acc[1][1] = __builtin_amdgcn_mfma_f32_16x16x32_bf16(va1, b1v, acc[1][1], 0, 0, 0);
          }
        }
      }
    } else if (s >= 1) {
      const size_t t0 = (size_t)(s - 1);
#pragma unroll
      for (int half = 0; half < 2; ++half) {       // h0 @ Wx1
        short8 a0[4], a1[4];
        const int kb = kw + half * 128;
#pragma unroll
        for (int kk = 0; kk < 4; ++kk) {
          a0[kk] = ldg_coh16(&Hb0[((size_t)la * T_ + t0) * H_ + kb + kk * 32]);
          a1[kk] = ldg_coh16(&Hb0[((size_t)(16 + la) * T_ + t0) * H_ + kb + kk * 32]);
        }
        vmwait0();
#pragma unroll
        for (int kk = 0; kk < 4; ++kk) {
          const int kx = (kb + kk * 32) ^ ((la & 7) << 3);
          const bf16x8 b0 = *(bf16x8*)&wA[la * 1024 + kx];
          const bf16x8 b1v = *(bf16x8*)&wA[(16 + la) * 1024 + kx];
          const bf16x8 va0 = __builtin_bit_cast(bf16x8, a0[kk]);
          const bf16x8 va1 = __builtin_bit_cast(bf16x8, a1[kk]);
          acc[0][0] = __builtin_amdgcn_mfma_f32_16x16x32_bf16(va0, b0, acc[0][0], 0, 0, 0);
          acc[0][1] = __builtin_amdgcn_mfma_f32_16x16x32_bf16(va0, b1v, acc[0][1], 0, 0, 0);
          acc[1][0] = __builtin_amdgcn_mfma_f32_16x16x32_bf16(va1, b0, acc[1][0], 0, 0, 0);
          acc[1][1] = __builtin_amdgcn_mfma_f32_16x16x32_bf16(va1, b1v, acc[1][1], 0, 0, 0);
        }
      }
      if (s >= 2) {
        const size_t t1 = (size_t)(s - 2);
#pragma unroll
        for (int half = 0; half < 2; ++half) {     // h1 @ Wh1
          short8 a0[4], a1[4];
          const int kb = kw + half * 128;
#pragma unroll
          for (int kk = 0; kk < 4; ++kk) {
            a0[kk] = ldg_coh16(&Hb1[((size_t)la * T_ + t1) * H_ + kb + kk * 32]);
            a1[kk] = ldg_coh16(&Hb1[((size_t)(16 + la) * T_ + t1) * H_ + kb + kk * 32]);
          }
          vmwait0();
#pragma unroll
          for (int kk = 0; kk < 4; ++kk) {
            const int kx = (kb + kk * 32) ^ ((la & 7) << 3);
            const bf16x8 b0 = *(bf16x8*)&wB[la * 1024 + kx];
            const bf16x8 b1v = *(bf16x8*)&wB[(16 + la) * 1024 + kx];
            const bf16x8 va0 = __builtin_bit_cast(bf16x8, a0[kk]);
            const bf16x8 va1 = __builtin_bit_cast(bf16x8, a1[kk]);
            acc[0][0] = __builtin_amdgcn_mfma_f32_16x16x32_bf16(va0, b0, acc[0][0], 0, 0, 0);
            acc[0][1] = __builtin_amdgcn_mfma_f32_16x16x32_bf16(va0, b1v, acc[0][1], 0, 0, 0);
            acc[1][0] = __builtin_amdgcn_mfma_f32_16x16x32_bf16(va1, b0, acc[1][0], 0, 0, 0);
            acc[1][1] = __builtin_amdgcn_mfma_f32_16x16x32_bf16(va1, b1v, acc[1][1], 0, 0, 0);
          }
        }
      }
    }

    // ---- reduce + store gf (block-uniform guard)
    const bool doStore = isL1 ? (s >= 1) : (s < T_);
    if (doStore) {
#pragma unroll
      for (int half = 0; half < 2; ++half)
#pragma unroll
        for (int cg = 0; cg < 2; ++cg)
#pragma unroll
          for (int r = 0; r < 4; ++r)
            red[w][half * 16 + lb * 4 + r][cg * 16 + la] = acc[half][cg][r];
      __syncthreads();
      const int b2 = tid >> 3, c4 = (tid & 7) * 4;
      f32x4 sv = *(f32x4*)&red[0][b2][c4];
      sv += *(f32x4*)&red[1][b2][c4];
      sv += *(f32x4*)&red[2][b2][c4];
      sv += *(f32x4*)&red[3][b2][c4];
      if (!isL1) {
        sv += *(const f32x4*)&G[((size_t)(b2 * T_ + s)) * G4H_ + cb + c4];
        stg_coh16f(&gf0[(size_t)b2 * G4H_ + cb + c4], sv);
      } else {
        sv += *(const f32x4*)&b1[cb + c4];
        stg_coh16f(&gf1[(size_t)b2 * G4H_ + cb + c4], sv);
      }
      __syncthreads();                       // drain gf stores + red consumed
      if (tid == 0) {
        if (!isL1)
          __hip_atomic_store(&flag_g0[16 * bid], (unsigned)(s + 1), __ATOMIC_RELAXED, __HIP_MEMORY_SCOPE_AGENT);
        else
          __hip_atomic_store(&flag_g1[16 * (bid - 128)], (unsigned)(s + 1), __ATOMIC_RELAXED, __HIP_MEMORY_SCOPE_AGENT);
      }
    }

    // ---- phase 2 (block-uniform guard)
    const bool doP2 = (!isL1) ? (bid < 32 && s < T_) : (bid < 160 && s >= 1);
    if (doP2) {
      const int b = isL1 ? (bid - 128) : bid;
      if (w == 0) wait_flags(isL1 ? flag_g1 : flag_g0, 128, (unsigned)(s + 1));
      __syncthreads();
      const float* gfp = (isL1 ? gf1 : gf0) + (size_t)b * G4H_;
      const float* g_ = isL1 ? (lng + 5120) : lng;
      const float* b_ = isL1 ? (lnb + 5120) : lnb;
      const int tt = isL1 ? (s - 1) : s;
      unsigned short* hout = (isL1 ? Hb1 : Hb0) + ((size_t)b * T_ + tt) * H_;
      lstm_pointwise(gfp, g_, b_, crow, rsc, hout, tid, lane, w);
      if (tid == 0) {
        if (isL1)
          __hip_atomic_store(&flag_h1[16 * b], (unsigned)s, __ATOMIC_RELAXED, __HIP_MEMORY_SCOPE_AGENT);
        else
          __hip_atomic_store(&flag_h0[16 * b], (unsigned)(s + 1), __ATOMIC_RELAXED, __HIP_MEMORY_SCOPE_AGENT);
      }
    }
  }
}

// ---------------------------------------------------------------- fused 2-layer LN-LSTM
// (r10-proven fallback: all blocks run A,B,C; VGPR=140.)
__global__ __launch_bounds__(256)
void k_lstm2(const float* __restrict__ G, const unsigned short* __restrict__ WhT0,
             const unsigned short* __restrict__ WxT1, const unsigned short* __restrict__ WhT1,
             const float* __restrict__ b1,
             const float* __restrict__ lng, const float* __restrict__ lnb,
             float* __restrict__ gf0, float* __restrict__ gf1,
             unsigned short* __restrict__ Hb0, unsigned short* __restrict__ Hb1,
             unsigned* flags) {
  __shared__ unsigned short wh0[16 * 1024];
  __shared__ unsigned short wx1[16 * 1024];
  __shared__ unsigned short wh1[16 * 1024];
  __shared__ float red[4][32][16];
  __shared__ float crow[1024];
  __shared__ float rsc[64];

  const int tid = threadIdx.x, bid = blockIdx.x;
  const int lane = tid & 63, w = tid >> 6;
  const int la = lane & 15, lb = lane >> 4;
  unsigned* flag_g0 = flags;                 // 256 slots
  unsigned* flag_g1 = flags + 4096;          // 256 slots
  unsigned* flag_h0 = flags + 8192;          // 32 slots
  unsigned* flag_h1 = flags + 8704;          // 32 slots

  for (int i = tid * 8; i < 16 * 1024; i += 2048) {
    const int cl = i >> 10, k = i & 1023;
    const int dst = cl * 1024 + (k ^ ((cl & 7) << 3));
    *(short8*)&wh0[dst] = *(const short8*)&WhT0[(size_t)bid * 16384 + i];
    *(short8*)&wx1[dst] = *(const short8*)&WxT1[(size_t)bid * 16384 + i];
    *(short8*)&wh1[dst] = *(const short8*)&WhT1[(size_t)bid * 16384 + i];
  }
  if (bid < 64)
    for (int e = tid; e < 1024; e += 256) crow[e] = 0.0f;
  __syncthreads();

  for (int s = 0; s <= T_; ++s) {
    if (w == 0) {
      if (s >= 1) wait_flags(flag_h0, 32, (unsigned)s);
      if (s >= 2) wait_flags(flag_h1, 32, (unsigned)(s - 1));
    }
    __syncthreads();

    f32x4 accA0 = {0.f,0.f,0.f,0.f}, accA1 = {0.f,0.f,0.f,0.f};
    f32x4 accB0 = {0.f,0.f,0.f,0.f}, accB1 = {0.f,0.f,0.f,0.f};
    f32x4 accC0 = {0.f,0.f,0.f,0.f}, accC1 = {0.f,0.f,0.f,0.f};
    if (s >= 1) {
      const int kw = w * 256 + lb * 8;
      const size_t t0 = (size_t)(s - 1);
      const size_t t1 = (size_t)(s - 2);
#pragma unroll
      for (int half = 0; half < 2; ++half) {
        short8 a0[4], a1[4], c0v[4], c1v[4];
        const int kb = kw + half * 128;
#pragma unroll
        for (int kk = 0; kk < 4; ++kk) {
          a0[kk] = ldg_coh16(&Hb0[((size_t)la * T_ + t0) * H_ + kb + kk * 32]);
          a1[kk] = ldg_coh16(&Hb0[((size_t)(16 + la) * T_ + t0) * H_ + kb + kk * 32]);
        }
        if (s >= 2) {
#pragma unroll
          for (int kk = 0; kk < 4; ++kk) {
            c0v[kk] = ldg_coh16(&Hb1[((size_t)la * T_ + t1) * H_ + kb + kk * 32]);
            c1v[kk] = ldg_coh16(&Hb1[((size_t)(16 + la) * T_ + t1) * H_ + kb + kk * 32]);
          }
        }
        vmwait0();
#pragma unroll
        for (int kk = 0; kk < 4; ++kk) {
          const int kx = (kb + kk * 32) ^ ((la & 7) << 3);
          const bf16x8 va0 = __builtin_bit_cast(bf16x8, a0[kk]);
          const bf16x8 va1 = __builtin_bit_cast(bf16x8, a1[kk]);
          const bf16x8 bB = *(bf16x8*)&wx1[la * 1024 + kx];
          accB0 = __builtin_amdgcn_mfma_f32_16x16x32_bf16(va0, bB, accB0, 0, 0, 0);
          accB1 = __builtin_amdgcn_mfma_f32_16x16x32_bf16(va1, bB, accB1, 0, 0, 0);
          if (s < T_) {
            const bf16x8 bA = *(bf16x8*)&wh0[la * 1024 + kx];
            accA0 = __builtin_amdgcn_mfma_f32_16x16x32_bf16(va0, bA, accA0, 0, 0, 0);
            accA1 = __builtin_amdgcn_mfma_f32_16x16x32_bf16(va1, bA, accA1, 0, 0, 0);
          }
          if (s >= 2) {
            const bf16x8 bC = *(bf16x8*)&wh1[la * 1024 + kx];
            const bf16x8 vc0 = __builtin_bit_cast(bf16x8, c0v[kk]);
            const bf16x8 vc1 = __builtin_bit_cast(bf16x8, c1v[kk]);
            accC0 = __builtin_amdgcn_mfma_f32_16x16x32_bf16(vc0, bC, accC0, 0, 0, 0);
            accC1 = __builtin_amdgcn_mfma_f32_16x16x32_bf16(vc1, bC, accC1, 0, 0, 0);
          }
        }
      }
    }

#pragma unroll
    for (int r = 0; r < 4; ++r) {
      red[w][lb * 4 + r][la] = accA0[r];
      red[w][16 + lb * 4 + r][la] = accA1[r];
    }
    __syncthreads();
    if (s < T_) {
      const int b2 = tid >> 3, c2 = (tid & 7) * 2;
      f32x2 sv;
      sv.x = red[0][b2][c2]     + red[1][b2][c2]     + red[2][b2][c2]     + red[3][b2][c2]
           + G[((size_t)(b2 * T_ + s)) * G4H_ + bid * 16 + c2];
      sv.y = red[0][b2][c2 + 1] + red[1][b2][c2 + 1] + red[2][b2][c2 + 1] + red[3][b2][c2 + 1]
           + G[((size_t)(b2 * T_ + s)) * G4H_ + bid * 16 + c2 + 1];
      stg_coh8f(&gf0[b2 * G4H_ + bid * 16 + c2], sv);
    }
    __syncthreads();
    if (tid == 0 && s < T_)
      __hip_atomic_store(&flag_g0[16 * bid], (unsigned)(s + 1), __ATOMIC_RELAXED, __HIP_MEMORY_SCOPE_AGENT);

#pragma unroll
    for (int r = 0; r < 4; ++r) {
      red[w][lb * 4 + r][la] = accB0[r] + accC0[r];
      red[w][16 + lb * 4 + r][la] = accB1[r] + accC1[r];
    }
    __syncthreads();
    if (s >= 1) {
      const int b2 = tid >> 3, c2 = (tid & 7) * 2;
      f32x2 sv;
      sv.x = red[0][b2][c2]     + red[1][b2][c2]     + red[2][b2][c2]     + red[3][b2][c2]
           + b1[bid * 16 + c2];
      sv.y = red[0][b2][c2 + 1] + red[1][b2][c2 + 1] + red[2][b2][c2 + 1] + red[3][b2][c2 + 1]
           + b1[bid * 16 + c2 + 1];
      stg_coh8f(&gf1[b2 * G4H_ + bid * 16 + c2], sv);
    }
    __syncthreads();
    if (tid == 0 && s >= 1)
      __hip_atomic_store(&flag_g1[16 * bid], (unsigned)(s + 1), __ATOMIC_RELAXED, __HIP_MEMORY_SCOPE_AGENT);

    const bool isP2 = (bid < 32) ? (s < T_) : (bid < 64 ? (s >= 1) : false);
    if (isP2) {
      const bool L1p = (bid >= 32);
      const int b = L1p ? (bid - 32) : bid;
      if (w == 0) wait_flags(L1p ? flag_g1 : flag_g0, 256, (unsigned)(s + 1));
      __syncthreads();
      const float* gfp = (L1p ? gf1 : gf0) + (size_t)b * G4H_;
      const float* g_ = L1p ? (lng + 5120) : lng;
      const float* b_ = L1p ? (lnb + 5120) : lnb;
      const int tt = L1p ? (s - 1) : s;
      unsigned short* hout = (L1p ? Hb1 : Hb0) + ((size_t)b * T_ + tt) * H_;
      lstm_pointwise(gfp, g_, b_, crow, rsc, hout, tid, lane, w);
      if (tid == 0) {
        if (L1p)
          __hip_atomic_store(&flag_h1[16 * b], (unsigned)s, __ATOMIC_RELAXED, __HIP_MEMORY_SCOPE_AGENT);
        else
          __hip_atomic_store(&flag_h0[16 * b], (unsigned)(s + 1), __ATOMIC_RELAXED, __HIP_MEMORY_SCOPE_AGENT);
      }
    }
  }
}

// ---------------------------------------------------------------- LSE finish
__global__ __launch_bounds__(256)
void k_lse_finish(const float* __restrict__ part, float* __restrict__ lse) {
  __shared__ float rm[4];
  __shared__ float rs[4];
  const int r = blockIdx.x, tid = threadIdx.x;
  const int lane = tid & 63, w = tid >> 6;
  float m = -1e30f, s = 0.f;
  for (int i = tid; i < 500; i += 256) {
    const float2 p = *(const float2*)&part[((size_t)r * 512 + i) * 2];
    const float nm = fmaxf(m, p.x);
    s = s * __expf(m - nm) + p.y * __expf(p.x - nm);
    m = nm;
  }
  for (int off = 32; off > 0; off >>= 1) {
    const float m2 = __shfl_down(m, off), s2 = __shfl_down(s, off);
    const float nm = fmaxf(m, m2);
    s = s * __expf(m - nm) + s2 * __expf(m2 - nm);
    m = nm;
  }
  if (lane == 0) { rm[w] = m; rs[w] = s; }
  __syncthreads();
  if (tid == 0) {
    float M = rm[0], S = rs[0];
#pragma unroll
    for (int i = 1; i < 4; ++i) {
      const float nm = fmaxf(M, rm[i]);
      S = S * __expf(M - nm) + rs[i] * __expf(rm[i] - nm);
      M = nm;
    }
    lse[r] = M + logf(S);
  }
}

// ---------------------------------------------------------------- loss (mean NLL)
__global__ __launch_bounds__(256)
void k_loss(const float* __restrict__ logits, const float* __restrict__ lse,
            const int* __restrict__ tgt, float* __restrict__ out) {
  __shared__ float rsc[4];
  const int tid = threadIdx.x;
  float s = 0.f;
  for (int r = tid; r < BT_; r += 256)
    s += lse[r] - logits[(size_t)r * V_ + tgt[r]];
  for (int off = 32; off > 0; off >>= 1) s += __shfl_down(s, off);
  if ((tid & 63) == 0) rsc[tid >> 6] = s;
  __syncthreads();
  if (tid == 0) out[(size_t)BT_ * V_] = (rsc[0] + rsc[1] + rsc[2] + rsc[3]) / (float)BT_;
}

// ================================================================ launch
// k_lstm3 (layer-split) with CHECKED launch -> fallback to proven k_lstm2.
// ws ~191.4 MB (budget ~192 MB): gf0/gf1/bars/lseb alias Xemb (dead after L0
// x-GEMM); LSE partials alias Gbuf (dead after LSTM).
extern "C" void kernel_launch(void* const* d_in, const int* in_sizes, int n_in,
                              void* d_out, int out_size, void* d_ws, size_t ws_size,
                              hipStream_t stream) {
  const int*   ids  = (const int*)d_in[0];
  const int*   tgt  = (const int*)d_in[1];
  const float* emb  = (const float*)d_in[2];
  const float* W    = (const float*)d_in[3];   // [2][2048][4096]
  const float* brnn = (const float*)d_in[4];   // [2][4096]
  const float* lng  = (const float*)d_in[5];   // [2][5][1024]
  const float* lnb  = (const float*)d_in[6];
  const float* sw   = (const float*)d_in[7];   // [1024][32000]
  const float* sb   = (const float*)d_in[8];   // [32000]
  float* out = (float*)d_out;

  char* ws = (char*)d_ws;
  size_t o = 0;
  auto take = [&](size_t n) { char* p = ws + o; o += (n + 255) & ~(size_t)255; return p; };
  unsigned short* WxT0 = (unsigned short*)take((size_t)G4H_ * H_ * 2);
  unsigned short* WhT0 = (unsigned short*)take((size_t)G4H_ * H_ * 2);
  unsigned short* WxT1 = (unsigned short*)take((size_t)G4H_ * H_ * 2);
  unsigned short* WhT1 = (unsigned short*)take((size_t)G4H_ * H_ * 2);
  unsigned short* WsT  = (unsigned short*)take((size_t)V_ * H_ * 2);
  unsigned short* Xemb = (unsigned short*)take((size_t)BT_ * H_ * 2);
  float*          Gbuf = (float*)take((size_t)BT_ * G4H_ * 4);
  unsigned short* Hb0  = (unsigned short*)take((size_t)BT_ * H_ * 2);
  unsigned short* Hb1  = (unsigned short*)take((size_t)BT_ * H_ * 2);
  char* xregion = (char*)Xemb;
  float*    gf0  = (float*)(xregion);
  float*    gf1  = (float*)(xregion + 524288);
  unsigned* bars = (unsigned*)(xregion + 1048576);
  float*    lseb = (float*)(xregion + 1089536);
  float*    lsepart = (float*)Gbuf;            // 16 MB, aliases Gbuf after LSTM

  const dim3 tb(32, 8);
  k_transpose_cast<<<dim3(128, 32),  tb, 0, stream>>>(W,                    WxT0, 1024, 4096, 4096);
  k_transpose_cast<<<dim3(128, 32),  tb, 0, stream>>>(W + 1024 * 4096,      WhT0, 1024, 4096, 4096);
  k_transpose_cast<<<dim3(128, 32),  tb, 0, stream>>>(W + 2048 * 4096,      WxT1, 1024, 4096, 4096);
  k_transpose_cast<<<dim3(128, 32),  tb, 0, stream>>>(W + 3072 * 4096,      WhT1, 1024, 4096, 4096);
  k_transpose_cast<<<dim3(1000, 32), tb, 0, stream>>>(sw,                   WsT,  1024, V_,  V_);

  k_gather<<<BT_, 256, 0, stream>>>(ids, emb, Xemb);
  k_gemm_bt<<<dim3(32, 32), 256, 0, stream>>>(Xemb, WxT0, brnn, Gbuf, BT_, G4H_, H_, nullptr);

  hipMemsetAsync(bars, 0, 40960, stream);

  const float* G_ = Gbuf;
  const unsigned short* Wh0_ = WhT0; const unsigned short* Wx1_ = WxT1; const unsigned short* Wh1_ = WhT1;
  const float* b1_ = brnn + 4096;
  const float* g0_ = lng; const float* bb0_ = lnb;
  float* gf0_ = gf0; float* gf1_ = gf1;
  unsigned short* H0_ = Hb0; unsigned short* H1_ = Hb1;
  unsigned* bars_ = bars;
  void* args[] = {&G_, &Wh0_, &Wx1_, &Wh1_, &b1_, &g0_, &bb0_, &gf0_, &gf1_, &H0_, &H1_, &bars_};

  hipError_t ce = hipLaunchCooperativeKernel((void*)k_lstm3, dim3(256), dim3(256), args, 0, stream);
  if (ce != hipSuccess) {
    // fallback: r10-proven fused kernel (flag layout differs but bars is zeroed
    // and only one kernel runs)
    hipLaunchCooperativeKernel((void*)k_lstm2, dim3(256), dim3(256), args, 0, stream);
  }

  k_gemm_bt<<<dim3(250, 32), 256, 0, stream>>>(Hb1, WsT, sb, out, BT_, V_, H_, lsepart);
  k_lse_finish<<<BT_, 256, 0, stream>>>(lsepart, lseb);
  k_loss<<<1, 256, 0, stream>>>(out, lseb, tgt, out);
}